// Round 3
// baseline (883.738 us; speedup 1.0000x reference)
//
#include <hip/hip_runtime.h>
#include <cstdint>
#include <cstddef>

#define EPISODES 128
#define LPAD     512
#define DDIM     512
#define NS_CAP   320
#define GTILE    64
#define NPAIRS   15          // 5*(5+1)/2 tile pairs (NS_CAP/GTILE = 5)
#define CG_ITERS 24
#define CROWS    48          // G rows per staged chunk (48*320*4 = 60 KB)
#define XROWS    24          // X rows per staged chunk (24*512*4 = 48 KB)
#define CHUNK    24          // fallback kernel
#define CG_ITERS_FB 48

__device__ __forceinline__ int lower_bound_dev(const int* __restrict__ a, int n, int key){
    int lo = 0, hi = n;
    while(lo < hi){
        int m = (lo + hi) >> 1;
        if(a[m] < key) lo = m + 1; else hi = m;
    }
    return lo;
}

// async global->LDS, 16B per lane. LDS dest = wave-uniform base + lane*16.
__device__ __forceinline__ void gl_lds16(const float* g, float* l){
    __builtin_amdgcn_global_load_lds(
        (const __attribute__((address_space(1))) void*)g,
        (__attribute__((address_space(3))) void*)l, 16, 0, 0);
}
__device__ __forceinline__ void gl_lds4(const float* g, float* l){
    __builtin_amdgcn_global_load_lds(
        (const __attribute__((address_space(1))) void*)g,
        (__attribute__((address_space(3))) void*)l, 4, 0, 0);
}

// ---------------------------------------------------------------------------
// Kernel 1: per-episode segmentation, gather, counts, means, support row sums.
// ---------------------------------------------------------------------------
__global__ __launch_bounds__(256) void k_gather(
        const int* __restrict__ labels, const int* __restrict__ is_query,
        const int* __restrict__ bidx, const float* __restrict__ X, int N,
        int* __restrict__ sup_idx, int* __restrict__ qry_idx,
        int* __restrict__ sup_lab, int* __restrict__ counts,
        float* __restrict__ task_mean, float* __restrict__ pos_mean,
        float* __restrict__ neg_mean, float* __restrict__ row_sums)
{
    const int b    = blockIdx.x;
    const int tid  = threadIdx.x;
    const int lane = tid & 63;
    const int wave = tid >> 6;

    __shared__ int s_start, s_end;
    __shared__ int wq[4];
    __shared__ int s_runq, s_npos;

    if(tid == 0){
        s_start = lower_bound_dev(bidx, N, b);
        s_end   = lower_bound_dev(bidx, N, b + 1);
        s_runq  = 0;
        s_npos  = 0;
    }
    __syncthreads();
    const int start = s_start, end = s_end;

    for(int base = start; base < end; base += 256){
        int idx   = base + tid;
        bool valid = idx < end;
        int q   = valid ? is_query[idx] : 0;
        int lab = valid ? labels[idx]   : 0;
        unsigned long long m = __ballot(q == 1);
        if(lane == 0) wq[wave] = __popcll(m);
        __syncthreads();
        int woff = 0;
        for(int w = 0; w < wave; w++) woff += wq[w];
        int qbefore = __popcll(m & ((1ull << lane) - 1ull)) + woff;
        int runq0 = s_runq;
        int chunk_total = wq[0] + wq[1] + wq[2] + wq[3];
        if(valid){
            int pos_in_seg = idx - start;
            if(q){
                int qr = runq0 + qbefore;
                if(qr < LPAD) qry_idx[b * LPAD + qr] = idx;
            } else {
                int sr = pos_in_seg - runq0 - qbefore;
                if(sr < LPAD){
                    sup_idx[b * LPAD + sr] = idx;
                    sup_lab[b * LPAD + sr] = lab;
                    if(lab == 1) atomicAdd(&s_npos, 1);
                }
            }
        }
        __syncthreads();
        if(tid == 0) s_runq = runq0 + chunk_total;
        __syncthreads();
    }

    const int nq   = s_runq;
    const int ns   = (end - start) - nq;
    const int npos = s_npos;
    const int nneg = ns - npos;
    if(tid == 0){
        counts[b*4 + 0] = ns;
        counts[b*4 + 1] = nq;
        counts[b*4 + 2] = npos;
        counts[b*4 + 3] = nneg;
    }
    __syncthreads();

    // Means: thread owns dims d0 = tid and d1 = tid + 256.
    const int d0 = tid, d1 = tid + 256;
    float sa0 = 0.f, sa1 = 0.f, sp0 = 0.f, sp1 = 0.f, sn0 = 0.f, sn1 = 0.f;
    for(int s = 0; s < ns; s++){
        int n   = sup_idx[b * LPAD + s];
        int lab = sup_lab[b * LPAD + s];
        float x0 = X[(size_t)n * DDIM + d0];
        float x1 = X[(size_t)n * DDIM + d1];
        sa0 += x0; sa1 += x1;
        if(lab){ sp0 += x0; sp1 += x1; } else { sn0 += x0; sn1 += x1; }
    }
    float fns = (float)ns, fnp = (float)npos, fnn = (float)nneg;
    task_mean[b*DDIM + d0] = sa0 / fns;  task_mean[b*DDIM + d1] = sa1 / fns;
    pos_mean [b*DDIM + d0] = sp0 / fnp;  pos_mean [b*DDIM + d1] = sp1 / fnp;
    neg_mean [b*DDIM + d0] = sn0 / fnn;  neg_mean [b*DDIM + d1] = sn1 / fnn;

    // Support row sums (t_s for p = 1_D): one wave per row, lanes over dims.
    for(int r = wave; r < ns; r += 4){
        int n = sup_idx[b * LPAD + r];
        float s = 0.f;
        #pragma unroll
        for(int k = 0; k < 8; k++) s += X[(size_t)n * DDIM + lane + 64*k];
        #pragma unroll
        for(int off = 32; off; off >>= 1) s += __shfl_xor(s, off);
        if(lane == 0) row_sums[b * LPAD + r] = s;
    }
}

// ---------------------------------------------------------------------------
// Kernel 2: raw support Gram G0[b] = Xs Xs^T, zero-padded to NS_CAP x NS_CAP.
// ---------------------------------------------------------------------------
__global__ __launch_bounds__(256) void k_gram(
        const float* __restrict__ X, const int* __restrict__ sup_idx,
        const int* __restrict__ counts, float* __restrict__ G0)
{
    const int bid = blockIdx.x;
    const int b   = bid / NPAIRS;
    int tp = bid % NPAIRS;
    int ti = 0;
    while((ti+1)*(ti+2)/2 <= tp) ti++;
    const int tj  = tp - ti*(ti+1)/2;          // ti >= tj
    const int tid = threadIdx.x;
    const int ty  = tid >> 4, tx = tid & 15;

    const int ns  = counts[b*4 + 0];
    const int nsc = min(ns, NS_CAP);
    float* G = G0 + (size_t)b * NS_CAP * NS_CAP;

    // fast path: tile entirely in the zero-padding region
    if(ti * GTILE >= nsc){
        float4 z = make_float4(0.f, 0.f, 0.f, 0.f);
        #pragma unroll
        for(int t = 0; t < 4; t++){
            int f = tid + t*256; int rr = f >> 4; int c4 = f & 15;
            *(float4*)&G[(size_t)(ti*GTILE + rr)*NS_CAP + tj*GTILE + 4*c4] = z;
            if(ti != tj)
                *(float4*)&G[(size_t)(tj*GTILE + rr)*NS_CAP + ti*GTILE + 4*c4] = z;
        }
        return;
    }

    __shared__ float Sb[64*68];                // Ast[32][68]+Bst[32][68]; reused as Tl[64][68]
    __shared__ int ia[GTILE], ib[GTILE];
    float* Ast = Sb;
    float* Bst = Sb + 32*68;

    if(tid < GTILE)            ia[tid]      = sup_idx[b*LPAD + min(ti*GTILE + tid,        nsc-1)];
    else if(tid < 2*GTILE)     ib[tid - 64] = sup_idx[b*LPAD + min(tj*GTILE + (tid - 64), nsc-1)];

    float acc[4][4];
    #pragma unroll
    for(int a = 0; a < 4; a++)
        #pragma unroll
        for(int c = 0; c < 4; c++) acc[a][c] = 0.f;

    for(int k0 = 0; k0 < DDIM; k0 += 32){
        __syncthreads();                       // Sb free (covers ia/ib at k0=0)
        #pragma unroll
        for(int t = 0; t < 2; t++){
            int f   = tid + t*256;
            int row = f >> 3, c4 = f & 7;
            float4 xa = *(const float4*)(X + (size_t)ia[row]*DDIM + k0 + 4*c4);
            float4 xb = *(const float4*)(X + (size_t)ib[row]*DDIM + k0 + 4*c4);
            Ast[(4*c4+0)*68 + row] = xa.x;
            Ast[(4*c4+1)*68 + row] = xa.y;
            Ast[(4*c4+2)*68 + row] = xa.z;
            Ast[(4*c4+3)*68 + row] = xa.w;
            Bst[(4*c4+0)*68 + row] = xb.x;
            Bst[(4*c4+1)*68 + row] = xb.y;
            Bst[(4*c4+2)*68 + row] = xb.z;
            Bst[(4*c4+3)*68 + row] = xb.w;
        }
        __syncthreads();
        #pragma unroll 8
        for(int k = 0; k < 32; k++){
            float4 af = *(const float4*)&Ast[k*68 + 4*ty];
            float4 bf = *(const float4*)&Bst[k*68 + 4*tx];
            acc[0][0] += af.x*bf.x; acc[0][1] += af.x*bf.y; acc[0][2] += af.x*bf.z; acc[0][3] += af.x*bf.w;
            acc[1][0] += af.y*bf.x; acc[1][1] += af.y*bf.y; acc[1][2] += af.y*bf.z; acc[1][3] += af.y*bf.w;
            acc[2][0] += af.z*bf.x; acc[2][1] += af.z*bf.y; acc[2][2] += af.z*bf.z; acc[2][3] += af.z*bf.w;
            acc[3][0] += af.w*bf.x; acc[3][1] += af.w*bf.y; acc[3][2] += af.w*bf.z; acc[3][3] += af.w*bf.w;
        }
    }

    // direct block (ti,tj): coalesced float4 rows, zero-masked padding
    #pragma unroll
    for(int a = 0; a < 4; a++){
        int i  = ti*GTILE + 4*ty + a;
        int j0 = tj*GTILE + 4*tx;
        float4 v;
        v.x = (i < nsc && j0+0 < nsc) ? acc[a][0] : 0.f;
        v.y = (i < nsc && j0+1 < nsc) ? acc[a][1] : 0.f;
        v.z = (i < nsc && j0+2 < nsc) ? acc[a][2] : 0.f;
        v.w = (i < nsc && j0+3 < nsc) ? acc[a][3] : 0.f;
        *(float4*)&G[(size_t)i*NS_CAP + j0] = v;
    }
    if(ti != tj){
        __syncthreads();                       // done with Ast/Bst
        #pragma unroll
        for(int a = 0; a < 4; a++)
            #pragma unroll
            for(int c = 0; c < 4; c++){
                int i = ti*GTILE + 4*ty + a;
                int j = tj*GTILE + 4*tx + c;
                Sb[(4*tx + c)*68 + 4*ty + a] = (i < nsc && j < nsc) ? acc[a][c] : 0.f;
            }
        __syncthreads();
        #pragma unroll
        for(int t = 0; t < 4; t++){
            int f = tid + t*256; int rr = f >> 4; int c4 = f & 15;
            float4 w = *(const float4*)&Sb[rr*68 + 4*c4];
            *(float4*)&G[(size_t)(tj*GTILE + rr)*NS_CAP + ti*GTILE + 4*c4] = w;
        }
    }
}

// ---------------------------------------------------------------------------
// Kernel 3: coefficient-space CG + reconstruction, with global_load_lds
// staging of G rows (matvec) and X rows (reconstruction) for deep MLP.
// One workgroup (512 threads) per (episode, class) system.
// ---------------------------------------------------------------------------
__global__ __launch_bounds__(512) void k_cgc(
        const float* __restrict__ X, const float* __restrict__ G0,
        const int* __restrict__ sup_idx, const int* __restrict__ sup_lab,
        const int* __restrict__ counts, const float* __restrict__ row_sums,
        float* __restrict__ vout)
{
    const int sys  = blockIdx.x;
    const int b    = sys >> 1;
    const int cls  = sys & 1;
    const int tid  = threadIdx.x;
    const int lane = tid & 63;
    const int wave = tid >> 6;

    __shared__ __align__(16) float gs[CROWS * NS_CAP];   // 60 KB staging
    __shared__ __align__(16) float u[NS_CAP];
    __shared__ float tq[NS_CAP];
    __shared__ float red1s[8];
    __shared__ float red2s[8][2];

    const int ns   = counts[b*4 + 0];
    const int nsc  = min(ns, NS_CAP);
    const int ncls = cls ? counts[b*4 + 2] : counts[b*4 + 3];
    const float c_task = 0.9f / (float)(ns - 1);
    const float c_cls  = 0.1f / (float)(ncls - 1);
    const float inv_ns = 1.f / (float)ns;
    const float inv_nc = 1.f / (float)ncls;
    const float* G = G0 + (size_t)b * NS_CAP * NS_CAP;

    const bool own = tid < nsc;
    float mfl = 0.f, sraw = 0.f;
    if(own){
        mfl  = (sup_lab[b*LPAD + tid] == cls) ? 1.f : 0.f;
        sraw = row_sums[b*LPAD + tid];
    }

    auto reduce1 = [&](float v) -> float {
        #pragma unroll
        for(int off = 32; off; off >>= 1) v += __shfl_xor(v, off);
        __syncthreads();
        if(lane == 0) red1s[wave] = v;
        __syncthreads();
        float s = 0.f;
        #pragma unroll
        for(int w = 0; w < 8; w++) s += red1s[w];
        return s;
    };
    auto reduce2 = [&](float a, float c, float& oa, float& oc){
        #pragma unroll
        for(int off = 32; off; off >>= 1){ a += __shfl_xor(a, off); c += __shfl_xor(c, off); }
        __syncthreads();
        if(lane == 0){ red2s[wave][0] = a; red2s[wave][1] = c; }
        __syncthreads();
        oa = 0.f; oc = 0.f;
        #pragma unroll
        for(int w = 0; w < 8; w++){ oa += red2s[w][0]; oc += red2s[w][1]; }
    };

    // tq[0..nsc) = G0 * u.  Stages G rows into LDS via global_load_lds
    // (1024B/row via 16B-wide DMA; +tail only when nsc>256), then dots from
    // LDS. Cols [nsc,256) of G are zero-padded by k_gram, u[] zero past nsc,
    // so full-width dots are exact.
    const bool big = (nsc > 256);
    auto matvec = [&](){
        const float4* uf4 = (const float4*)u;
        float4 ua = uf4[lane];
        float4 ub = big ? uf4[(lane & 15) + 64] : make_float4(0.f,0.f,0.f,0.f);
        for(int cs = 0; cs < nsc; cs += CROWS){
            int nrows = min(CROWS, nsc - cs);
            __syncthreads();                   // gs free from previous phase
            for(int r = wave; r < nrows; r += 8){
                const float* gsrc = G + (size_t)(cs + r) * NS_CAP;
                float* ldst = &gs[r * NS_CAP];
                gl_lds16(gsrc + 4*lane, ldst + 4*lane);
                if(big) gl_lds4(gsrc + 256 + lane, ldst + 256 + lane);
            }
            __syncthreads();                   // vmcnt(0) drain + barrier
            for(int r = wave; r < nrows; r += 8){
                const float4* row = (const float4*)&gs[r * NS_CAP];
                float4 ga = row[lane];
                float s = ga.x*ua.x + ga.y*ua.y + ga.z*ua.z + ga.w*ua.w;
                if(big && lane < 16){
                    float4 gb = row[lane + 64];
                    s += gb.x*ub.x + gb.y*ub.y + gb.z*ub.z + gb.w*ub.w;
                }
                #pragma unroll
                for(int off = 32; off; off >>= 1) s += __shfl_xor(s, off);
                if(lane == 0) tq[cs + r] = s;
            }
        }
    };

    // r0 = 1 - M(10*1) = -10 * A * 1  (t for p=1_D is the row-sum vector)
    float A0, A1;
    reduce2(sraw, mfl * sraw, A0, A1);
    A0 *= inv_ns; A1 *= inv_nc;
    float cr = own ? -10.f * (c_task*(sraw - A0) + mfl*c_cls*(sraw - A1)) : 0.f;
    if(tid < NS_CAP) u[tid] = cr;
    __syncthreads();
    matvec();
    __syncthreads();
    float tr  = own ? tq[tid] : 0.f;
    float cp  = cr, tpv = tr, cx = 0.f;
    float rr  = reduce1(cr * tr);

    for(int it = 0; it < CG_ITERS; ++it){
        reduce2(tpv, mfl * tpv, A0, A1);
        A0 *= inv_ns; A1 *= inv_nc;
        float ui = own ? (c_task*(tpv - A0) + mfl*c_cls*(tpv - A1)) : 0.f;
        float qc = 0.1f*cp + ui;               // c_q = 0.1 c_p + u
        if(tid < NS_CAP) u[tid] = ui;
        float pq = reduce1(tpv * qc);          // barrier inside publishes u
        matvec();                              // G0 * u
        __syncthreads();
        float tqf = 0.1f*tpv + (own ? tq[tid] : 0.f);   // t_q = 0.1 t_p + G0 u
        float alpha = rr / pq;
        cx += alpha * cp;
        cr -= alpha * qc;
        tr -= alpha * tqf;
        float rrn = reduce1(cr * tr);
        float beta = rrn / rr;
        rr = rrn;
        cp  = cr + beta * cp;
        tpv = tr + beta * tpv;
        if(rr < 1e-26f) break;                 // uniform across block
    }

    // v = 10*1 + Xs^T c_x  (staged X rows; thread owns dim tid)
    __syncthreads();
    if(tid < NS_CAP) u[tid] = own ? cx : 0.f;
    __syncthreads();
    float v = 10.f;
    for(int cs = 0; cs < nsc; cs += XROWS){
        int nrows = min(XROWS, nsc - cs);
        __syncthreads();                       // gs free
        for(int r = wave; r < nrows; r += 8){
            int n = sup_idx[b*LPAD + cs + r];
            const float* xsrc = X + (size_t)n * DDIM;
            float* ldst = &gs[r * DDIM];
            gl_lds16(xsrc + 4*lane, ldst + 4*lane);
            gl_lds16(xsrc + 256 + 4*lane, ldst + 256 + 4*lane);
        }
        __syncthreads();
        for(int r = 0; r < nrows; r++) v += u[cs + r] * gs[r*DDIM + tid];
    }
    vout[(size_t)sys * DDIM + tid] = v;
}

// ---------------------------------------------------------------------------
// Fallback kernel (D-space CG) if workspace is too small for G0.
// ---------------------------------------------------------------------------
__global__ __launch_bounds__(512) void k_cg(
        const float* __restrict__ X,
        const int* __restrict__ sup_idx, const int* __restrict__ sup_lab,
        const int* __restrict__ counts,
        const float* __restrict__ task_mean, const float* __restrict__ pos_mean,
        const float* __restrict__ neg_mean,
        float* __restrict__ vout)
{
    const int sys  = blockIdx.x;
    const int b    = sys >> 1;
    const int cls  = sys & 1;
    const int tid  = threadIdx.x;
    const int lane = tid & 63;
    const int wave = tid >> 6;
    const int d    = tid;

    __shared__ float xs[CHUNK][DDIM];
    __shared__ float p_lds[DDIM];
    __shared__ float w_lds[CHUNK];
    __shared__ int   lab_lds[CHUNK];
    __shared__ int   idx_lds[CHUNK];
    __shared__ float red1[8];
    __shared__ float red2[8][2];

    const int ns   = counts[b*4 + 0];
    const int ncls = cls ? counts[b*4 + 2] : counts[b*4 + 3];
    const float c_task = 0.9f / (float)(ns - 1);
    const float c_cls  = 0.1f / (float)(ncls - 1);
    const float mu_d    = task_mean[b*DDIM + d];
    const float mucls_d = cls ? pos_mean[b*DDIM + d] : neg_mean[b*DDIM + d];

    auto blockReduce = [&](float v) -> float {
        #pragma unroll
        for(int off = 32; off; off >>= 1) v += __shfl_xor(v, off);
        __syncthreads();
        if(lane == 0) red1[wave] = v;
        __syncthreads();
        float s = 0.f;
        #pragma unroll
        for(int w = 0; w < 8; w++) s += red1[w];
        return s;
    };
    auto matvec = [&](float pd_reg) -> float {
        float part0 = mu_d * pd_reg, part1 = mucls_d * pd_reg;
        #pragma unroll
        for(int off = 32; off; off >>= 1){
            part0 += __shfl_xor(part0, off);
            part1 += __shfl_xor(part1, off);
        }
        __syncthreads();
        if(lane == 0){ red2[wave][0] = part0; red2[wave][1] = part1; }
        __syncthreads();
        float a0 = 0.f, a1 = 0.f;
        #pragma unroll
        for(int w = 0; w < 8; w++){ a0 += red2[w][0]; a1 += red2[w][1]; }
        float preg[8];
        #pragma unroll
        for(int k = 0; k < 8; k++) preg[k] = p_lds[lane + 64*k];
        float q = 0.1f * pd_reg;
        for(int cs = 0; cs < ns; cs += CHUNK){
            int nrows = min(CHUNK, ns - cs);
            __syncthreads();
            if(tid < nrows){
                idx_lds[tid] = sup_idx[b * LPAD + cs + tid];
                lab_lds[tid] = sup_lab[b * LPAD + cs + tid];
            }
            __syncthreads();
            for(int f = tid; f < nrows * 128; f += 512){
                int r  = f >> 7;
                int c4 = f & 127;
                const float4* src = (const float4*)(X + (size_t)idx_lds[r] * DDIM);
                ((float4*)&xs[r][0])[c4] = src[c4];
            }
            __syncthreads();
            for(int r = wave; r < nrows; r += 8){
                float t = 0.f;
                #pragma unroll
                for(int k = 0; k < 8; k++) t += xs[r][lane + 64*k] * preg[k];
                #pragma unroll
                for(int off = 32; off; off >>= 1) t += __shfl_xor(t, off);
                if(lane == 0){
                    int lm = (lab_lds[r] == cls) ? 1 : 0;
                    w_lds[r] = c_task * (t - a0) + (lm ? c_cls * (t - a1) : 0.f);
                }
            }
            __syncthreads();
            for(int r = 0; r < nrows; r++) q += w_lds[r] * xs[r][d];
        }
        return q;
    };

    float xv = 10.0f;
    float pd = 10.0f;
    p_lds[d] = pd;
    __syncthreads();
    float qd = matvec(pd);
    float rd = 1.0f - qd;
    pd = rd;
    float rr = blockReduce(rd * rd);
    __syncthreads();
    p_lds[d] = pd;
    __syncthreads();

    for(int it = 0; it < CG_ITERS_FB; it++){
        if(rr < 1e-30f) break;
        qd = matvec(pd);
        float pq = blockReduce(pd * qd);
        float alpha = rr / pq;
        xv += alpha * pd;
        rd -= alpha * qd;
        float rr_new = blockReduce(rd * rd);
        float beta = rr_new / rr;
        rr = rr_new;
        pd = rd + beta * pd;
        __syncthreads();
        p_lds[d] = pd;
        __syncthreads();
    }
    vout[(size_t)(b*2 + cls) * DDIM + d] = xv;
}

// ---------------------------------------------------------------------------
// Kernel 4: per-query output (unchanged).
// ---------------------------------------------------------------------------
__global__ __launch_bounds__(256) void k_out(
        const float* __restrict__ X,
        const int* __restrict__ qry_idx, const int* __restrict__ counts,
        const float* __restrict__ pos_mean, const float* __restrict__ neg_mean,
        const float* __restrict__ vsol, const float* __restrict__ log_scale,
        float* __restrict__ out)
{
    const int b    = blockIdx.x;
    const int tid  = threadIdx.x;
    const int lane = tid & 63;
    const int wave = tid >> 6;

    __shared__ float vpos[DDIM], vneg[DDIM];
    __shared__ float red4[4][4];
    __shared__ float sc[4];

    const int nq  = counts[b*4 + 1];
    const int nqc = min(nq, LPAD);
    const float scale = expf(log_scale[0]);

    float pm0 = pos_mean[b*DDIM + tid], pm1 = pos_mean[b*DDIM + tid + 256];
    float nm0 = neg_mean[b*DDIM + tid], nm1 = neg_mean[b*DDIM + tid + 256];
    float vp0 = vsol[(size_t)(b*2 + 1) * DDIM + tid];
    float vp1 = vsol[(size_t)(b*2 + 1) * DDIM + tid + 256];
    float vn0 = vsol[(size_t)(b*2 + 0) * DDIM + tid];
    float vn1 = vsol[(size_t)(b*2 + 0) * DDIM + tid + 256];
    vpos[tid] = vp0; vpos[tid + 256] = vp1;
    vneg[tid] = vn0; vneg[tid + 256] = vn1;

    float smp = pm0 + pm1;
    float smn = nm0 + nm1;
    float mvp = pm0 * vp0 + pm1 * vp1;
    float mvn = nm0 * vn0 + nm1 * vn1;
    #pragma unroll
    for(int off = 32; off; off >>= 1){
        smp += __shfl_xor(smp, off);
        smn += __shfl_xor(smn, off);
        mvp += __shfl_xor(mvp, off);
        mvn += __shfl_xor(mvn, off);
    }
    if(lane == 0){
        red4[wave][0] = smp; red4[wave][1] = smn;
        red4[wave][2] = mvp; red4[wave][3] = mvn;
    }
    __syncthreads();
    if(tid < 4) sc[tid] = red4[0][tid] + red4[1][tid] + red4[2][tid] + red4[3][tid];
    __syncthreads();

    for(int r = wave; r < nqc; r += 4){
        int n = qry_idx[b * LPAD + r];
        float tp = 0.f, tn = 0.f, sx = 0.f;
        #pragma unroll
        for(int k = 0; k < 8; k++){
            float x = X[(size_t)n * DDIM + lane + 64*k];
            tp += x * vpos[lane + 64*k];
            tn += x * vneg[lane + 64*k];
            sx += x;
        }
        #pragma unroll
        for(int off = 32; off; off >>= 1){
            tp += __shfl_xor(tp, off);
            tn += __shfl_xor(tn, off);
            sx += __shfl_xor(sx, off);
        }
        if(lane == 0){
            float mp = (tp - sc[2]) * (sx - sc[0]);
            float mn = (tn - sc[3]) * (sx - sc[1]);
            ((float2*)out)[(size_t)b * LPAD + r] = make_float2(mn * scale, mp * scale);
        }
    }
    for(int r = nqc + tid; r < LPAD; r += 256)
        ((float2*)out)[(size_t)b * LPAD + r] = make_float2(0.f, 0.f);
}

// ---------------------------------------------------------------------------
extern "C" void kernel_launch(void* const* d_in, const int* in_sizes, int n_in,
                              void* d_out, int out_size, void* d_ws, size_t ws_size,
                              hipStream_t stream)
{
    const float* X         = (const float*)d_in[0];
    const float* log_scale = (const float*)d_in[1];
    const int*   labels    = (const int*)d_in[2];
    const int*   is_query  = (const int*)d_in[3];
    const int*   bidx      = (const int*)d_in[4];
    const int N = in_sizes[2];

    char* ws = (char*)d_ws;
    auto alloc = [&](size_t bytes) -> char* {
        char* p = ws;
        ws += (bytes + 255) & ~(size_t)255;
        return p;
    };
    int*   sup_idx   = (int*)  alloc((size_t)EPISODES * LPAD * sizeof(int));
    int*   qry_idx   = (int*)  alloc((size_t)EPISODES * LPAD * sizeof(int));
    int*   sup_lab   = (int*)  alloc((size_t)EPISODES * LPAD * sizeof(int));
    int*   counts    = (int*)  alloc((size_t)EPISODES * 4 * sizeof(int));
    float* task_mean = (float*)alloc((size_t)EPISODES * DDIM * sizeof(float));
    float* pos_mean  = (float*)alloc((size_t)EPISODES * DDIM * sizeof(float));
    float* neg_mean  = (float*)alloc((size_t)EPISODES * DDIM * sizeof(float));
    float* vsol      = (float*)alloc((size_t)EPISODES * 2 * DDIM * sizeof(float));
    float* row_sums  = (float*)alloc((size_t)EPISODES * LPAD * sizeof(float));
    float* G0        = (float*)alloc((size_t)EPISODES * NS_CAP * NS_CAP * sizeof(float));
    const size_t used = (size_t)(ws - (char*)d_ws);
    const bool fits = used <= ws_size;         // constant per process -> graph-safe

    k_gather<<<EPISODES, 256, 0, stream>>>(labels, is_query, bidx, X, N,
                                           sup_idx, qry_idx, sup_lab, counts,
                                           task_mean, pos_mean, neg_mean, row_sums);
    if(fits){
        k_gram<<<EPISODES * NPAIRS, 256, 0, stream>>>(X, sup_idx, counts, G0);
        k_cgc<<<EPISODES * 2, 512, 0, stream>>>(X, G0, sup_idx, sup_lab, counts,
                                                row_sums, vsol);
    } else {
        k_cg<<<EPISODES * 2, 512, 0, stream>>>(X, sup_idx, sup_lab, counts,
                                               task_mean, pos_mean, neg_mean, vsol);
    }
    k_out<<<EPISODES, 256, 0, stream>>>(X, qry_idx, counts, pos_mean, neg_mean,
                                        vsol, log_scale, (float*)d_out);
}

// Round 4
// 603.308 us; speedup vs baseline: 1.4648x; 1.4648x over previous
//
#include <hip/hip_runtime.h>
#include <cstdint>
#include <cstddef>

#define EPISODES 128
#define LPAD     512
#define DDIM     512
#define NS_CAP   320
#define GTILE    64
#define NPAIRS   15          // 5*(5+1)/2 tile pairs (NS_CAP/GTILE = 5)
#define CG_ITERS 24
#define CHUNK    24          // fallback kernel
#define CG_ITERS_FB 48

__device__ __forceinline__ int lower_bound_dev(const int* __restrict__ a, int n, int key){
    int lo = 0, hi = n;
    while(lo < hi){
        int m = (lo + hi) >> 1;
        if(a[m] < key) lo = m + 1; else hi = m;
    }
    return lo;
}

// ---------------------------------------------------------------------------
// Kernel 1: per-episode segmentation, gather, counts, means, support row sums.
// ---------------------------------------------------------------------------
__global__ __launch_bounds__(256) void k_gather(
        const int* __restrict__ labels, const int* __restrict__ is_query,
        const int* __restrict__ bidx, const float* __restrict__ X, int N,
        int* __restrict__ sup_idx, int* __restrict__ qry_idx,
        int* __restrict__ sup_lab, int* __restrict__ counts,
        float* __restrict__ task_mean, float* __restrict__ pos_mean,
        float* __restrict__ neg_mean, float* __restrict__ row_sums)
{
    const int b    = blockIdx.x;
    const int tid  = threadIdx.x;
    const int lane = tid & 63;
    const int wave = tid >> 6;

    __shared__ int s_start, s_end;
    __shared__ int wq[4];
    __shared__ int s_runq, s_npos;
    __shared__ int sidx[NS_CAP];
    __shared__ int slab[NS_CAP];

    if(tid == 0){
        s_start = lower_bound_dev(bidx, N, b);
        s_end   = lower_bound_dev(bidx, N, b + 1);
        s_runq  = 0;
        s_npos  = 0;
    }
    __syncthreads();
    const int start = s_start, end = s_end;

    for(int base = start; base < end; base += 256){
        int idx   = base + tid;
        bool valid = idx < end;
        int q   = valid ? is_query[idx] : 0;
        int lab = valid ? labels[idx]   : 0;
        unsigned long long m = __ballot(q == 1);
        if(lane == 0) wq[wave] = __popcll(m);
        __syncthreads();
        int woff = 0;
        for(int w = 0; w < wave; w++) woff += wq[w];
        int qbefore = __popcll(m & ((1ull << lane) - 1ull)) + woff;
        int runq0 = s_runq;
        int chunk_total = wq[0] + wq[1] + wq[2] + wq[3];
        if(valid){
            int pos_in_seg = idx - start;
            if(q){
                int qr = runq0 + qbefore;
                if(qr < LPAD) qry_idx[b * LPAD + qr] = idx;
            } else {
                int sr = pos_in_seg - runq0 - qbefore;
                if(sr < LPAD){
                    sup_idx[b * LPAD + sr] = idx;
                    sup_lab[b * LPAD + sr] = lab;
                    if(sr < NS_CAP){ sidx[sr] = idx; slab[sr] = lab; }
                    if(lab == 1) atomicAdd(&s_npos, 1);
                }
            }
        }
        __syncthreads();
        if(tid == 0) s_runq = runq0 + chunk_total;
        __syncthreads();
    }

    const int nq   = s_runq;
    const int ns   = (end - start) - nq;
    const int npos = s_npos;
    const int nneg = ns - npos;
    if(tid == 0){
        counts[b*4 + 0] = ns;
        counts[b*4 + 1] = nq;
        counts[b*4 + 2] = npos;
        counts[b*4 + 3] = nneg;
    }
    __syncthreads();

    const int nsb = min(ns, NS_CAP);

    // Means: thread owns dims d0 = tid and d1 = tid + 256. 8-deep unrolled
    // independent row loads (indices from LDS broadcasts) for MLP.
    const int d0 = tid, d1 = tid + 256;
    float sa0 = 0.f, sa1 = 0.f, sp0 = 0.f, sp1 = 0.f, sn0 = 0.f, sn1 = 0.f;
    int s = 0;
    for(; s + 8 <= nsb; s += 8){
        #pragma unroll
        for(int k = 0; k < 8; k++){
            int n   = sidx[s + k];
            float l = (float)slab[s + k];
            float x0 = X[(size_t)n * DDIM + d0];
            float x1 = X[(size_t)n * DDIM + d1];
            sa0 += x0; sa1 += x1;
            sp0 += l * x0; sp1 += l * x1;
        }
    }
    for(; s < nsb; s++){
        int n   = sidx[s];
        float l = (float)slab[s];
        float x0 = X[(size_t)n * DDIM + d0];
        float x1 = X[(size_t)n * DDIM + d1];
        sa0 += x0; sa1 += x1;
        sp0 += l * x0; sp1 += l * x1;
    }
    sn0 = sa0 - sp0; sn1 = sa1 - sp1;
    float fns = (float)ns, fnp = (float)npos, fnn = (float)nneg;
    task_mean[b*DDIM + d0] = sa0 / fns;  task_mean[b*DDIM + d1] = sa1 / fns;
    pos_mean [b*DDIM + d0] = sp0 / fnp;  pos_mean [b*DDIM + d1] = sp1 / fnp;
    neg_mean [b*DDIM + d0] = sn0 / fnn;  neg_mean [b*DDIM + d1] = sn1 / fnn;

    // Support row sums: one wave per 2 rows (r, r+4) interleaved for MLP.
    for(int r = wave; r < nsb; r += 8){
        int r1 = r + 4;
        int n0 = sidx[r];
        int n1 = (r1 < nsb) ? sidx[r1] : n0;
        float s0 = 0.f, s1 = 0.f;
        #pragma unroll
        for(int k = 0; k < 8; k++){
            s0 += X[(size_t)n0 * DDIM + lane + 64*k];
            s1 += X[(size_t)n1 * DDIM + lane + 64*k];
        }
        #pragma unroll
        for(int off = 32; off; off >>= 1){
            s0 += __shfl_xor(s0, off);
            s1 += __shfl_xor(s1, off);
        }
        if(lane == 0){
            row_sums[b * LPAD + r] = s0;
            if(r1 < nsb) row_sums[b * LPAD + r1] = s1;
        }
    }
}

// ---------------------------------------------------------------------------
// Kernel 2: raw support Gram in interleaved layout for the matvec:
//   element (c,t) of G0 lives at  G[(c>>2)*1280 + 4*t + (c&3)]
// so thread t in k_cgc reads float4 { G(4c4..4c4+3, t) } at G4[c4*320 + t]
// fully coalesced. Zero-padded to NS_CAP in both indices.
// ---------------------------------------------------------------------------
__global__ __launch_bounds__(256) void k_gram(
        const float* __restrict__ X, const int* __restrict__ sup_idx,
        const int* __restrict__ counts, float* __restrict__ G0)
{
    const int bid = blockIdx.x;
    const int b   = bid / NPAIRS;
    int tp = bid % NPAIRS;
    int ti = 0;
    while((ti+1)*(ti+2)/2 <= tp) ti++;
    const int tj  = tp - ti*(ti+1)/2;          // ti >= tj
    const int tid = threadIdx.x;
    const int ty  = tid >> 4, tx = tid & 15;

    const int ns  = counts[b*4 + 0];
    const int nsc = min(ns, NS_CAP);
    float* G = G0 + (size_t)b * NS_CAP * NS_CAP;

    // fast path: tile entirely in the zero-padding region
    if(ti * GTILE >= nsc){
        #pragma unroll
        for(int t = 0; t < 4; t++){
            int f = tid + t*256; int rr = f >> 4; int cc = f & 15;
            int c  = ti*GTILE + rr;
            int j0 = tj*GTILE + 4*cc;
            size_t base = (size_t)(c >> 2)*1280 + (c & 3);
            G[base + 4*(j0+0)] = 0.f; G[base + 4*(j0+1)] = 0.f;
            G[base + 4*(j0+2)] = 0.f; G[base + 4*(j0+3)] = 0.f;
            if(ti != tj){
                int c2 = tj*GTILE + rr;
                int j2 = ti*GTILE + 4*cc;
                size_t base2 = (size_t)(c2 >> 2)*1280 + (c2 & 3);
                G[base2 + 4*(j2+0)] = 0.f; G[base2 + 4*(j2+1)] = 0.f;
                G[base2 + 4*(j2+2)] = 0.f; G[base2 + 4*(j2+3)] = 0.f;
            }
        }
        return;
    }

    __shared__ float Sb[64*68];                // Ast[32][68]+Bst[32][68]
    __shared__ int ia[GTILE], ib[GTILE];
    float* Ast = Sb;
    float* Bst = Sb + 32*68;

    if(tid < GTILE)            ia[tid]      = sup_idx[b*LPAD + min(ti*GTILE + tid,        nsc-1)];
    else if(tid < 2*GTILE)     ib[tid - 64] = sup_idx[b*LPAD + min(tj*GTILE + (tid - 64), nsc-1)];

    float acc[4][4];
    #pragma unroll
    for(int a = 0; a < 4; a++)
        #pragma unroll
        for(int c = 0; c < 4; c++) acc[a][c] = 0.f;

    for(int k0 = 0; k0 < DDIM; k0 += 32){
        __syncthreads();                       // Sb free (covers ia/ib at k0=0)
        #pragma unroll
        for(int t = 0; t < 2; t++){
            int f   = tid + t*256;
            int row = f >> 3, c4 = f & 7;
            float4 xa = *(const float4*)(X + (size_t)ia[row]*DDIM + k0 + 4*c4);
            float4 xb = *(const float4*)(X + (size_t)ib[row]*DDIM + k0 + 4*c4);
            Ast[(4*c4+0)*68 + row] = xa.x;
            Ast[(4*c4+1)*68 + row] = xa.y;
            Ast[(4*c4+2)*68 + row] = xa.z;
            Ast[(4*c4+3)*68 + row] = xa.w;
            Bst[(4*c4+0)*68 + row] = xb.x;
            Bst[(4*c4+1)*68 + row] = xb.y;
            Bst[(4*c4+2)*68 + row] = xb.z;
            Bst[(4*c4+3)*68 + row] = xb.w;
        }
        __syncthreads();
        #pragma unroll 8
        for(int k = 0; k < 32; k++){
            float4 af = *(const float4*)&Ast[k*68 + 4*ty];
            float4 bf = *(const float4*)&Bst[k*68 + 4*tx];
            acc[0][0] += af.x*bf.x; acc[0][1] += af.x*bf.y; acc[0][2] += af.x*bf.z; acc[0][3] += af.x*bf.w;
            acc[1][0] += af.y*bf.x; acc[1][1] += af.y*bf.y; acc[1][2] += af.y*bf.z; acc[1][3] += af.y*bf.w;
            acc[2][0] += af.z*bf.x; acc[2][1] += af.z*bf.y; acc[2][2] += af.z*bf.z; acc[2][3] += af.z*bf.w;
            acc[3][0] += af.w*bf.x; acc[3][1] += af.w*bf.y; acc[3][2] += af.w*bf.z; acc[3][3] += af.w*bf.w;
        }
    }

    // direct block (c = i from ti-range, t = j from tj-range)
    #pragma unroll
    for(int a = 0; a < 4; a++){
        int i = ti*GTILE + 4*ty + a;
        size_t ibase = (size_t)(i >> 2)*1280 + (i & 3);
        #pragma unroll
        for(int c = 0; c < 4; c++){
            int j = tj*GTILE + 4*tx + c;
            float val = (i < nsc && j < nsc) ? acc[a][c] : 0.f;
            G[ibase + 4*j] = val;
        }
    }
    // mirror block (c = j, t = i) — G symmetric
    if(ti != tj){
        #pragma unroll
        for(int a = 0; a < 4; a++){
            int i = ti*GTILE + 4*ty + a;
            #pragma unroll
            for(int c = 0; c < 4; c++){
                int j = tj*GTILE + 4*tx + c;
                float val = (i < nsc && j < nsc) ? acc[a][c] : 0.f;
                G[(size_t)(j >> 2)*1280 + 4*i + (j & 3)] = val;
            }
        }
    }
}

// ---------------------------------------------------------------------------
// Kernel 3: coefficient-space CG. Thread t owns coefficient t; the Gram
// matvec is a coalesced column-sweep (float4 along c via interleaved G),
// output stays in registers — no shuffle reduces, no staging, no barriers
// inside the matvec. One fused 5-way reduction per CG iteration.
// ---------------------------------------------------------------------------
__global__ __launch_bounds__(512) void k_cgc(
        const float* __restrict__ X, const float* __restrict__ G0,
        const int* __restrict__ sup_idx, const int* __restrict__ sup_lab,
        const int* __restrict__ counts, const float* __restrict__ row_sums,
        float* __restrict__ vout)
{
    const int sys  = blockIdx.x;
    const int b    = sys >> 1;
    const int cls  = sys & 1;
    const int tid  = threadIdx.x;
    const int lane = tid & 63;
    const int wave = tid >> 6;

    __shared__ __align__(16) float u[NS_CAP];
    __shared__ int   idx_l[NS_CAP];
    __shared__ float redA[8][5];
    __shared__ float redB[8];

    const int ns   = counts[b*4 + 0];
    const int nsc  = min(ns, NS_CAP);
    const int ncls = cls ? counts[b*4 + 2] : counts[b*4 + 3];
    const float c_task = 0.9f / (float)(ns - 1);
    const float c_cls  = 0.1f / (float)(ncls - 1);
    const float inv_ns = 1.f / (float)ns;
    const float inv_nc = 1.f / (float)ncls;
    const float4* G4 = (const float4*)(G0 + (size_t)b * NS_CAP * NS_CAP);
    const float4* u4 = (const float4*)u;

    const bool own = tid < nsc;
    const bool mth = tid < NS_CAP;
    float mfl = 0.f, sraw = 0.f;
    if(own){
        mfl  = (sup_lab[b*LPAD + tid] == cls) ? 1.f : 0.f;
        sraw = row_sums[b*LPAD + tid];
    }
    for(int s = tid; s < nsc; s += 512) idx_l[s] = sup_idx[b*LPAD + s];

    auto reduce1 = [&](float v) -> float {
        #pragma unroll
        for(int off = 32; off; off >>= 1) v += __shfl_xor(v, off);
        __syncthreads();
        if(lane == 0) redB[wave] = v;
        __syncthreads();
        float s = 0.f;
        #pragma unroll
        for(int w = 0; w < 8; w++) s += redB[w];
        return s;
    };
    auto reduce5 = [&](float v0, float v1, float v2, float v3, float v4,
                       float* out){
        #pragma unroll
        for(int off = 32; off; off >>= 1){
            v0 += __shfl_xor(v0, off); v1 += __shfl_xor(v1, off);
            v2 += __shfl_xor(v2, off); v3 += __shfl_xor(v3, off);
            v4 += __shfl_xor(v4, off);
        }
        __syncthreads();
        if(lane == 0){
            redA[wave][0] = v0; redA[wave][1] = v1; redA[wave][2] = v2;
            redA[wave][3] = v3; redA[wave][4] = v4;
        }
        __syncthreads();
        #pragma unroll
        for(int k = 0; k < 5; k++){
            float s = 0.f;
            #pragma unroll
            for(int w = 0; w < 8; w++) s += redA[w][k];
            out[k] = s;
        }
    };
    // tq[tid] = sum_c u[c] * G(c, tid).  Requires u published + barrier.
    auto matvec = [&]() -> float {
        float s0 = 0.f, s1 = 0.f, s2 = 0.f, s3 = 0.f;
        if(mth){
            const int nf4 = (nsc + 3) >> 2;
            int c4 = 0;
            for(; c4 + 4 <= nf4; c4 += 4){
                float4 g0 = G4[(size_t)(c4+0)*NS_CAP + tid];
                float4 g1 = G4[(size_t)(c4+1)*NS_CAP + tid];
                float4 g2 = G4[(size_t)(c4+2)*NS_CAP + tid];
                float4 g3 = G4[(size_t)(c4+3)*NS_CAP + tid];
                float4 w0 = u4[c4+0], w1 = u4[c4+1], w2 = u4[c4+2], w3 = u4[c4+3];
                s0 += g0.x*w0.x + g0.y*w0.y + g0.z*w0.z + g0.w*w0.w;
                s1 += g1.x*w1.x + g1.y*w1.y + g1.z*w1.z + g1.w*w1.w;
                s2 += g2.x*w2.x + g2.y*w2.y + g2.z*w2.z + g2.w*w2.w;
                s3 += g3.x*w3.x + g3.y*w3.y + g3.z*w3.z + g3.w*w3.w;
            }
            for(; c4 < nf4; c4++){
                float4 g = G4[(size_t)c4*NS_CAP + tid];
                float4 w = u4[c4];
                s0 += g.x*w.x + g.y*w.y + g.z*w.z + g.w*w.w;
            }
        }
        return (s0 + s1) + (s2 + s3);
    };

    // init: r0 = -10 * A * 1  (t-image of p=1_D is the row-sum vector)
    float out5[5];
    reduce5(sraw, mfl * sraw, 0.f, 0.f, 0.f, out5);
    float A0 = out5[0] * inv_ns, A1 = out5[1] * inv_nc;
    float cr = own ? -10.f * (c_task*(sraw - A0) + mfl*c_cls*(sraw - A1)) : 0.f;
    if(mth) u[tid] = cr;
    __syncthreads();
    float tr = matvec();
    float rr = reduce1(cr * tr);
    float cp = cr, tpv = tr, cx = 0.f;

    for(int it = 0; it < CG_ITERS; ++it){
        // S1=Σtp, S2=Σm·tp, S3=Σtp², S4=Σm·tp², S5=Σtp·cp
        reduce5(tpv, mfl*tpv, tpv*tpv, mfl*tpv*tpv, tpv*cp, out5);
        A0 = out5[0] * inv_ns; A1 = out5[1] * inv_nc;
        float pq = 0.1f*out5[4] + c_task*(out5[2] - out5[0]*A0)
                                + c_cls *(out5[3] - out5[1]*A1);
        float ui = own ? (c_task*(tpv - A0) + mfl*c_cls*(tpv - A1)) : 0.f;
        float qc = 0.1f*cp + ui;               // c_q = 0.1 c_p + u
        if(mth) u[tid] = ui;
        __syncthreads();
        float gv = matvec();                   // G0 * u
        float tqf = 0.1f*tpv + gv;             // t_q
        float alpha = rr / pq;
        cx += alpha * cp;
        cr -= alpha * qc;
        tr -= alpha * tqf;
        float rrn = reduce1(cr * tr);
        float beta = rrn / rr;
        rr = rrn;
        cp  = cr + beta * cp;
        tpv = tr + beta * tpv;
        if(rr < 1e-26f) break;                 // uniform across block
    }

    // v = 10*1 + Xs^T c_x  (thread owns dim tid; 8 independent loads deep)
    if(mth) u[tid] = cx;
    __syncthreads();
    float v = 10.f;
    int s = 0;
    for(; s + 8 <= nsc; s += 8){
        #pragma unroll
        for(int k = 0; k < 8; k++)
            v += u[s+k] * X[(size_t)idx_l[s+k]*DDIM + tid];
    }
    for(; s < nsc; s++) v += u[s] * X[(size_t)idx_l[s]*DDIM + tid];
    vout[(size_t)sys * DDIM + tid] = v;
}

// ---------------------------------------------------------------------------
// Fallback kernel (D-space CG) if workspace is too small for G0.
// ---------------------------------------------------------------------------
__global__ __launch_bounds__(512) void k_cg(
        const float* __restrict__ X,
        const int* __restrict__ sup_idx, const int* __restrict__ sup_lab,
        const int* __restrict__ counts,
        const float* __restrict__ task_mean, const float* __restrict__ pos_mean,
        const float* __restrict__ neg_mean,
        float* __restrict__ vout)
{
    const int sys  = blockIdx.x;
    const int b    = sys >> 1;
    const int cls  = sys & 1;
    const int tid  = threadIdx.x;
    const int lane = tid & 63;
    const int wave = tid >> 6;
    const int d    = tid;

    __shared__ float xs[CHUNK][DDIM];
    __shared__ float p_lds[DDIM];
    __shared__ float w_lds[CHUNK];
    __shared__ int   lab_lds[CHUNK];
    __shared__ int   idx_lds[CHUNK];
    __shared__ float red1[8];
    __shared__ float red2[8][2];

    const int ns   = counts[b*4 + 0];
    const int ncls = cls ? counts[b*4 + 2] : counts[b*4 + 3];
    const float c_task = 0.9f / (float)(ns - 1);
    const float c_cls  = 0.1f / (float)(ncls - 1);
    const float mu_d    = task_mean[b*DDIM + d];
    const float mucls_d = cls ? pos_mean[b*DDIM + d] : neg_mean[b*DDIM + d];

    auto blockReduce = [&](float v) -> float {
        #pragma unroll
        for(int off = 32; off; off >>= 1) v += __shfl_xor(v, off);
        __syncthreads();
        if(lane == 0) red1[wave] = v;
        __syncthreads();
        float s = 0.f;
        #pragma unroll
        for(int w = 0; w < 8; w++) s += red1[w];
        return s;
    };
    auto matvec = [&](float pd_reg) -> float {
        float part0 = mu_d * pd_reg, part1 = mucls_d * pd_reg;
        #pragma unroll
        for(int off = 32; off; off >>= 1){
            part0 += __shfl_xor(part0, off);
            part1 += __shfl_xor(part1, off);
        }
        __syncthreads();
        if(lane == 0){ red2[wave][0] = part0; red2[wave][1] = part1; }
        __syncthreads();
        float a0 = 0.f, a1 = 0.f;
        #pragma unroll
        for(int w = 0; w < 8; w++){ a0 += red2[w][0]; a1 += red2[w][1]; }
        float preg[8];
        #pragma unroll
        for(int k = 0; k < 8; k++) preg[k] = p_lds[lane + 64*k];
        float q = 0.1f * pd_reg;
        for(int cs = 0; cs < ns; cs += CHUNK){
            int nrows = min(CHUNK, ns - cs);
            __syncthreads();
            if(tid < nrows){
                idx_lds[tid] = sup_idx[b * LPAD + cs + tid];
                lab_lds[tid] = sup_lab[b * LPAD + cs + tid];
            }
            __syncthreads();
            for(int f = tid; f < nrows * 128; f += 512){
                int r  = f >> 7;
                int c4 = f & 127;
                const float4* src = (const float4*)(X + (size_t)idx_lds[r] * DDIM);
                ((float4*)&xs[r][0])[c4] = src[c4];
            }
            __syncthreads();
            for(int r = wave; r < nrows; r += 8){
                float t = 0.f;
                #pragma unroll
                for(int k = 0; k < 8; k++) t += xs[r][lane + 64*k] * preg[k];
                #pragma unroll
                for(int off = 32; off; off >>= 1) t += __shfl_xor(t, off);
                if(lane == 0){
                    int lm = (lab_lds[r] == cls) ? 1 : 0;
                    w_lds[r] = c_task * (t - a0) + (lm ? c_cls * (t - a1) : 0.f);
                }
            }
            __syncthreads();
            for(int r = 0; r < nrows; r++) q += w_lds[r] * xs[r][d];
        }
        return q;
    };

    float xv = 10.0f;
    float pd = 10.0f;
    p_lds[d] = pd;
    __syncthreads();
    float qd = matvec(pd);
    float rd = 1.0f - qd;
    pd = rd;
    float rr = blockReduce(rd * rd);
    __syncthreads();
    p_lds[d] = pd;
    __syncthreads();

    for(int it = 0; it < CG_ITERS_FB; it++){
        if(rr < 1e-30f) break;
        qd = matvec(pd);
        float pq = blockReduce(pd * qd);
        float alpha = rr / pq;
        xv += alpha * pd;
        rd -= alpha * qd;
        float rr_new = blockReduce(rd * rd);
        float beta = rr_new / rr;
        rr = rr_new;
        pd = rd + beta * pd;
        __syncthreads();
        p_lds[d] = pd;
        __syncthreads();
    }
    vout[(size_t)(b*2 + cls) * DDIM + d] = xv;
}

// ---------------------------------------------------------------------------
// Kernel 4: per-query output (unchanged).
// ---------------------------------------------------------------------------
__global__ __launch_bounds__(256) void k_out(
        const float* __restrict__ X,
        const int* __restrict__ qry_idx, const int* __restrict__ counts,
        const float* __restrict__ pos_mean, const float* __restrict__ neg_mean,
        const float* __restrict__ vsol, const float* __restrict__ log_scale,
        float* __restrict__ out)
{
    const int b    = blockIdx.x;
    const int tid  = threadIdx.x;
    const int lane = tid & 63;
    const int wave = tid >> 6;

    __shared__ float vpos[DDIM], vneg[DDIM];
    __shared__ float red4[4][4];
    __shared__ float sc[4];

    const int nq  = counts[b*4 + 1];
    const int nqc = min(nq, LPAD);
    const float scale = expf(log_scale[0]);

    float pm0 = pos_mean[b*DDIM + tid], pm1 = pos_mean[b*DDIM + tid + 256];
    float nm0 = neg_mean[b*DDIM + tid], nm1 = neg_mean[b*DDIM + tid + 256];
    float vp0 = vsol[(size_t)(b*2 + 1) * DDIM + tid];
    float vp1 = vsol[(size_t)(b*2 + 1) * DDIM + tid + 256];
    float vn0 = vsol[(size_t)(b*2 + 0) * DDIM + tid];
    float vn1 = vsol[(size_t)(b*2 + 0) * DDIM + tid + 256];
    vpos[tid] = vp0; vpos[tid + 256] = vp1;
    vneg[tid] = vn0; vneg[tid + 256] = vn1;

    float smp = pm0 + pm1;
    float smn = nm0 + nm1;
    float mvp = pm0 * vp0 + pm1 * vp1;
    float mvn = nm0 * vn0 + nm1 * vn1;
    #pragma unroll
    for(int off = 32; off; off >>= 1){
        smp += __shfl_xor(smp, off);
        smn += __shfl_xor(smn, off);
        mvp += __shfl_xor(mvp, off);
        mvn += __shfl_xor(mvn, off);
    }
    if(lane == 0){
        red4[wave][0] = smp; red4[wave][1] = smn;
        red4[wave][2] = mvp; red4[wave][3] = mvn;
    }
    __syncthreads();
    if(tid < 4) sc[tid] = red4[0][tid] + red4[1][tid] + red4[2][tid] + red4[3][tid];
    __syncthreads();

    for(int r = wave; r < nqc; r += 4){
        int n = qry_idx[b * LPAD + r];
        float tp = 0.f, tn = 0.f, sx = 0.f;
        #pragma unroll
        for(int k = 0; k < 8; k++){
            float x = X[(size_t)n * DDIM + lane + 64*k];
            tp += x * vpos[lane + 64*k];
            tn += x * vneg[lane + 64*k];
            sx += x;
        }
        #pragma unroll
        for(int off = 32; off; off >>= 1){
            tp += __shfl_xor(tp, off);
            tn += __shfl_xor(tn, off);
            sx += __shfl_xor(sx, off);
        }
        if(lane == 0){
            float mp = (tp - sc[2]) * (sx - sc[0]);
            float mn = (tn - sc[3]) * (sx - sc[1]);
            ((float2*)out)[(size_t)b * LPAD + r] = make_float2(mn * scale, mp * scale);
        }
    }
    for(int r = nqc + tid; r < LPAD; r += 256)
        ((float2*)out)[(size_t)b * LPAD + r] = make_float2(0.f, 0.f);
}

// ---------------------------------------------------------------------------
extern "C" void kernel_launch(void* const* d_in, const int* in_sizes, int n_in,
                              void* d_out, int out_size, void* d_ws, size_t ws_size,
                              hipStream_t stream)
{
    const float* X         = (const float*)d_in[0];
    const float* log_scale = (const float*)d_in[1];
    const int*   labels    = (const int*)d_in[2];
    const int*   is_query  = (const int*)d_in[3];
    const int*   bidx      = (const int*)d_in[4];
    const int N = in_sizes[2];

    char* ws = (char*)d_ws;
    auto alloc = [&](size_t bytes) -> char* {
        char* p = ws;
        ws += (bytes + 255) & ~(size_t)255;
        return p;
    };
    int*   sup_idx   = (int*)  alloc((size_t)EPISODES * LPAD * sizeof(int));
    int*   qry_idx   = (int*)  alloc((size_t)EPISODES * LPAD * sizeof(int));
    int*   sup_lab   = (int*)  alloc((size_t)EPISODES * LPAD * sizeof(int));
    int*   counts    = (int*)  alloc((size_t)EPISODES * 4 * sizeof(int));
    float* task_mean = (float*)alloc((size_t)EPISODES * DDIM * sizeof(float));
    float* pos_mean  = (float*)alloc((size_t)EPISODES * DDIM * sizeof(float));
    float* neg_mean  = (float*)alloc((size_t)EPISODES * DDIM * sizeof(float));
    float* vsol      = (float*)alloc((size_t)EPISODES * 2 * DDIM * sizeof(float));
    float* row_sums  = (float*)alloc((size_t)EPISODES * LPAD * sizeof(float));
    float* G0        = (float*)alloc((size_t)EPISODES * NS_CAP * NS_CAP * sizeof(float));
    const size_t used = (size_t)(ws - (char*)d_ws);
    const bool fits = used <= ws_size;         // constant per process -> graph-safe

    k_gather<<<EPISODES, 256, 0, stream>>>(labels, is_query, bidx, X, N,
                                           sup_idx, qry_idx, sup_lab, counts,
                                           task_mean, pos_mean, neg_mean, row_sums);
    if(fits){
        k_gram<<<EPISODES * NPAIRS, 256, 0, stream>>>(X, sup_idx, counts, G0);
        k_cgc<<<EPISODES * 2, 512, 0, stream>>>(X, G0, sup_idx, sup_lab, counts,
                                                row_sums, vsol);
    } else {
        k_cg<<<EPISODES * 2, 512, 0, stream>>>(X, sup_idx, sup_lab, counts,
                                               task_mean, pos_mean, neg_mean, vsol);
    }
    k_out<<<EPISODES, 256, 0, stream>>>(X, qry_idx, counts, pos_mean, neg_mean,
                                        vsol, log_scale, (float*)d_out);
}

// Round 5
// 598.335 us; speedup vs baseline: 1.4770x; 1.0083x over previous
//
#include <hip/hip_runtime.h>
#include <cstdint>
#include <cstddef>

#define EPISODES 128
#define LPAD     512
#define DDIM     512
#define NS_CAP   320
#define GTILE    64
#define NPAIRS   15          // 5*(5+1)/2 tile pairs (NS_CAP/GTILE = 5)
#define CG_ITERS 24
#define CGC_NTH  960         // 3 phases x 320 coefficients
#define NWAVE    15

__device__ __forceinline__ int lower_bound_dev(const int* __restrict__ a, int n, int key){
    int lo = 0, hi = n;
    while(lo < hi){
        int m = (lo + hi) >> 1;
        if(a[m] < key) lo = m + 1; else hi = m;
    }
    return lo;
}

// ---------------------------------------------------------------------------
// Kernel 1a: per-episode segmentation + gather of indices/labels + counts.
// One WG (256 thr) per episode; batch_index sorted -> ballot prefix-scan.
// ---------------------------------------------------------------------------
__global__ __launch_bounds__(256) void k_seg(
        const int* __restrict__ labels, const int* __restrict__ is_query,
        const int* __restrict__ bidx, int N,
        int* __restrict__ sup_idx, int* __restrict__ qry_idx,
        int* __restrict__ sup_lab, int* __restrict__ counts)
{
    const int b    = blockIdx.x;
    const int tid  = threadIdx.x;
    const int lane = tid & 63;
    const int wave = tid >> 6;

    __shared__ int s_start, s_end;
    __shared__ int wq[4];
    __shared__ int s_runq, s_npos;

    if(tid == 0){
        s_start = lower_bound_dev(bidx, N, b);
        s_end   = lower_bound_dev(bidx, N, b + 1);
        s_runq  = 0;
        s_npos  = 0;
    }
    __syncthreads();
    const int start = s_start, end = s_end;

    for(int base = start; base < end; base += 256){
        int idx   = base + tid;
        bool valid = idx < end;
        int q   = valid ? is_query[idx] : 0;
        int lab = valid ? labels[idx]   : 0;
        unsigned long long m = __ballot(q == 1);
        if(lane == 0) wq[wave] = __popcll(m);
        __syncthreads();
        int woff = 0;
        for(int w = 0; w < wave; w++) woff += wq[w];
        int qbefore = __popcll(m & ((1ull << lane) - 1ull)) + woff;
        int runq0 = s_runq;
        int chunk_total = wq[0] + wq[1] + wq[2] + wq[3];
        if(valid){
            int pos_in_seg = idx - start;
            if(q){
                int qr = runq0 + qbefore;
                if(qr < LPAD) qry_idx[b * LPAD + qr] = idx;
            } else {
                int sr = pos_in_seg - runq0 - qbefore;
                if(sr < LPAD){
                    sup_idx[b * LPAD + sr] = idx;
                    sup_lab[b * LPAD + sr] = lab;
                    if(lab == 1) atomicAdd(&s_npos, 1);
                }
            }
        }
        __syncthreads();
        if(tid == 0) s_runq = runq0 + chunk_total;
        __syncthreads();
    }

    if(tid == 0){
        int nq = s_runq;
        int ns = (end - start) - nq;
        counts[b*4 + 0] = ns;
        counts[b*4 + 1] = nq;
        counts[b*4 + 2] = s_npos;
        counts[b*4 + 3] = ns - s_npos;
    }
}

// ---------------------------------------------------------------------------
// Kernel 1b: per-episode means + support row sums.  2 WGs per episode:
// WG h owns dim half [h*256,(h+1)*256) for means and row half for rowsums.
// ---------------------------------------------------------------------------
__global__ __launch_bounds__(256) void k_stats(
        const float* __restrict__ X,
        const int* __restrict__ sup_idx, const int* __restrict__ sup_lab,
        const int* __restrict__ counts,
        float* __restrict__ task_mean, float* __restrict__ pos_mean,
        float* __restrict__ neg_mean, float* __restrict__ row_sums)
{
    const int bid  = blockIdx.x;
    const int b    = bid >> 1;
    const int h    = bid & 1;
    const int tid  = threadIdx.x;
    const int lane = tid & 63;
    const int wave = tid >> 6;

    __shared__ int sidx[NS_CAP];
    __shared__ int slab[NS_CAP];

    const int ns   = counts[b*4 + 0];
    const int npos = counts[b*4 + 2];
    const int nneg = counts[b*4 + 3];
    const int nsb  = min(ns, NS_CAP);

    for(int s = tid; s < nsb; s += 256){
        sidx[s] = sup_idx[b*LPAD + s];
        slab[s] = sup_lab[b*LPAD + s];
    }
    __syncthreads();

    // Means for dim d = h*256 + tid (8-deep independent row loads).
    const int d = h*256 + tid;
    float sa = 0.f, sp = 0.f;
    int s = 0;
    for(; s + 8 <= nsb; s += 8){
        #pragma unroll
        for(int k = 0; k < 8; k++){
            int n   = sidx[s + k];
            float l = (float)slab[s + k];
            float x = X[(size_t)n * DDIM + d];
            sa += x; sp += l * x;
        }
    }
    for(; s < nsb; s++){
        float x = X[(size_t)sidx[s] * DDIM + d];
        sa += x; sp += (float)slab[s] * x;
    }
    float sn = sa - sp;
    task_mean[b*DDIM + d] = sa / (float)ns;
    pos_mean [b*DDIM + d] = sp / (float)npos;
    neg_mean [b*DDIM + d] = sn / (float)nneg;

    // Row sums for row half [r0, r1): one wave per 2 rows interleaved.
    const int r0 = (nsb * h) >> 1;
    const int r1 = (nsb * (h + 1)) >> 1;
    for(int r = r0 + wave; r < r1; r += 8){
        int rb = r + 4;
        int n0 = sidx[r];
        int n1 = (rb < r1) ? sidx[rb] : n0;
        float s0 = 0.f, s1 = 0.f;
        #pragma unroll
        for(int k = 0; k < 8; k++){
            s0 += X[(size_t)n0 * DDIM + lane + 64*k];
            s1 += X[(size_t)n1 * DDIM + lane + 64*k];
        }
        #pragma unroll
        for(int off = 32; off; off >>= 1){
            s0 += __shfl_xor(s0, off);
            s1 += __shfl_xor(s1, off);
        }
        if(lane == 0){
            row_sums[b * LPAD + r] = s0;
            if(rb < r1) row_sums[b * LPAD + rb] = s1;
        }
    }
}

// ---------------------------------------------------------------------------
// Kernel 2: raw support Gram in interleaved layout for the matvec:
//   element (c,t) of G0 lives at  G[(c>>2)*1280 + 4*t + (c&3)]
// so thread t in k_cgc reads float4 { G(4c4..4c4+3, t) } at G4[c4*320 + t]
// fully coalesced. Zero-padded to NS_CAP in both indices.
// ---------------------------------------------------------------------------
__global__ __launch_bounds__(256) void k_gram(
        const float* __restrict__ X, const int* __restrict__ sup_idx,
        const int* __restrict__ counts, float* __restrict__ G0)
{
    const int bid = blockIdx.x;
    const int b   = bid / NPAIRS;
    int tp = bid % NPAIRS;
    int ti = 0;
    while((ti+1)*(ti+2)/2 <= tp) ti++;
    const int tj  = tp - ti*(ti+1)/2;          // ti >= tj
    const int tid = threadIdx.x;
    const int ty  = tid >> 4, tx = tid & 15;

    const int ns  = counts[b*4 + 0];
    const int nsc = min(ns, NS_CAP);
    float* G = G0 + (size_t)b * NS_CAP * NS_CAP;

    // fast path: tile entirely in the zero-padding region
    if(ti * GTILE >= nsc){
        #pragma unroll
        for(int t = 0; t < 4; t++){
            int f = tid + t*256; int rr = f >> 4; int cc = f & 15;
            int c  = ti*GTILE + rr;
            int j0 = tj*GTILE + 4*cc;
            size_t base = (size_t)(c >> 2)*1280 + (c & 3);
            G[base + 4*(j0+0)] = 0.f; G[base + 4*(j0+1)] = 0.f;
            G[base + 4*(j0+2)] = 0.f; G[base + 4*(j0+3)] = 0.f;
            if(ti != tj){
                int c2 = tj*GTILE + rr;
                int j2 = ti*GTILE + 4*cc;
                size_t base2 = (size_t)(c2 >> 2)*1280 + (c2 & 3);
                G[base2 + 4*(j2+0)] = 0.f; G[base2 + 4*(j2+1)] = 0.f;
                G[base2 + 4*(j2+2)] = 0.f; G[base2 + 4*(j2+3)] = 0.f;
            }
        }
        return;
    }

    __shared__ float Sb[64*68];                // Ast[32][68]+Bst[32][68]
    __shared__ int ia[GTILE], ib[GTILE];
    float* Ast = Sb;
    float* Bst = Sb + 32*68;

    if(tid < GTILE)            ia[tid]      = sup_idx[b*LPAD + min(ti*GTILE + tid,        nsc-1)];
    else if(tid < 2*GTILE)     ib[tid - 64] = sup_idx[b*LPAD + min(tj*GTILE + (tid - 64), nsc-1)];

    float acc[4][4];
    #pragma unroll
    for(int a = 0; a < 4; a++)
        #pragma unroll
        for(int c = 0; c < 4; c++) acc[a][c] = 0.f;

    for(int k0 = 0; k0 < DDIM; k0 += 32){
        __syncthreads();                       // Sb free (covers ia/ib at k0=0)
        #pragma unroll
        for(int t = 0; t < 2; t++){
            int f   = tid + t*256;
            int row = f >> 3, c4 = f & 7;
            float4 xa = *(const float4*)(X + (size_t)ia[row]*DDIM + k0 + 4*c4);
            float4 xb = *(const float4*)(X + (size_t)ib[row]*DDIM + k0 + 4*c4);
            Ast[(4*c4+0)*68 + row] = xa.x;
            Ast[(4*c4+1)*68 + row] = xa.y;
            Ast[(4*c4+2)*68 + row] = xa.z;
            Ast[(4*c4+3)*68 + row] = xa.w;
            Bst[(4*c4+0)*68 + row] = xb.x;
            Bst[(4*c4+1)*68 + row] = xb.y;
            Bst[(4*c4+2)*68 + row] = xb.z;
            Bst[(4*c4+3)*68 + row] = xb.w;
        }
        __syncthreads();
        #pragma unroll 8
        for(int k = 0; k < 32; k++){
            float4 af = *(const float4*)&Ast[k*68 + 4*ty];
            float4 bf = *(const float4*)&Bst[k*68 + 4*tx];
            acc[0][0] += af.x*bf.x; acc[0][1] += af.x*bf.y; acc[0][2] += af.x*bf.z; acc[0][3] += af.x*bf.w;
            acc[1][0] += af.y*bf.x; acc[1][1] += af.y*bf.y; acc[1][2] += af.y*bf.z; acc[1][3] += af.y*bf.w;
            acc[2][0] += af.z*bf.x; acc[2][1] += af.z*bf.y; acc[2][2] += af.z*bf.z; acc[2][3] += af.z*bf.w;
            acc[3][0] += af.w*bf.x; acc[3][1] += af.w*bf.y; acc[3][2] += af.w*bf.z; acc[3][3] += af.w*bf.w;
        }
    }

    // direct block (c = i from ti-range, t = j from tj-range)
    #pragma unroll
    for(int a = 0; a < 4; a++){
        int i = ti*GTILE + 4*ty + a;
        size_t ibase = (size_t)(i >> 2)*1280 + (i & 3);
        #pragma unroll
        for(int c = 0; c < 4; c++){
            int j = tj*GTILE + 4*tx + c;
            float val = (i < nsc && j < nsc) ? acc[a][c] : 0.f;
            G[ibase + 4*j] = val;
        }
    }
    // mirror block (c = j, t = i) — G symmetric
    if(ti != tj){
        #pragma unroll
        for(int a = 0; a < 4; a++){
            int i = ti*GTILE + 4*ty + a;
            #pragma unroll
            for(int c = 0; c < 4; c++){
                int j = tj*GTILE + 4*tx + c;
                float val = (i < nsc && j < nsc) ? acc[a][c] : 0.f;
                G[(size_t)(j >> 2)*1280 + 4*i + (j & 3)] = val;
            }
        }
    }
}

// ---------------------------------------------------------------------------
// Kernel 3: coefficient-space CG. 960 threads = 3 phases x 320 coefficients;
// phase p sweeps Gram columns c4 ≡ p (mod 3), partials combined via LDS.
// 15 waves/CU for latency hiding; coalesced float4 column sweep; one fused
// 5-way reduction per CG iteration.
// ---------------------------------------------------------------------------
__global__ __launch_bounds__(CGC_NTH) void k_cgc(
        const float* __restrict__ X, const float* __restrict__ G0,
        const int* __restrict__ sup_idx, const int* __restrict__ sup_lab,
        const int* __restrict__ counts, const float* __restrict__ row_sums,
        float* __restrict__ vout)
{
    const int sys  = blockIdx.x;
    const int b    = sys >> 1;
    const int cls  = sys & 1;
    const int tid  = threadIdx.x;
    const int lane = tid & 63;
    const int wave = tid >> 6;
    const int phase = wave / 5;                // waves 0-4: ph0, 5-9: ph1, 10-14: ph2
    const int t     = tid - phase * NS_CAP;    // coefficient index within phase

    __shared__ __align__(16) float u[NS_CAP];
    __shared__ float part[2][NS_CAP];
    __shared__ int   idx_l[NS_CAP];
    __shared__ float redA[NWAVE][5];
    __shared__ float redB[NWAVE];

    const int ns   = counts[b*4 + 0];
    const int nsc  = min(ns, NS_CAP);
    const int ncls = cls ? counts[b*4 + 2] : counts[b*4 + 3];
    const float c_task = 0.9f / (float)(ns - 1);
    const float c_cls  = 0.1f / (float)(ncls - 1);
    const float inv_ns = 1.f / (float)ns;
    const float inv_nc = 1.f / (float)ncls;
    const float4* G4 = (const float4*)(G0 + (size_t)b * NS_CAP * NS_CAP);
    const float4* u4 = (const float4*)u;
    const int nf4 = (nsc + 3) >> 2;

    const bool mth = tid < NS_CAP;             // phase-0 threads own coefficients
    const bool own = tid < nsc;
    float mfl = 0.f, sraw = 0.f;
    if(own){
        mfl  = (sup_lab[b*LPAD + tid] == cls) ? 1.f : 0.f;
        sraw = row_sums[b*LPAD + tid];
    }
    for(int s = tid; s < nsc; s += CGC_NTH) idx_l[s] = sup_idx[b*LPAD + s];

    auto reduce1 = [&](float v) -> float {
        #pragma unroll
        for(int off = 32; off; off >>= 1) v += __shfl_xor(v, off);
        __syncthreads();
        if(lane == 0) redB[wave] = v;
        __syncthreads();
        float s = 0.f;
        #pragma unroll
        for(int w = 0; w < NWAVE; w++) s += redB[w];
        return s;
    };
    auto reduce5 = [&](float v0, float v1, float v2, float v3, float v4,
                       float* out){
        #pragma unroll
        for(int off = 32; off; off >>= 1){
            v0 += __shfl_xor(v0, off); v1 += __shfl_xor(v1, off);
            v2 += __shfl_xor(v2, off); v3 += __shfl_xor(v3, off);
            v4 += __shfl_xor(v4, off);
        }
        __syncthreads();
        if(lane == 0){
            redA[wave][0] = v0; redA[wave][1] = v1; redA[wave][2] = v2;
            redA[wave][3] = v3; redA[wave][4] = v4;
        }
        __syncthreads();
        #pragma unroll
        for(int k = 0; k < 5; k++){
            float s = 0.f;
            #pragma unroll
            for(int w = 0; w < NWAVE; w++) s += redA[w][k];
            out[k] = s;
        }
    };
    // result on phase-0 threads: tq[t] = sum_c u[c] * G(c,t); others return 0.
    // Requires u published + barrier before call.
    auto matvec = [&]() -> float {
        float s0 = 0.f, s1 = 0.f, s2 = 0.f, s3 = 0.f;
        int c4 = phase;
        for(; c4 + 9 < nf4; c4 += 12){
            float4 g0 = G4[(size_t)(c4+0)*NS_CAP + t];
            float4 g1 = G4[(size_t)(c4+3)*NS_CAP + t];
            float4 g2 = G4[(size_t)(c4+6)*NS_CAP + t];
            float4 g3 = G4[(size_t)(c4+9)*NS_CAP + t];
            float4 w0 = u4[c4+0], w1 = u4[c4+3], w2 = u4[c4+6], w3 = u4[c4+9];
            s0 += g0.x*w0.x + g0.y*w0.y + g0.z*w0.z + g0.w*w0.w;
            s1 += g1.x*w1.x + g1.y*w1.y + g1.z*w1.z + g1.w*w1.w;
            s2 += g2.x*w2.x + g2.y*w2.y + g2.z*w2.z + g2.w*w2.w;
            s3 += g3.x*w3.x + g3.y*w3.y + g3.z*w3.z + g3.w*w3.w;
        }
        for(; c4 < nf4; c4 += 3){
            float4 g = G4[(size_t)c4*NS_CAP + t];
            float4 w = u4[c4];
            s0 += g.x*w.x + g.y*w.y + g.z*w.z + g.w*w.w;
        }
        float s = (s0 + s1) + (s2 + s3);
        if(phase > 0) part[phase - 1][t] = s;
        __syncthreads();
        float r = 0.f;
        if(phase == 0) r = s + part[0][t] + part[1][t];
        return r;
    };

    // init: r0 = -10 * A * 1  (t-image of p=1_D is the row-sum vector)
    float out5[5];
    reduce5(sraw, mfl * sraw, 0.f, 0.f, 0.f, out5);
    float A0 = out5[0] * inv_ns, A1 = out5[1] * inv_nc;
    float cr = own ? -10.f * (c_task*(sraw - A0) + mfl*c_cls*(sraw - A1)) : 0.f;
    if(mth) u[tid] = cr;
    __syncthreads();
    float tr = matvec();
    float rr = reduce1(cr * tr);
    float cp = cr, tpv = tr, cx = 0.f;

    for(int it = 0; it < CG_ITERS; ++it){
        // S1=Σtp, S2=Σm·tp, S3=Σtp², S4=Σm·tp², S5=Σtp·cp
        reduce5(tpv, mfl*tpv, tpv*tpv, mfl*tpv*tpv, tpv*cp, out5);
        A0 = out5[0] * inv_ns; A1 = out5[1] * inv_nc;
        float pq = 0.1f*out5[4] + c_task*(out5[2] - out5[0]*A0)
                                + c_cls *(out5[3] - out5[1]*A1);
        float ui = own ? (c_task*(tpv - A0) + mfl*c_cls*(tpv - A1)) : 0.f;
        float qc = 0.1f*cp + ui;               // c_q = 0.1 c_p + u
        if(mth) u[tid] = ui;
        __syncthreads();
        float gv = matvec();                   // G0 * u (phase-0 holds result)
        float tqf = 0.1f*tpv + gv;             // t_q
        float alpha = rr / pq;
        cx += alpha * cp;
        cr -= alpha * qc;
        tr -= alpha * tqf;
        float rrn = reduce1(cr * tr);
        float beta = rrn / rr;
        rr = rrn;
        cp  = cr + beta * cp;
        tpv = tr + beta * tpv;
        if(rr < 1e-26f) break;                 // uniform across block
    }

    // v = 10*1 + Xs^T c_x  (threads 0..511 own dims; 8 independent loads deep)
    if(mth) u[tid] = own ? cx : 0.f;
    __syncthreads();
    if(tid < DDIM){
        float v = 10.f;
        int s = 0;
        for(; s + 8 <= nsc; s += 8){
            #pragma unroll
            for(int k = 0; k < 8; k++)
                v += u[s+k] * X[(size_t)idx_l[s+k]*DDIM + tid];
        }
        for(; s < nsc; s++) v += u[s] * X[(size_t)idx_l[s]*DDIM + tid];
        vout[(size_t)sys * DDIM + tid] = v;
    }
}

// ---------------------------------------------------------------------------
// Kernel 4: per-query output. 2 WGs per episode (half the query rows each).
// ---------------------------------------------------------------------------
__global__ __launch_bounds__(256) void k_out(
        const float* __restrict__ X,
        const int* __restrict__ qry_idx, const int* __restrict__ counts,
        const float* __restrict__ pos_mean, const float* __restrict__ neg_mean,
        const float* __restrict__ vsol, const float* __restrict__ log_scale,
        float* __restrict__ out)
{
    const int bid  = blockIdx.x;
    const int b    = bid >> 1;
    const int h    = bid & 1;
    const int tid  = threadIdx.x;
    const int lane = tid & 63;
    const int wave = tid >> 6;

    __shared__ float vpos[DDIM], vneg[DDIM];
    __shared__ float red4[4][4];
    __shared__ float sc[4];

    const int nq  = counts[b*4 + 1];
    const int nqc = min(nq, LPAD);
    const float scale = expf(log_scale[0]);

    float pm0 = pos_mean[b*DDIM + tid], pm1 = pos_mean[b*DDIM + tid + 256];
    float nm0 = neg_mean[b*DDIM + tid], nm1 = neg_mean[b*DDIM + tid + 256];
    float vp0 = vsol[(size_t)(b*2 + 1) * DDIM + tid];
    float vp1 = vsol[(size_t)(b*2 + 1) * DDIM + tid + 256];
    float vn0 = vsol[(size_t)(b*2 + 0) * DDIM + tid];
    float vn1 = vsol[(size_t)(b*2 + 0) * DDIM + tid + 256];
    vpos[tid] = vp0; vpos[tid + 256] = vp1;
    vneg[tid] = vn0; vneg[tid + 256] = vn1;

    float smp = pm0 + pm1;
    float smn = nm0 + nm1;
    float mvp = pm0 * vp0 + pm1 * vp1;
    float mvn = nm0 * vn0 + nm1 * vn1;
    #pragma unroll
    for(int off = 32; off; off >>= 1){
        smp += __shfl_xor(smp, off);
        smn += __shfl_xor(smn, off);
        mvp += __shfl_xor(mvp, off);
        mvn += __shfl_xor(mvn, off);
    }
    if(lane == 0){
        red4[wave][0] = smp; red4[wave][1] = smn;
        red4[wave][2] = mvp; red4[wave][3] = mvn;
    }
    __syncthreads();
    if(tid < 4) sc[tid] = red4[0][tid] + red4[1][tid] + red4[2][tid] + red4[3][tid];
    __syncthreads();

    for(int r = wave + 4*h; r < nqc; r += 8){
        int n = qry_idx[b * LPAD + r];
        float tp = 0.f, tn = 0.f, sx = 0.f;
        #pragma unroll
        for(int k = 0; k < 8; k++){
            float x = X[(size_t)n * DDIM + lane + 64*k];
            tp += x * vpos[lane + 64*k];
            tn += x * vneg[lane + 64*k];
            sx += x;
        }
        #pragma unroll
        for(int off = 32; off; off >>= 1){
            tp += __shfl_xor(tp, off);
            tn += __shfl_xor(tn, off);
            sx += __shfl_xor(sx, off);
        }
        if(lane == 0){
            float mp = (tp - sc[2]) * (sx - sc[0]);
            float mn = (tn - sc[3]) * (sx - sc[1]);
            ((float2*)out)[(size_t)b * LPAD + r] = make_float2(mn * scale, mp * scale);
        }
    }
    // masked query rows -> exact zeros; WG h fills its half [h*256,(h+1)*256)
    const int lo = max(nqc, h * 256), hi = (h + 1) * 256;
    for(int r = lo + tid; r < hi; r += 256)
        ((float2*)out)[(size_t)b * LPAD + r] = make_float2(0.f, 0.f);
}

// ---------------------------------------------------------------------------
extern "C" void kernel_launch(void* const* d_in, const int* in_sizes, int n_in,
                              void* d_out, int out_size, void* d_ws, size_t ws_size,
                              hipStream_t stream)
{
    const float* X         = (const float*)d_in[0];
    const float* log_scale = (const float*)d_in[1];
    const int*   labels    = (const int*)d_in[2];
    const int*   is_query  = (const int*)d_in[3];
    const int*   bidx      = (const int*)d_in[4];
    const int N = in_sizes[2];

    char* ws = (char*)d_ws;
    auto alloc = [&](size_t bytes) -> char* {
        char* p = ws;
        ws += (bytes + 255) & ~(size_t)255;
        return p;
    };
    int*   sup_idx   = (int*)  alloc((size_t)EPISODES * LPAD * sizeof(int));
    int*   qry_idx   = (int*)  alloc((size_t)EPISODES * LPAD * sizeof(int));
    int*   sup_lab   = (int*)  alloc((size_t)EPISODES * LPAD * sizeof(int));
    int*   counts    = (int*)  alloc((size_t)EPISODES * 4 * sizeof(int));
    float* task_mean = (float*)alloc((size_t)EPISODES * DDIM * sizeof(float));
    float* pos_mean  = (float*)alloc((size_t)EPISODES * DDIM * sizeof(float));
    float* neg_mean  = (float*)alloc((size_t)EPISODES * DDIM * sizeof(float));
    float* vsol      = (float*)alloc((size_t)EPISODES * 2 * DDIM * sizeof(float));
    float* row_sums  = (float*)alloc((size_t)EPISODES * LPAD * sizeof(float));
    float* G0        = (float*)alloc((size_t)EPISODES * NS_CAP * NS_CAP * sizeof(float));
    (void)ws_size;
    (void)task_mean;

    k_seg<<<EPISODES, 256, 0, stream>>>(labels, is_query, bidx, N,
                                        sup_idx, qry_idx, sup_lab, counts);
    k_stats<<<EPISODES*2, 256, 0, stream>>>(X, sup_idx, sup_lab, counts,
                                            task_mean, pos_mean, neg_mean, row_sums);
    k_gram<<<EPISODES * NPAIRS, 256, 0, stream>>>(X, sup_idx, counts, G0);
    k_cgc<<<EPISODES * 2, CGC_NTH, 0, stream>>>(X, G0, sup_idx, sup_lab, counts,
                                                row_sums, vsol);
    k_out<<<EPISODES*2, 256, 0, stream>>>(X, qry_idx, counts, pos_mean, neg_mean,
                                          vsol, log_scale, (float*)d_out);
}

// Round 6
// 444.687 us; speedup vs baseline: 1.9873x; 1.3455x over previous
//
#include <hip/hip_runtime.h>
#include <cstdint>
#include <cstddef>

#define EPISODES 128
#define LPAD     512
#define DDIM     512
#define NS_CAP   320
#define GTILE    64
#define NPAIRS   15          // 5*(5+1)/2 tile pairs (NS_CAP/GTILE = 5)
#define CG_ITERS 18

__device__ __forceinline__ int lower_bound_dev(const int* __restrict__ a, int n, int key){
    int lo = 0, hi = n;
    while(lo < hi){
        int m = (lo + hi) >> 1;
        if(a[m] < key) lo = m + 1; else hi = m;
    }
    return lo;
}

// ---------------------------------------------------------------------------
// Kernel 1a: per-episode segmentation + gather of indices/labels + counts.
// ---------------------------------------------------------------------------
__global__ __launch_bounds__(256) void k_seg(
        const int* __restrict__ labels, const int* __restrict__ is_query,
        const int* __restrict__ bidx, int N,
        int* __restrict__ sup_idx, int* __restrict__ qry_idx,
        int* __restrict__ sup_lab, int* __restrict__ counts)
{
    const int b    = blockIdx.x;
    const int tid  = threadIdx.x;
    const int lane = tid & 63;
    const int wave = tid >> 6;

    __shared__ int s_start, s_end;
    __shared__ int wq[4];
    __shared__ int s_runq, s_npos;

    if(tid == 0){
        s_start = lower_bound_dev(bidx, N, b);
        s_end   = lower_bound_dev(bidx, N, b + 1);
        s_runq  = 0;
        s_npos  = 0;
    }
    __syncthreads();
    const int start = s_start, end = s_end;

    for(int base = start; base < end; base += 256){
        int idx   = base + tid;
        bool valid = idx < end;
        int q   = valid ? is_query[idx] : 0;
        int lab = valid ? labels[idx]   : 0;
        unsigned long long m = __ballot(q == 1);
        if(lane == 0) wq[wave] = __popcll(m);
        __syncthreads();
        int woff = 0;
        for(int w = 0; w < wave; w++) woff += wq[w];
        int qbefore = __popcll(m & ((1ull << lane) - 1ull)) + woff;
        int runq0 = s_runq;
        int chunk_total = wq[0] + wq[1] + wq[2] + wq[3];
        if(valid){
            int pos_in_seg = idx - start;
            if(q){
                int qr = runq0 + qbefore;
                if(qr < LPAD) qry_idx[b * LPAD + qr] = idx;
            } else {
                int sr = pos_in_seg - runq0 - qbefore;
                if(sr < LPAD){
                    sup_idx[b * LPAD + sr] = idx;
                    sup_lab[b * LPAD + sr] = lab;
                    if(lab == 1) atomicAdd(&s_npos, 1);
                }
            }
        }
        __syncthreads();
        if(tid == 0) s_runq = runq0 + chunk_total;
        __syncthreads();
    }

    if(tid == 0){
        int nq = s_runq;
        int ns = (end - start) - nq;
        counts[b*4 + 0] = ns;
        counts[b*4 + 1] = nq;
        counts[b*4 + 2] = s_npos;
        counts[b*4 + 3] = ns - s_npos;
    }
}

// ---------------------------------------------------------------------------
// Kernel 1b: per-episode means + support row sums. 2 WGs per episode.
// ---------------------------------------------------------------------------
__global__ __launch_bounds__(256) void k_stats(
        const float* __restrict__ X,
        const int* __restrict__ sup_idx, const int* __restrict__ sup_lab,
        const int* __restrict__ counts,
        float* __restrict__ task_mean, float* __restrict__ pos_mean,
        float* __restrict__ neg_mean, float* __restrict__ row_sums)
{
    const int bid  = blockIdx.x;
    const int b    = bid >> 1;
    const int h    = bid & 1;
    const int tid  = threadIdx.x;
    const int lane = tid & 63;
    const int wave = tid >> 6;

    __shared__ int sidx[NS_CAP];
    __shared__ int slab[NS_CAP];

    const int ns   = counts[b*4 + 0];
    const int npos = counts[b*4 + 2];
    const int nneg = counts[b*4 + 3];
    const int nsb  = min(ns, NS_CAP);

    for(int s = tid; s < nsb; s += 256){
        sidx[s] = sup_idx[b*LPAD + s];
        slab[s] = sup_lab[b*LPAD + s];
    }
    __syncthreads();

    const int d = h*256 + tid;
    float sa = 0.f, sp = 0.f;
    int s = 0;
    for(; s + 8 <= nsb; s += 8){
        #pragma unroll
        for(int k = 0; k < 8; k++){
            int n   = sidx[s + k];
            float l = (float)slab[s + k];
            float x = X[(size_t)n * DDIM + d];
            sa += x; sp += l * x;
        }
    }
    for(; s < nsb; s++){
        float x = X[(size_t)sidx[s] * DDIM + d];
        sa += x; sp += (float)slab[s] * x;
    }
    float sn = sa - sp;
    task_mean[b*DDIM + d] = sa / (float)ns;
    pos_mean [b*DDIM + d] = sp / (float)npos;
    neg_mean [b*DDIM + d] = sn / (float)nneg;

    const int r0 = (nsb * h) >> 1;
    const int r1 = (nsb * (h + 1)) >> 1;
    for(int r = r0 + wave; r < r1; r += 8){
        int rb = r + 4;
        int n0 = sidx[r];
        int n1 = (rb < r1) ? sidx[rb] : n0;
        float s0 = 0.f, s1 = 0.f;
        #pragma unroll
        for(int k = 0; k < 8; k++){
            s0 += X[(size_t)n0 * DDIM + lane + 64*k];
            s1 += X[(size_t)n1 * DDIM + lane + 64*k];
        }
        #pragma unroll
        for(int off = 32; off; off >>= 1){
            s0 += __shfl_xor(s0, off);
            s1 += __shfl_xor(s1, off);
        }
        if(lane == 0){
            row_sums[b * LPAD + r] = s0;
            if(rb < r1) row_sums[b * LPAD + rb] = s1;
        }
    }
}

// ---------------------------------------------------------------------------
// Kernel 2: raw support Gram in interleaved layout:
//   element (c,t) of G0 lives at  G[(c>>2)*1280 + 4*t + (c&3)]
// Zero-padded to NS_CAP in both indices.
// ---------------------------------------------------------------------------
__global__ __launch_bounds__(256) void k_gram(
        const float* __restrict__ X, const int* __restrict__ sup_idx,
        const int* __restrict__ counts, float* __restrict__ G0)
{
    const int bid = blockIdx.x;
    const int b   = bid / NPAIRS;
    int tp = bid % NPAIRS;
    int ti = 0;
    while((ti+1)*(ti+2)/2 <= tp) ti++;
    const int tj  = tp - ti*(ti+1)/2;          // ti >= tj
    const int tid = threadIdx.x;
    const int ty  = tid >> 4, tx = tid & 15;

    const int ns  = counts[b*4 + 0];
    const int nsc = min(ns, NS_CAP);
    float* G = G0 + (size_t)b * NS_CAP * NS_CAP;

    if(ti * GTILE >= nsc){
        #pragma unroll
        for(int t = 0; t < 4; t++){
            int f = tid + t*256; int rr = f >> 4; int cc = f & 15;
            int c  = ti*GTILE + rr;
            int j0 = tj*GTILE + 4*cc;
            size_t base = (size_t)(c >> 2)*1280 + (c & 3);
            G[base + 4*(j0+0)] = 0.f; G[base + 4*(j0+1)] = 0.f;
            G[base + 4*(j0+2)] = 0.f; G[base + 4*(j0+3)] = 0.f;
            if(ti != tj){
                int c2 = tj*GTILE + rr;
                int j2 = ti*GTILE + 4*cc;
                size_t base2 = (size_t)(c2 >> 2)*1280 + (c2 & 3);
                G[base2 + 4*(j2+0)] = 0.f; G[base2 + 4*(j2+1)] = 0.f;
                G[base2 + 4*(j2+2)] = 0.f; G[base2 + 4*(j2+3)] = 0.f;
            }
        }
        return;
    }

    __shared__ float Sb[64*68];                // Ast[32][68]+Bst[32][68]
    __shared__ int ia[GTILE], ib[GTILE];
    float* Ast = Sb;
    float* Bst = Sb + 32*68;

    if(tid < GTILE)            ia[tid]      = sup_idx[b*LPAD + min(ti*GTILE + tid,        nsc-1)];
    else if(tid < 2*GTILE)     ib[tid - 64] = sup_idx[b*LPAD + min(tj*GTILE + (tid - 64), nsc-1)];

    float acc[4][4];
    #pragma unroll
    for(int a = 0; a < 4; a++)
        #pragma unroll
        for(int c = 0; c < 4; c++) acc[a][c] = 0.f;

    for(int k0 = 0; k0 < DDIM; k0 += 32){
        __syncthreads();
        #pragma unroll
        for(int t = 0; t < 2; t++){
            int f   = tid + t*256;
            int row = f >> 3, c4 = f & 7;
            float4 xa = *(const float4*)(X + (size_t)ia[row]*DDIM + k0 + 4*c4);
            float4 xb = *(const float4*)(X + (size_t)ib[row]*DDIM + k0 + 4*c4);
            Ast[(4*c4+0)*68 + row] = xa.x;
            Ast[(4*c4+1)*68 + row] = xa.y;
            Ast[(4*c4+2)*68 + row] = xa.z;
            Ast[(4*c4+3)*68 + row] = xa.w;
            Bst[(4*c4+0)*68 + row] = xb.x;
            Bst[(4*c4+1)*68 + row] = xb.y;
            Bst[(4*c4+2)*68 + row] = xb.z;
            Bst[(4*c4+3)*68 + row] = xb.w;
        }
        __syncthreads();
        #pragma unroll 8
        for(int k = 0; k < 32; k++){
            float4 af = *(const float4*)&Ast[k*68 + 4*ty];
            float4 bf = *(const float4*)&Bst[k*68 + 4*tx];
            acc[0][0] += af.x*bf.x; acc[0][1] += af.x*bf.y; acc[0][2] += af.x*bf.z; acc[0][3] += af.x*bf.w;
            acc[1][0] += af.y*bf.x; acc[1][1] += af.y*bf.y; acc[1][2] += af.y*bf.z; acc[1][3] += af.y*bf.w;
            acc[2][0] += af.z*bf.x; acc[2][1] += af.z*bf.y; acc[2][2] += af.z*bf.z; acc[2][3] += af.z*bf.w;
            acc[3][0] += af.w*bf.x; acc[3][1] += af.w*bf.y; acc[3][2] += af.w*bf.z; acc[3][3] += af.w*bf.w;
        }
    }

    #pragma unroll
    for(int a = 0; a < 4; a++){
        int i = ti*GTILE + 4*ty + a;
        size_t ibase = (size_t)(i >> 2)*1280 + (i & 3);
        #pragma unroll
        for(int c = 0; c < 4; c++){
            int j = tj*GTILE + 4*tx + c;
            float val = (i < nsc && j < nsc) ? acc[a][c] : 0.f;
            G[ibase + 4*j] = val;
        }
    }
    if(ti != tj){
        #pragma unroll
        for(int a = 0; a < 4; a++){
            int i = ti*GTILE + 4*ty + a;
            #pragma unroll
            for(int c = 0; c < 4; c++){
                int j = tj*GTILE + 4*tx + c;
                float val = (i < nsc && j < nsc) ? acc[a][c] : 0.f;
                G[(size_t)(j >> 2)*1280 + 4*i + (j & 3)] = val;
            }
        }
    }
}

// ---------------------------------------------------------------------------
// Kernel 3: coefficient-space Chronopoulos-Gear CG (single reduction bundle
// per iteration). 512 threads; thread t owns coefficient t (t < 320).
// Matvec: ILP-12 coalesced float4 column sweep, no internal barriers.
// 3 barriers per iteration total. XCD swizzle pairs pos/neg systems of an
// episode on the same XCD for L2 reuse of the shared Gram.
// ---------------------------------------------------------------------------
__global__ __launch_bounds__(512) void k_cgc(
        const float* __restrict__ X, const float* __restrict__ G0,
        const int* __restrict__ sup_idx, const int* __restrict__ sup_lab,
        const int* __restrict__ counts, const float* __restrict__ row_sums,
        float* __restrict__ vout)
{
    const int bid  = blockIdx.x;
    const int sys  = ((bid & 7) << 5) | (bid >> 3);   // pair-local XCD swizzle
    const int b    = sys >> 1;
    const int cls  = sys & 1;
    const int tid  = threadIdx.x;
    const int lane = tid & 63;
    const int wave = tid >> 6;

    __shared__ __align__(16) float u[NS_CAP];
    __shared__ int   idx_l[NS_CAP];
    __shared__ float redA[8][5];

    const int ns   = counts[b*4 + 0];
    const int nsc  = min(ns, NS_CAP);
    const int ncls = cls ? counts[b*4 + 2] : counts[b*4 + 3];
    const float c_task = 0.9f / (float)(ns - 1);
    const float c_cls  = 0.1f / (float)(ncls - 1);
    const float inv_ns = 1.f / (float)ns;
    const float inv_nc = 1.f / (float)ncls;
    const float4* G4 = (const float4*)(G0 + (size_t)b * NS_CAP * NS_CAP);
    const float4* u4 = (const float4*)u;
    const int nf4 = (nsc + 3) >> 2;

    const bool mth = tid < NS_CAP;
    const bool own = tid < nsc;
    float mfl = 0.f, sraw = 0.f;
    if(own){
        mfl  = (sup_lab[b*LPAD + tid] == cls) ? 1.f : 0.f;
        sraw = row_sums[b*LPAD + tid];
    }
    for(int s = tid; s < nsc; s += 512) idx_l[s] = sup_idx[b*LPAD + s];

    auto reduce5 = [&](float v0, float v1, float v2, float v3, float v4,
                       float* out){
        #pragma unroll
        for(int off = 32; off; off >>= 1){
            v0 += __shfl_xor(v0, off); v1 += __shfl_xor(v1, off);
            v2 += __shfl_xor(v2, off); v3 += __shfl_xor(v3, off);
            v4 += __shfl_xor(v4, off);
        }
        __syncthreads();
        if(lane == 0){
            redA[wave][0] = v0; redA[wave][1] = v1; redA[wave][2] = v2;
            redA[wave][3] = v3; redA[wave][4] = v4;
        }
        __syncthreads();
        #pragma unroll
        for(int k = 0; k < 5; k++){
            float s = 0.f;
            #pragma unroll
            for(int w = 0; w < 8; w++) s += redA[w][k];
            out[k] = s;
        }
    };

    // tq[tid] = sum_c u[c] * G(c, tid); requires u published + barrier.
    auto matvec = [&]() -> float {
        float s0 = 0.f, s1 = 0.f, s2 = 0.f, s3 = 0.f;
        if(mth){
            int c4 = 0;
            for(; c4 + 12 <= nf4; c4 += 12){
                float4 g[12];
                #pragma unroll
                for(int j = 0; j < 12; j++)
                    g[j] = G4[(size_t)(c4 + j)*NS_CAP + tid];
                #pragma unroll
                for(int j = 0; j < 12; j += 4){
                    float4 w0 = u4[c4+j+0], w1 = u4[c4+j+1];
                    float4 w2 = u4[c4+j+2], w3 = u4[c4+j+3];
                    s0 += g[j+0].x*w0.x + g[j+0].y*w0.y + g[j+0].z*w0.z + g[j+0].w*w0.w;
                    s1 += g[j+1].x*w1.x + g[j+1].y*w1.y + g[j+1].z*w1.z + g[j+1].w*w1.w;
                    s2 += g[j+2].x*w2.x + g[j+2].y*w2.y + g[j+2].z*w2.z + g[j+2].w*w2.w;
                    s3 += g[j+3].x*w3.x + g[j+3].y*w3.y + g[j+3].z*w3.z + g[j+3].w*w3.w;
                }
            }
            for(; c4 + 4 <= nf4; c4 += 4){
                float4 g0 = G4[(size_t)(c4+0)*NS_CAP + tid];
                float4 g1 = G4[(size_t)(c4+1)*NS_CAP + tid];
                float4 g2 = G4[(size_t)(c4+2)*NS_CAP + tid];
                float4 g3 = G4[(size_t)(c4+3)*NS_CAP + tid];
                float4 w0 = u4[c4+0], w1 = u4[c4+1], w2 = u4[c4+2], w3 = u4[c4+3];
                s0 += g0.x*w0.x + g0.y*w0.y + g0.z*w0.z + g0.w*w0.w;
                s1 += g1.x*w1.x + g1.y*w1.y + g1.z*w1.z + g1.w*w1.w;
                s2 += g2.x*w2.x + g2.y*w2.y + g2.z*w2.z + g2.w*w2.w;
                s3 += g3.x*w3.x + g3.y*w3.y + g3.z*w3.z + g3.w*w3.w;
            }
            for(; c4 < nf4; c4++){
                float4 g = G4[(size_t)c4*NS_CAP + tid];
                float4 w = u4[c4];
                s0 += g.x*w.x + g.y*w.y + g.z*w.z + g.w*w.w;
            }
        }
        return (s0 + s1) + (s2 + s3);
    };

    // init: r0 = -10 * A * 1  (t-image of p=1_D is the row-sum vector)
    float out5[5];
    reduce5(sraw, mfl * sraw, 0.f, 0.f, 0.f, out5);
    float A0 = out5[0] * inv_ns, A1 = out5[1] * inv_nc;
    float cr = own ? -10.f * (c_task*(sraw - A0) + mfl*c_cls*(sraw - A1)) : 0.f;
    if(mth) u[tid] = cr;
    __syncthreads();
    float tr = matvec();

    float cp = 0.f, tp = 0.f, cq = 0.f, tq = 0.f, cx = 0.f;
    float gamma_old = 1.f, alpha_old = 1.f;
    bool first = true;

    for(int it = 0; it < CG_ITERS; ++it){
        // bundle: S1=Σtr, S2=Σm·tr, S3=Σtr², S4=Σm·tr², S5=Σtr·cr
        reduce5(tr, mfl*tr, tr*tr, mfl*tr*tr, tr*cr, out5);
        A0 = out5[0] * inv_ns; A1 = out5[1] * inv_nc;
        float gamma = out5[4];                               // (r,r)
        float delta = 0.1f*gamma + c_task*(out5[2] - out5[0]*A0)
                                 + c_cls *(out5[3] - out5[1]*A1);  // (r,Mr)
        if(gamma < 1e-26f) break;
        float ur = own ? (c_task*(tr - A0) + mfl*c_cls*(tr - A1)) : 0.f;
        float cw = 0.1f*cr + ur;                             // c of w = M r
        if(mth) u[tid] = ur;
        __syncthreads();
        float gv = matvec();                                 // G0 * u_r
        float tw = 0.1f*tr + gv;                             // t of w
        float beta  = first ? 0.f : gamma / gamma_old;
        float alpha = first ? gamma / delta
                            : gamma / (delta - beta * gamma / alpha_old);
        cp = cr + beta * cp;  tp = tr + beta * tp;
        cq = cw + beta * cq;  tq = tw + beta * tq;
        cx += alpha * cp;
        cr -= alpha * cq;     tr -= alpha * tq;
        gamma_old = gamma; alpha_old = alpha; first = false;
    }

    // v = 10*1 + Xs^T c_x  (threads 0..511 own dims; 8 independent loads)
    __syncthreads();                                         // u free
    if(mth) u[tid] = own ? cx : 0.f;
    __syncthreads();
    float v = 10.f;
    int s = 0;
    for(; s + 8 <= nsc; s += 8){
        #pragma unroll
        for(int k = 0; k < 8; k++)
            v += u[s+k] * X[(size_t)idx_l[s+k]*DDIM + tid];
    }
    for(; s < nsc; s++) v += u[s] * X[(size_t)idx_l[s]*DDIM + tid];
    vout[(size_t)sys * DDIM + tid] = v;
}

// ---------------------------------------------------------------------------
// Kernel 4: per-query output. 2 WGs per episode (half the query rows each).
// ---------------------------------------------------------------------------
__global__ __launch_bounds__(256) void k_out(
        const float* __restrict__ X,
        const int* __restrict__ qry_idx, const int* __restrict__ counts,
        const float* __restrict__ pos_mean, const float* __restrict__ neg_mean,
        const float* __restrict__ vsol, const float* __restrict__ log_scale,
        float* __restrict__ out)
{
    const int bid  = blockIdx.x;
    const int b    = bid >> 1;
    const int h    = bid & 1;
    const int tid  = threadIdx.x;
    const int lane = tid & 63;
    const int wave = tid >> 6;

    __shared__ float vpos[DDIM], vneg[DDIM];
    __shared__ float red4[4][4];
    __shared__ float sc[4];

    const int nq  = counts[b*4 + 1];
    const int nqc = min(nq, LPAD);
    const float scale = expf(log_scale[0]);

    float pm0 = pos_mean[b*DDIM + tid], pm1 = pos_mean[b*DDIM + tid + 256];
    float nm0 = neg_mean[b*DDIM + tid], nm1 = neg_mean[b*DDIM + tid + 256];
    float vp0 = vsol[(size_t)(b*2 + 1) * DDIM + tid];
    float vp1 = vsol[(size_t)(b*2 + 1) * DDIM + tid + 256];
    float vn0 = vsol[(size_t)(b*2 + 0) * DDIM + tid];
    float vn1 = vsol[(size_t)(b*2 + 0) * DDIM + tid + 256];
    vpos[tid] = vp0; vpos[tid + 256] = vp1;
    vneg[tid] = vn0; vneg[tid + 256] = vn1;

    float smp = pm0 + pm1;
    float smn = nm0 + nm1;
    float mvp = pm0 * vp0 + pm1 * vp1;
    float mvn = nm0 * vn0 + nm1 * vn1;
    #pragma unroll
    for(int off = 32; off; off >>= 1){
        smp += __shfl_xor(smp, off);
        smn += __shfl_xor(smn, off);
        mvp += __shfl_xor(mvp, off);
        mvn += __shfl_xor(mvn, off);
    }
    if(lane == 0){
        red4[wave][0] = smp; red4[wave][1] = smn;
        red4[wave][2] = mvp; red4[wave][3] = mvn;
    }
    __syncthreads();
    if(tid < 4) sc[tid] = red4[0][tid] + red4[1][tid] + red4[2][tid] + red4[3][tid];
    __syncthreads();

    for(int r = wave + 4*h; r < nqc; r += 8){
        int n = qry_idx[b * LPAD + r];
        float tp = 0.f, tn = 0.f, sx = 0.f;
        #pragma unroll
        for(int k = 0; k < 8; k++){
            float x = X[(size_t)n * DDIM + lane + 64*k];
            tp += x * vpos[lane + 64*k];
            tn += x * vneg[lane + 64*k];
            sx += x;
        }
        #pragma unroll
        for(int off = 32; off; off >>= 1){
            tp += __shfl_xor(tp, off);
            tn += __shfl_xor(tn, off);
            sx += __shfl_xor(sx, off);
        }
        if(lane == 0){
            float mp = (tp - sc[2]) * (sx - sc[0]);
            float mn = (tn - sc[3]) * (sx - sc[1]);
            ((float2*)out)[(size_t)b * LPAD + r] = make_float2(mn * scale, mp * scale);
        }
    }
    const int lo = max(nqc, h * 256), hi = (h + 1) * 256;
    for(int r = lo + tid; r < hi; r += 256)
        ((float2*)out)[(size_t)b * LPAD + r] = make_float2(0.f, 0.f);
}

// ---------------------------------------------------------------------------
extern "C" void kernel_launch(void* const* d_in, const int* in_sizes, int n_in,
                              void* d_out, int out_size, void* d_ws, size_t ws_size,
                              hipStream_t stream)
{
    const float* X         = (const float*)d_in[0];
    const float* log_scale = (const float*)d_in[1];
    const int*   labels    = (const int*)d_in[2];
    const int*   is_query  = (const int*)d_in[3];
    const int*   bidx      = (const int*)d_in[4];
    const int N = in_sizes[2];

    char* ws = (char*)d_ws;
    auto alloc = [&](size_t bytes) -> char* {
        char* p = ws;
        ws += (bytes + 255) & ~(size_t)255;
        return p;
    };
    int*   sup_idx   = (int*)  alloc((size_t)EPISODES * LPAD * sizeof(int));
    int*   qry_idx   = (int*)  alloc((size_t)EPISODES * LPAD * sizeof(int));
    int*   sup_lab   = (int*)  alloc((size_t)EPISODES * LPAD * sizeof(int));
    int*   counts    = (int*)  alloc((size_t)EPISODES * 4 * sizeof(int));
    float* task_mean = (float*)alloc((size_t)EPISODES * DDIM * sizeof(float));
    float* pos_mean  = (float*)alloc((size_t)EPISODES * DDIM * sizeof(float));
    float* neg_mean  = (float*)alloc((size_t)EPISODES * DDIM * sizeof(float));
    float* vsol      = (float*)alloc((size_t)EPISODES * 2 * DDIM * sizeof(float));
    float* row_sums  = (float*)alloc((size_t)EPISODES * LPAD * sizeof(float));
    float* G0        = (float*)alloc((size_t)EPISODES * NS_CAP * NS_CAP * sizeof(float));
    (void)ws_size;
    (void)task_mean;

    k_seg<<<EPISODES, 256, 0, stream>>>(labels, is_query, bidx, N,
                                        sup_idx, qry_idx, sup_lab, counts);
    k_stats<<<EPISODES*2, 256, 0, stream>>>(X, sup_idx, sup_lab, counts,
                                            task_mean, pos_mean, neg_mean, row_sums);
    k_gram<<<EPISODES * NPAIRS, 256, 0, stream>>>(X, sup_idx, counts, G0);
    k_cgc<<<EPISODES * 2, 512, 0, stream>>>(X, G0, sup_idx, sup_lab, counts,
                                            row_sums, vsol);
    k_out<<<EPISODES*2, 256, 0, stream>>>(X, qry_idx, counts, pos_mean, neg_mean,
                                          vsol, log_scale, (float*)d_out);
}

// Round 7
// 396.597 us; speedup vs baseline: 2.2283x; 1.1213x over previous
//
#include <hip/hip_runtime.h>
#include <cstdint>
#include <cstddef>

#define EPISODES 128
#define LPAD     512
#define DDIM     512
#define NS_CAP   320
#define GTILE    64
#define NPAIRS   15          // 5*(5+1)/2 tile pairs (NS_CAP/GTILE = 5)
#define CG_ITERS 18
#define GL_F4    9536        // dynamic-LDS float4 capacity (152576 B)

__device__ __forceinline__ int lower_bound_dev(const int* __restrict__ a, int n, int key){
    int lo = 0, hi = n;
    while(lo < hi){
        int m = (lo + hi) >> 1;
        if(a[m] < key) lo = m + 1; else hi = m;
    }
    return lo;
}

__device__ __forceinline__ float4 f4add(float4 a, float4 b){
    return make_float4(a.x+b.x, a.y+b.y, a.z+b.z, a.w+b.w);
}
__device__ __forceinline__ float4 f4fma(float s, float4 a, float4 acc){
    return make_float4(acc.x + s*a.x, acc.y + s*a.y, acc.z + s*a.z, acc.w + s*a.w);
}
__device__ __forceinline__ float f4dot(float4 a, float4 b){
    return a.x*b.x + a.y*b.y + a.z*b.z + a.w*b.w;
}
__device__ __forceinline__ float f4sum(float4 a){ return (a.x+a.y)+(a.z+a.w); }

// ---------------------------------------------------------------------------
// Kernel 1a: per-episode segmentation + gather of indices/labels + counts.
// ---------------------------------------------------------------------------
__global__ __launch_bounds__(256) void k_seg(
        const int* __restrict__ labels, const int* __restrict__ is_query,
        const int* __restrict__ bidx, int N,
        int* __restrict__ sup_idx, int* __restrict__ qry_idx,
        int* __restrict__ sup_lab, int* __restrict__ counts)
{
    const int b    = blockIdx.x;
    const int tid  = threadIdx.x;
    const int lane = tid & 63;
    const int wave = tid >> 6;

    __shared__ int s_start, s_end;
    __shared__ int wq[4];
    __shared__ int s_runq, s_npos;

    if(tid == 0){
        s_start = lower_bound_dev(bidx, N, b);
        s_end   = lower_bound_dev(bidx, N, b + 1);
        s_runq  = 0;
        s_npos  = 0;
    }
    __syncthreads();
    const int start = s_start, end = s_end;

    for(int base = start; base < end; base += 256){
        int idx   = base + tid;
        bool valid = idx < end;
        int q   = valid ? is_query[idx] : 0;
        int lab = valid ? labels[idx]   : 0;
        unsigned long long m = __ballot(q == 1);
        if(lane == 0) wq[wave] = __popcll(m);
        __syncthreads();
        int woff = 0;
        for(int w = 0; w < wave; w++) woff += wq[w];
        int qbefore = __popcll(m & ((1ull << lane) - 1ull)) + woff;
        int runq0 = s_runq;
        int chunk_total = wq[0] + wq[1] + wq[2] + wq[3];
        if(valid){
            int pos_in_seg = idx - start;
            if(q){
                int qr = runq0 + qbefore;
                if(qr < LPAD) qry_idx[b * LPAD + qr] = idx;
            } else {
                int sr = pos_in_seg - runq0 - qbefore;
                if(sr < LPAD){
                    sup_idx[b * LPAD + sr] = idx;
                    sup_lab[b * LPAD + sr] = lab;
                    if(lab == 1) atomicAdd(&s_npos, 1);
                }
            }
        }
        __syncthreads();
        if(tid == 0) s_runq = runq0 + chunk_total;
        __syncthreads();
    }

    if(tid == 0){
        int nq = s_runq;
        int ns = (end - start) - nq;
        counts[b*4 + 0] = ns;
        counts[b*4 + 1] = nq;
        counts[b*4 + 2] = s_npos;
        counts[b*4 + 3] = ns - s_npos;
    }
}

// ---------------------------------------------------------------------------
// Kernel 1b: per-episode means + support row sums. 2 WGs per episode.
// float4 gathers (4x fewer load instructions than scalar).
// ---------------------------------------------------------------------------
__global__ __launch_bounds__(256) void k_stats(
        const float* __restrict__ X,
        const int* __restrict__ sup_idx, const int* __restrict__ sup_lab,
        const int* __restrict__ counts,
        float* __restrict__ task_mean, float* __restrict__ pos_mean,
        float* __restrict__ neg_mean, float* __restrict__ row_sums)
{
    const int bid  = blockIdx.x;
    const int b    = bid >> 1;
    const int h    = bid & 1;
    const int tid  = threadIdx.x;
    const int lane = tid & 63;
    const int wave = tid >> 6;

    __shared__ int   sidx[NS_CAP];
    __shared__ float slabf[NS_CAP];
    __shared__ float4 pa[4][64];
    __shared__ float4 pp[4][64];

    const int ns   = counts[b*4 + 0];
    const int npos = counts[b*4 + 2];
    const int nneg = counts[b*4 + 3];
    const int nsb  = min(ns, NS_CAP);

    for(int s = tid; s < nsb; s += 256){
        sidx[s]  = sup_idx[b*LPAD + s];
        slabf[s] = (float)sup_lab[b*LPAD + s];
    }
    __syncthreads();

    const float4* X4 = (const float4*)X;
    const int colg = h*64 + (tid & 63);        // global float4 column
    const int rg   = tid >> 6;                 // row group (stride 4)

    float4 sa = make_float4(0.f,0.f,0.f,0.f);
    float4 sp = make_float4(0.f,0.f,0.f,0.f);
    int r = rg;
    for(; r + 12 < nsb; r += 16){
        int n0 = sidx[r], n1 = sidx[r+4], n2 = sidx[r+8], n3 = sidx[r+12];
        float l0 = slabf[r], l1 = slabf[r+4], l2 = slabf[r+8], l3 = slabf[r+12];
        float4 x0 = X4[(size_t)n0*128 + colg];
        float4 x1 = X4[(size_t)n1*128 + colg];
        float4 x2 = X4[(size_t)n2*128 + colg];
        float4 x3 = X4[(size_t)n3*128 + colg];
        sa = f4add(sa, f4add(f4add(x0,x1), f4add(x2,x3)));
        sp = f4fma(l0,x0, f4fma(l1,x1, f4fma(l2,x2, f4fma(l3,x3, sp))));
    }
    for(; r < nsb; r += 4){
        int n = sidx[r];
        float l = slabf[r];
        float4 x = X4[(size_t)n*128 + colg];
        sa = f4add(sa, x);
        sp = f4fma(l, x, sp);
    }
    pa[rg][tid & 63] = sa;
    pp[rg][tid & 63] = sp;
    __syncthreads();
    if(tid < 64){
        float4 A = f4add(f4add(pa[0][tid],pa[1][tid]), f4add(pa[2][tid],pa[3][tid]));
        float4 P = f4add(f4add(pp[0][tid],pp[1][tid]), f4add(pp[2][tid],pp[3][tid]));
        float4 Nn = make_float4(A.x-P.x, A.y-P.y, A.z-P.z, A.w-P.w);
        float ia = 1.f/(float)ns, ip = 1.f/(float)npos, in = 1.f/(float)nneg;
        int c = b*128 + h*64 + tid;
        ((float4*)task_mean)[c] = make_float4(A.x*ia, A.y*ia, A.z*ia, A.w*ia);
        ((float4*)pos_mean )[c] = make_float4(P.x*ip, P.y*ip, P.z*ip, P.w*ip);
        ((float4*)neg_mean )[c] = make_float4(Nn.x*in, Nn.y*in, Nn.z*in, Nn.w*in);
    }

    // Row sums for row half [r0, r1): float4, 2 rows per wave iteration.
    const int r0 = (nsb * h) >> 1;
    const int r1 = (nsb * (h + 1)) >> 1;
    for(int rr = r0 + wave; rr < r1; rr += 8){
        int rb = rr + 4;
        const float4* xr0 = (const float4*)(X + (size_t)sidx[rr]*DDIM);
        const float4* xr1 = (rb < r1) ? (const float4*)(X + (size_t)sidx[rb]*DDIM) : xr0;
        float4 a0 = xr0[lane], a1 = xr0[lane + 64];
        float4 b0 = xr1[lane], b1 = xr1[lane + 64];
        float s0 = f4sum(a0) + f4sum(a1);
        float s1 = f4sum(b0) + f4sum(b1);
        #pragma unroll
        for(int off = 32; off; off >>= 1){
            s0 += __shfl_xor(s0, off);
            s1 += __shfl_xor(s1, off);
        }
        if(lane == 0){
            row_sums[b * LPAD + rr] = s0;
            if(rb < r1) row_sums[b * LPAD + rb] = s1;
        }
    }
}

// ---------------------------------------------------------------------------
// Kernel 2: raw support Gram in interleaved layout:
//   element (c,t) of G0 lives at  G[(c>>2)*1280 + 4*t + (c&3)]
// Zero-padded to NS_CAP in both indices.
// ---------------------------------------------------------------------------
__global__ __launch_bounds__(256) void k_gram(
        const float* __restrict__ X, const int* __restrict__ sup_idx,
        const int* __restrict__ counts, float* __restrict__ G0)
{
    const int bid = blockIdx.x;
    const int b   = bid / NPAIRS;
    int tp = bid % NPAIRS;
    int ti = 0;
    while((ti+1)*(ti+2)/2 <= tp) ti++;
    const int tj  = tp - ti*(ti+1)/2;          // ti >= tj
    const int tid = threadIdx.x;
    const int ty  = tid >> 4, tx = tid & 15;

    const int ns  = counts[b*4 + 0];
    const int nsc = min(ns, NS_CAP);
    float* G = G0 + (size_t)b * NS_CAP * NS_CAP;

    if(ti * GTILE >= nsc){
        #pragma unroll
        for(int t = 0; t < 4; t++){
            int f = tid + t*256; int rr = f >> 4; int cc = f & 15;
            int c  = ti*GTILE + rr;
            int j0 = tj*GTILE + 4*cc;
            size_t base = (size_t)(c >> 2)*1280 + (c & 3);
            G[base + 4*(j0+0)] = 0.f; G[base + 4*(j0+1)] = 0.f;
            G[base + 4*(j0+2)] = 0.f; G[base + 4*(j0+3)] = 0.f;
            if(ti != tj){
                int c2 = tj*GTILE + rr;
                int j2 = ti*GTILE + 4*cc;
                size_t base2 = (size_t)(c2 >> 2)*1280 + (c2 & 3);
                G[base2 + 4*(j2+0)] = 0.f; G[base2 + 4*(j2+1)] = 0.f;
                G[base2 + 4*(j2+2)] = 0.f; G[base2 + 4*(j2+3)] = 0.f;
            }
        }
        return;
    }

    __shared__ float Sb[64*68];                // Ast[32][68]+Bst[32][68]
    __shared__ int ia[GTILE], ib[GTILE];
    float* Ast = Sb;
    float* Bst = Sb + 32*68;

    if(tid < GTILE)            ia[tid]      = sup_idx[b*LPAD + min(ti*GTILE + tid,        nsc-1)];
    else if(tid < 2*GTILE)     ib[tid - 64] = sup_idx[b*LPAD + min(tj*GTILE + (tid - 64), nsc-1)];

    float acc[4][4];
    #pragma unroll
    for(int a = 0; a < 4; a++)
        #pragma unroll
        for(int c = 0; c < 4; c++) acc[a][c] = 0.f;

    for(int k0 = 0; k0 < DDIM; k0 += 32){
        __syncthreads();
        #pragma unroll
        for(int t = 0; t < 2; t++){
            int f   = tid + t*256;
            int row = f >> 3, c4 = f & 7;
            float4 xa = *(const float4*)(X + (size_t)ia[row]*DDIM + k0 + 4*c4);
            float4 xb = *(const float4*)(X + (size_t)ib[row]*DDIM + k0 + 4*c4);
            Ast[(4*c4+0)*68 + row] = xa.x;
            Ast[(4*c4+1)*68 + row] = xa.y;
            Ast[(4*c4+2)*68 + row] = xa.z;
            Ast[(4*c4+3)*68 + row] = xa.w;
            Bst[(4*c4+0)*68 + row] = xb.x;
            Bst[(4*c4+1)*68 + row] = xb.y;
            Bst[(4*c4+2)*68 + row] = xb.z;
            Bst[(4*c4+3)*68 + row] = xb.w;
        }
        __syncthreads();
        #pragma unroll 8
        for(int k = 0; k < 32; k++){
            float4 af = *(const float4*)&Ast[k*68 + 4*ty];
            float4 bf = *(const float4*)&Bst[k*68 + 4*tx];
            acc[0][0] += af.x*bf.x; acc[0][1] += af.x*bf.y; acc[0][2] += af.x*bf.z; acc[0][3] += af.x*bf.w;
            acc[1][0] += af.y*bf.x; acc[1][1] += af.y*bf.y; acc[1][2] += af.y*bf.z; acc[1][3] += af.y*bf.w;
            acc[2][0] += af.z*bf.x; acc[2][1] += af.z*bf.y; acc[2][2] += af.z*bf.z; acc[2][3] += af.z*bf.w;
            acc[3][0] += af.w*bf.x; acc[3][1] += af.w*bf.y; acc[3][2] += af.w*bf.z; acc[3][3] += af.w*bf.w;
        }
    }

    #pragma unroll
    for(int a = 0; a < 4; a++){
        int i = ti*GTILE + 4*ty + a;
        size_t ibase = (size_t)(i >> 2)*1280 + (i & 3);
        #pragma unroll
        for(int c = 0; c < 4; c++){
            int j = tj*GTILE + 4*tx + c;
            float val = (i < nsc && j < nsc) ? acc[a][c] : 0.f;
            G[ibase + 4*j] = val;
        }
    }
    if(ti != tj){
        #pragma unroll
        for(int a = 0; a < 4; a++){
            int i = ti*GTILE + 4*ty + a;
            #pragma unroll
            for(int c = 0; c < 4; c++){
                int j = tj*GTILE + 4*tx + c;
                float val = (i < nsc && j < nsc) ? acc[a][c] : 0.f;
                G[(size_t)(j >> 2)*1280 + 4*i + (j & 3)] = val;
            }
        }
    }
}

// ---------------------------------------------------------------------------
// Kernel 3: coefficient-space Chronopoulos-Gear CG with the Gram cached in
// dynamic LDS (compact stride nsc; typically the WHOLE Gram fits). Overflow
// blocks (nsc > ~195) sweep from global with ILP-8. 3 barriers/iteration.
// Reconstruction reuses the LDS buffer as float4 scratch (4-way row split).
// ---------------------------------------------------------------------------
extern __shared__ float4 gl4[];                // GL_F4 float4 (152576 B)

__global__ __launch_bounds__(512, 2) void k_cgc(
        const float* __restrict__ X, const float* __restrict__ G0,
        const int* __restrict__ sup_idx, const int* __restrict__ sup_lab,
        const int* __restrict__ counts, const float* __restrict__ row_sums,
        float* __restrict__ vout)
{
    const int bid  = blockIdx.x;
    const int sys  = ((bid & 7) << 5) | (bid >> 3);   // pair-local XCD swizzle
    const int b    = sys >> 1;
    const int cls  = sys & 1;
    const int tid  = threadIdx.x;
    const int lane = tid & 63;
    const int wave = tid >> 6;

    __shared__ __align__(16) float u[NS_CAP];
    __shared__ int   idx_l[NS_CAP];
    __shared__ float redA[8][5];

    const int ns   = counts[b*4 + 0];
    const int nsc  = min(ns, NS_CAP);
    const int ncls = cls ? counts[b*4 + 2] : counts[b*4 + 3];
    const float c_task = 0.9f / (float)(ns - 1);
    const float c_cls  = 0.1f / (float)(ncls - 1);
    const float inv_ns = 1.f / (float)ns;
    const float inv_nc = 1.f / (float)ncls;
    const float4* G4 = (const float4*)(G0 + (size_t)b * NS_CAP * NS_CAP);
    const float4* u4 = (const float4*)u;
    const int nf4 = (nsc + 3) >> 2;
    const int c4l = min(nf4, GL_F4 / nsc);     // Gram blocks cached in LDS

    const bool mth = tid < NS_CAP;
    const bool own = tid < nsc;
    float mfl = 0.f, sraw = 0.f;
    if(own){
        mfl  = (sup_lab[b*LPAD + tid] == cls) ? 1.f : 0.f;
        sraw = row_sums[b*LPAD + tid];
    }
    for(int s = tid; s < nsc; s += 512) idx_l[s] = sup_idx[b*LPAD + s];

    // Stage Gram blocks into LDS: gl4[c4*nsc + t] = G4[c4*NS_CAP + t]
    {
        const int total = c4l * nsc;
        for(int i = tid; i < total; i += 512){
            int c4 = i / nsc;
            int t  = i - c4 * nsc;
            gl4[i] = G4[(size_t)c4 * NS_CAP + t];
        }
    }
    __syncthreads();

    auto reduce5 = [&](float v0, float v1, float v2, float v3, float v4,
                       float* out){
        #pragma unroll
        for(int off = 32; off; off >>= 1){
            v0 += __shfl_xor(v0, off); v1 += __shfl_xor(v1, off);
            v2 += __shfl_xor(v2, off); v3 += __shfl_xor(v3, off);
            v4 += __shfl_xor(v4, off);
        }
        __syncthreads();
        if(lane == 0){
            redA[wave][0] = v0; redA[wave][1] = v1; redA[wave][2] = v2;
            redA[wave][3] = v3; redA[wave][4] = v4;
        }
        __syncthreads();
        #pragma unroll
        for(int k = 0; k < 5; k++){
            float s = 0.f;
            #pragma unroll
            for(int w = 0; w < 8; w++) s += redA[w][k];
            out[k] = s;
        }
    };

    // tq[tid] = sum_c u[c] * G(c, tid); requires u published + barrier.
    auto matvec = [&]() -> float {
        float s0 = 0.f, s1 = 0.f, s2 = 0.f, s3 = 0.f;
        if(own){
            const float4* gq = gl4 + tid;
            int c4 = 0;
            for(; c4 + 8 <= c4l; c4 += 8){
                float4 g0 = gq[(c4+0)*nsc], g1 = gq[(c4+1)*nsc];
                float4 g2 = gq[(c4+2)*nsc], g3 = gq[(c4+3)*nsc];
                float4 g4 = gq[(c4+4)*nsc], g5 = gq[(c4+5)*nsc];
                float4 g6 = gq[(c4+6)*nsc], g7 = gq[(c4+7)*nsc];
                s0 += f4dot(g0, u4[c4+0]); s1 += f4dot(g1, u4[c4+1]);
                s2 += f4dot(g2, u4[c4+2]); s3 += f4dot(g3, u4[c4+3]);
                s0 += f4dot(g4, u4[c4+4]); s1 += f4dot(g5, u4[c4+5]);
                s2 += f4dot(g6, u4[c4+6]); s3 += f4dot(g7, u4[c4+7]);
            }
            for(; c4 < c4l; c4++) s0 += f4dot(gq[c4*nsc], u4[c4]);
            // overflow blocks from global (rare): ILP-8
            for(; c4 + 8 <= nf4; c4 += 8){
                float4 g[8];
                #pragma unroll
                for(int j = 0; j < 8; j++) g[j] = G4[(size_t)(c4+j)*NS_CAP + tid];
                #pragma unroll
                for(int j = 0; j < 8; j++){
                    float d = f4dot(g[j], u4[c4+j]);
                    if((j & 3) == 0) s0 += d; else if((j & 3) == 1) s1 += d;
                    else if((j & 3) == 2) s2 += d; else s3 += d;
                }
            }
            for(; c4 < nf4; c4++) s0 += f4dot(G4[(size_t)c4*NS_CAP + tid], u4[c4]);
        }
        return (s0 + s1) + (s2 + s3);
    };

    // init: r0 = -10 * A * 1  (t-image of p=1_D is the row-sum vector)
    float out5[5];
    reduce5(sraw, mfl * sraw, 0.f, 0.f, 0.f, out5);
    float A0 = out5[0] * inv_ns, A1 = out5[1] * inv_nc;
    float cr = own ? -10.f * (c_task*(sraw - A0) + mfl*c_cls*(sraw - A1)) : 0.f;
    if(mth) u[tid] = own ? cr : 0.f;
    __syncthreads();
    float tr = matvec();

    float cp = 0.f, tp = 0.f, cq = 0.f, tq = 0.f, cx = 0.f;
    float gamma_old = 1.f, alpha_old = 1.f;
    bool first = true;

    for(int it = 0; it < CG_ITERS; ++it){
        // bundle: S1=Σtr, S2=Σm·tr, S3=Σtr², S4=Σm·tr², S5=Σtr·cr
        reduce5(tr, mfl*tr, tr*tr, mfl*tr*tr, tr*cr, out5);
        A0 = out5[0] * inv_ns; A1 = out5[1] * inv_nc;
        float gamma = out5[4];                               // (r,r)
        float delta = 0.1f*gamma + c_task*(out5[2] - out5[0]*A0)
                                 + c_cls *(out5[3] - out5[1]*A1);  // (r,Mr)
        if(gamma < 1e-26f) break;
        float ur = own ? (c_task*(tr - A0) + mfl*c_cls*(tr - A1)) : 0.f;
        float cw = 0.1f*cr + ur;                             // c of w = M r
        if(mth) u[tid] = ur;
        __syncthreads();
        float gv = matvec();                                 // G0 * u_r
        float tw = 0.1f*tr + gv;                             // t of w
        float beta  = first ? 0.f : gamma / gamma_old;
        float alpha = first ? gamma / delta
                            : gamma / (delta - beta * gamma / alpha_old);
        cp = cr + beta * cp;  tp = tr + beta * tp;
        cq = cw + beta * cq;  tq = tw + beta * tq;
        cx += alpha * cp;
        cr -= alpha * cq;     tr -= alpha * tq;
        gamma_old = gamma; alpha_old = alpha; first = false;
    }

    // v = 10*1 + Xs^T c_x : float4, 4-way row split, gl4 reused as scratch.
    __syncthreads();
    if(mth) u[tid] = own ? cx : 0.f;
    __syncthreads();
    const float4* X4 = (const float4*)X;
    const int f4c = tid & 127;
    const int rg  = tid >> 7;                  // 0..3
    float4 acc = make_float4(0.f,0.f,0.f,0.f);
    int s = rg;
    for(; s + 12 < nsc; s += 16){
        int n0 = idx_l[s], n1 = idx_l[s+4], n2 = idx_l[s+8], n3 = idx_l[s+12];
        float w0 = u[s], w1 = u[s+4], w2 = u[s+8], w3 = u[s+12];
        float4 x0 = X4[(size_t)n0*128 + f4c];
        float4 x1 = X4[(size_t)n1*128 + f4c];
        float4 x2 = X4[(size_t)n2*128 + f4c];
        float4 x3 = X4[(size_t)n3*128 + f4c];
        acc = f4fma(w0,x0, f4fma(w1,x1, f4fma(w2,x2, f4fma(w3,x3, acc))));
    }
    for(; s < nsc; s += 4)
        acc = f4fma(u[s], X4[(size_t)idx_l[s]*128 + f4c], acc);
    gl4[rg*128 + f4c] = acc;
    __syncthreads();
    if(tid < 128){
        float4 v = f4add(f4add(gl4[tid], gl4[128+tid]),
                         f4add(gl4[256+tid], gl4[384+tid]));
        v.x += 10.f; v.y += 10.f; v.z += 10.f; v.w += 10.f;
        ((float4*)vout)[(size_t)sys * 128 + tid] = v;
    }
}

// ---------------------------------------------------------------------------
// Kernel 4: per-query output. 2 WGs per episode; float4 row loads.
// ---------------------------------------------------------------------------
__global__ __launch_bounds__(256) void k_out(
        const float* __restrict__ X,
        const int* __restrict__ qry_idx, const int* __restrict__ counts,
        const float* __restrict__ pos_mean, const float* __restrict__ neg_mean,
        const float* __restrict__ vsol, const float* __restrict__ log_scale,
        float* __restrict__ out)
{
    const int bid  = blockIdx.x;
    const int b    = bid >> 1;
    const int h    = bid & 1;
    const int tid  = threadIdx.x;
    const int lane = tid & 63;
    const int wave = tid >> 6;

    __shared__ __align__(16) float vpos[DDIM];
    __shared__ __align__(16) float vneg[DDIM];
    __shared__ float red4[4][4];
    __shared__ float sc[4];

    const int nq  = counts[b*4 + 1];
    const int nqc = min(nq, LPAD);
    const float scale = expf(log_scale[0]);

    float pm0 = pos_mean[b*DDIM + tid], pm1 = pos_mean[b*DDIM + tid + 256];
    float nm0 = neg_mean[b*DDIM + tid], nm1 = neg_mean[b*DDIM + tid + 256];
    float vp0 = vsol[(size_t)(b*2 + 1) * DDIM + tid];
    float vp1 = vsol[(size_t)(b*2 + 1) * DDIM + tid + 256];
    float vn0 = vsol[(size_t)(b*2 + 0) * DDIM + tid];
    float vn1 = vsol[(size_t)(b*2 + 0) * DDIM + tid + 256];
    vpos[tid] = vp0; vpos[tid + 256] = vp1;
    vneg[tid] = vn0; vneg[tid + 256] = vn1;

    float smp = pm0 + pm1;
    float smn = nm0 + nm1;
    float mvp = pm0 * vp0 + pm1 * vp1;
    float mvn = nm0 * vn0 + nm1 * vn1;
    #pragma unroll
    for(int off = 32; off; off >>= 1){
        smp += __shfl_xor(smp, off);
        smn += __shfl_xor(smn, off);
        mvp += __shfl_xor(mvp, off);
        mvn += __shfl_xor(mvn, off);
    }
    if(lane == 0){
        red4[wave][0] = smp; red4[wave][1] = smn;
        red4[wave][2] = mvp; red4[wave][3] = mvn;
    }
    __syncthreads();
    if(tid < 4) sc[tid] = red4[0][tid] + red4[1][tid] + red4[2][tid] + red4[3][tid];
    __syncthreads();

    const float4* vp4 = (const float4*)vpos;
    const float4* vn4 = (const float4*)vneg;
    for(int r = wave + 4*h; r < nqc; r += 8){
        int n = qry_idx[b * LPAD + r];
        const float4* xr = (const float4*)(X + (size_t)n * DDIM);
        float4 x0 = xr[lane], x1 = xr[lane + 64];
        float tp = f4dot(x0, vp4[lane]) + f4dot(x1, vp4[lane + 64]);
        float tn = f4dot(x0, vn4[lane]) + f4dot(x1, vn4[lane + 64]);
        float sx = f4sum(x0) + f4sum(x1);
        #pragma unroll
        for(int off = 32; off; off >>= 1){
            tp += __shfl_xor(tp, off);
            tn += __shfl_xor(tn, off);
            sx += __shfl_xor(sx, off);
        }
        if(lane == 0){
            float mp = (tp - sc[2]) * (sx - sc[0]);
            float mn = (tn - sc[3]) * (sx - sc[1]);
            ((float2*)out)[(size_t)b * LPAD + r] = make_float2(mn * scale, mp * scale);
        }
    }
    const int lo = max(nqc, h * 256), hi = (h + 1) * 256;
    for(int r = lo + tid; r < hi; r += 256)
        ((float2*)out)[(size_t)b * LPAD + r] = make_float2(0.f, 0.f);
}

// ---------------------------------------------------------------------------
extern "C" void kernel_launch(void* const* d_in, const int* in_sizes, int n_in,
                              void* d_out, int out_size, void* d_ws, size_t ws_size,
                              hipStream_t stream)
{
    const float* X         = (const float*)d_in[0];
    const float* log_scale = (const float*)d_in[1];
    const int*   labels    = (const int*)d_in[2];
    const int*   is_query  = (const int*)d_in[3];
    const int*   bidx      = (const int*)d_in[4];
    const int N = in_sizes[2];

    char* ws = (char*)d_ws;
    auto alloc = [&](size_t bytes) -> char* {
        char* p = ws;
        ws += (bytes + 255) & ~(size_t)255;
        return p;
    };
    int*   sup_idx   = (int*)  alloc((size_t)EPISODES * LPAD * sizeof(int));
    int*   qry_idx   = (int*)  alloc((size_t)EPISODES * LPAD * sizeof(int));
    int*   sup_lab   = (int*)  alloc((size_t)EPISODES * LPAD * sizeof(int));
    int*   counts    = (int*)  alloc((size_t)EPISODES * 4 * sizeof(int));
    float* task_mean = (float*)alloc((size_t)EPISODES * DDIM * sizeof(float));
    float* pos_mean  = (float*)alloc((size_t)EPISODES * DDIM * sizeof(float));
    float* neg_mean  = (float*)alloc((size_t)EPISODES * DDIM * sizeof(float));
    float* vsol      = (float*)alloc((size_t)EPISODES * 2 * DDIM * sizeof(float));
    float* row_sums  = (float*)alloc((size_t)EPISODES * LPAD * sizeof(float));
    float* G0        = (float*)alloc((size_t)EPISODES * NS_CAP * NS_CAP * sizeof(float));
    (void)ws_size;
    (void)task_mean;

    k_seg<<<EPISODES, 256, 0, stream>>>(labels, is_query, bidx, N,
                                        sup_idx, qry_idx, sup_lab, counts);
    k_stats<<<EPISODES*2, 256, 0, stream>>>(X, sup_idx, sup_lab, counts,
                                            task_mean, pos_mean, neg_mean, row_sums);
    k_gram<<<EPISODES * NPAIRS, 256, 0, stream>>>(X, sup_idx, counts, G0);
    k_cgc<<<EPISODES * 2, 512, GL_F4 * sizeof(float4), stream>>>(
                                            X, G0, sup_idx, sup_lab, counts,
                                            row_sums, vsol);
    k_out<<<EPISODES*2, 256, 0, stream>>>(X, qry_idx, counts, pos_mean, neg_mean,
                                          vsol, log_scale, (float*)d_out);
}

// Round 8
// 356.778 us; speedup vs baseline: 2.4770x; 1.1116x over previous
//
#include <hip/hip_runtime.h>
#include <cstdint>
#include <cstddef>

#define EPISODES 128
#define LPAD     512
#define DDIM     512
#define NS_CAP   320
#define GTILE    64
#define NPAIRS   15          // 5*(5+1)/2 tile pairs (NS_CAP/GTILE = 5)
#define CG_ITERS 18
#define GL_F4    9536        // dynamic-LDS float4 capacity (152576 B)

__device__ __forceinline__ int lower_bound_dev(const int* __restrict__ a, int n, int key){
    int lo = 0, hi = n;
    while(lo < hi){
        int m = (lo + hi) >> 1;
        if(a[m] < key) lo = m + 1; else hi = m;
    }
    return lo;
}

__device__ __forceinline__ float4 f4add(float4 a, float4 b){
    return make_float4(a.x+b.x, a.y+b.y, a.z+b.z, a.w+b.w);
}
__device__ __forceinline__ float4 f4fma(float s, float4 a, float4 acc){
    return make_float4(acc.x + s*a.x, acc.y + s*a.y, acc.z + s*a.z, acc.w + s*a.w);
}
__device__ __forceinline__ float f4dot(float4 a, float4 b){
    return a.x*b.x + a.y*b.y + a.z*b.z + a.w*b.w;
}
__device__ __forceinline__ float f4sum(float4 a){ return (a.x+a.y)+(a.z+a.w); }

// ---------------------------------------------------------------------------
// Kernel 1a: per-episode segmentation + gather of indices/labels + counts.
// ---------------------------------------------------------------------------
__global__ __launch_bounds__(256) void k_seg(
        const int* __restrict__ labels, const int* __restrict__ is_query,
        const int* __restrict__ bidx, int N,
        int* __restrict__ sup_idx, int* __restrict__ qry_idx,
        int* __restrict__ sup_lab, int* __restrict__ counts)
{
    const int b    = blockIdx.x;
    const int tid  = threadIdx.x;
    const int lane = tid & 63;
    const int wave = tid >> 6;

    __shared__ int s_start, s_end;
    __shared__ int wq[4];
    __shared__ int s_runq, s_npos;

    if(tid == 0){
        s_start = lower_bound_dev(bidx, N, b);
        s_end   = lower_bound_dev(bidx, N, b + 1);
        s_runq  = 0;
        s_npos  = 0;
    }
    __syncthreads();
    const int start = s_start, end = s_end;

    for(int base = start; base < end; base += 256){
        int idx   = base + tid;
        bool valid = idx < end;
        int q   = valid ? is_query[idx] : 0;
        int lab = valid ? labels[idx]   : 0;
        unsigned long long m = __ballot(q == 1);
        if(lane == 0) wq[wave] = __popcll(m);
        __syncthreads();
        int woff = 0;
        for(int w = 0; w < wave; w++) woff += wq[w];
        int qbefore = __popcll(m & ((1ull << lane) - 1ull)) + woff;
        int runq0 = s_runq;
        int chunk_total = wq[0] + wq[1] + wq[2] + wq[3];
        if(valid){
            int pos_in_seg = idx - start;
            if(q){
                int qr = runq0 + qbefore;
                if(qr < LPAD) qry_idx[b * LPAD + qr] = idx;
            } else {
                int sr = pos_in_seg - runq0 - qbefore;
                if(sr < LPAD){
                    sup_idx[b * LPAD + sr] = idx;
                    sup_lab[b * LPAD + sr] = lab;
                    if(lab == 1) atomicAdd(&s_npos, 1);
                }
            }
        }
        __syncthreads();
        if(tid == 0) s_runq = runq0 + chunk_total;
        __syncthreads();
    }

    if(tid == 0){
        int nq = s_runq;
        int ns = (end - start) - nq;
        counts[b*4 + 0] = ns;
        counts[b*4 + 1] = nq;
        counts[b*4 + 2] = s_npos;
        counts[b*4 + 3] = ns - s_npos;
    }
}

// ---------------------------------------------------------------------------
// Kernel 1b: per-episode means + support row sums. 2 WGs per episode.
// ---------------------------------------------------------------------------
__global__ __launch_bounds__(256) void k_stats(
        const float* __restrict__ X,
        const int* __restrict__ sup_idx, const int* __restrict__ sup_lab,
        const int* __restrict__ counts,
        float* __restrict__ task_mean, float* __restrict__ pos_mean,
        float* __restrict__ neg_mean, float* __restrict__ row_sums)
{
    const int bid  = blockIdx.x;
    const int b    = bid >> 1;
    const int h    = bid & 1;
    const int tid  = threadIdx.x;
    const int lane = tid & 63;
    const int wave = tid >> 6;

    __shared__ int   sidx[NS_CAP];
    __shared__ float slabf[NS_CAP];
    __shared__ float4 pa[4][64];
    __shared__ float4 pp[4][64];

    const int ns   = counts[b*4 + 0];
    const int npos = counts[b*4 + 2];
    const int nneg = counts[b*4 + 3];
    const int nsb  = min(ns, NS_CAP);

    for(int s = tid; s < nsb; s += 256){
        sidx[s]  = sup_idx[b*LPAD + s];
        slabf[s] = (float)sup_lab[b*LPAD + s];
    }
    __syncthreads();

    const float4* X4 = (const float4*)X;
    const int colg = h*64 + (tid & 63);        // global float4 column
    const int rg   = tid >> 6;                 // row group (stride 4)

    float4 sa = make_float4(0.f,0.f,0.f,0.f);
    float4 sp = make_float4(0.f,0.f,0.f,0.f);
    int r = rg;
    for(; r + 12 < nsb; r += 16){
        int n0 = sidx[r], n1 = sidx[r+4], n2 = sidx[r+8], n3 = sidx[r+12];
        float l0 = slabf[r], l1 = slabf[r+4], l2 = slabf[r+8], l3 = slabf[r+12];
        float4 x0 = X4[(size_t)n0*128 + colg];
        float4 x1 = X4[(size_t)n1*128 + colg];
        float4 x2 = X4[(size_t)n2*128 + colg];
        float4 x3 = X4[(size_t)n3*128 + colg];
        sa = f4add(sa, f4add(f4add(x0,x1), f4add(x2,x3)));
        sp = f4fma(l0,x0, f4fma(l1,x1, f4fma(l2,x2, f4fma(l3,x3, sp))));
    }
    for(; r < nsb; r += 4){
        int n = sidx[r];
        float l = slabf[r];
        float4 x = X4[(size_t)n*128 + colg];
        sa = f4add(sa, x);
        sp = f4fma(l, x, sp);
    }
    pa[rg][tid & 63] = sa;
    pp[rg][tid & 63] = sp;
    __syncthreads();
    if(tid < 64){
        float4 A = f4add(f4add(pa[0][tid],pa[1][tid]), f4add(pa[2][tid],pa[3][tid]));
        float4 P = f4add(f4add(pp[0][tid],pp[1][tid]), f4add(pp[2][tid],pp[3][tid]));
        float4 Nn = make_float4(A.x-P.x, A.y-P.y, A.z-P.z, A.w-P.w);
        float ia = 1.f/(float)ns, ip = 1.f/(float)npos, in = 1.f/(float)nneg;
        int c = b*128 + h*64 + tid;
        ((float4*)task_mean)[c] = make_float4(A.x*ia, A.y*ia, A.z*ia, A.w*ia);
        ((float4*)pos_mean )[c] = make_float4(P.x*ip, P.y*ip, P.z*ip, P.w*ip);
        ((float4*)neg_mean )[c] = make_float4(Nn.x*in, Nn.y*in, Nn.z*in, Nn.w*in);
    }

    // Row sums for row half [r0, r1): float4, 2 rows per wave iteration.
    const int r0 = (nsb * h) >> 1;
    const int r1 = (nsb * (h + 1)) >> 1;
    for(int rr = r0 + wave; rr < r1; rr += 8){
        int rb = rr + 4;
        const float4* xr0 = (const float4*)(X + (size_t)sidx[rr]*DDIM);
        const float4* xr1 = (rb < r1) ? (const float4*)(X + (size_t)sidx[rb]*DDIM) : xr0;
        float4 a0 = xr0[lane], a1 = xr0[lane + 64];
        float4 b0 = xr1[lane], b1 = xr1[lane + 64];
        float s0 = f4sum(a0) + f4sum(a1);
        float s1 = f4sum(b0) + f4sum(b1);
        #pragma unroll
        for(int off = 32; off; off >>= 1){
            s0 += __shfl_xor(s0, off);
            s1 += __shfl_xor(s1, off);
        }
        if(lane == 0){
            row_sums[b * LPAD + rr] = s0;
            if(rb < r1) row_sums[b * LPAD + rb] = s1;
        }
    }
}

// ---------------------------------------------------------------------------
// Kernel 2: raw support Gram, float4 layout Gf4[(c>>2)*NS_CAP + t] with
// component (c&3) — exactly what k_cgc stages. NO zero-fill: entries with
// row c >= nsc are multiplied by u[c]=0 in k_cgc; cols t >= nsc never read.
// Double-buffered LDS staging (1 barrier/K-chunk, register prefetch),
// diagonal tiles stage a single tile (A == B), contiguous float4 G stores.
// ---------------------------------------------------------------------------
__global__ __launch_bounds__(256) void k_gram(
        const float* __restrict__ X, const int* __restrict__ sup_idx,
        const int* __restrict__ counts, float* __restrict__ G0)
{
    const int bid = blockIdx.x;
    const int b   = bid / NPAIRS;
    int tp = bid % NPAIRS;
    int ti = 0;
    while((ti+1)*(ti+2)/2 <= tp) ti++;
    const int tj  = tp - ti*(ti+1)/2;          // ti >= tj
    const int tid = threadIdx.x;
    const int ty  = tid >> 4, tx = tid & 15;

    const int ns  = counts[b*4 + 0];
    const int nsc = min(ns, NS_CAP);
    if(ti * GTILE >= nsc) return;              // tile fully beyond support: no work

    const bool diag = (ti == tj);

    __shared__ float Sb[2][2][32*68];          // [buf][A/B][(4c4+j)*68 + row]
    __shared__ int ia[GTILE], ib[GTILE];

    if(tid < GTILE)        ia[tid]    = sup_idx[b*LPAD + min(ti*GTILE + tid,      nsc-1)];
    else if(tid < 2*GTILE) ib[tid-64] = sup_idx[b*LPAD + min(tj*GTILE + (tid-64), nsc-1)];
    __syncthreads();

    // staging coords: thread covers f = tid and f = tid+256
    const int r0 = tid >> 3,  c4s = tid & 7;   // rows 0..31
    const int r1 = r0 + 32;                    // rows 32..63
    const float* a0p = X + (size_t)ia[r0]*DDIM + 4*c4s;
    const float* a1p = X + (size_t)ia[r1]*DDIM + 4*c4s;
    const float* b0p = X + (size_t)ib[r0]*DDIM + 4*c4s;
    const float* b1p = X + (size_t)ib[r1]*DDIM + 4*c4s;

    float acc[4][4];
    #pragma unroll
    for(int a = 0; a < 4; a++)
        #pragma unroll
        for(int c = 0; c < 4; c++) acc[a][c] = 0.f;

    float4 xa0 = *(const float4*)a0p;
    float4 xa1 = *(const float4*)a1p;
    float4 xb0 = make_float4(0,0,0,0), xb1 = make_float4(0,0,0,0);
    if(!diag){ xb0 = *(const float4*)b0p; xb1 = *(const float4*)b1p; }
    {
        float* A = Sb[0][0];
        A[(4*c4s+0)*68+r0]=xa0.x; A[(4*c4s+1)*68+r0]=xa0.y;
        A[(4*c4s+2)*68+r0]=xa0.z; A[(4*c4s+3)*68+r0]=xa0.w;
        A[(4*c4s+0)*68+r1]=xa1.x; A[(4*c4s+1)*68+r1]=xa1.y;
        A[(4*c4s+2)*68+r1]=xa1.z; A[(4*c4s+3)*68+r1]=xa1.w;
        if(!diag){
            float* B = Sb[0][1];
            B[(4*c4s+0)*68+r0]=xb0.x; B[(4*c4s+1)*68+r0]=xb0.y;
            B[(4*c4s+2)*68+r0]=xb0.z; B[(4*c4s+3)*68+r0]=xb0.w;
            B[(4*c4s+0)*68+r1]=xb1.x; B[(4*c4s+1)*68+r1]=xb1.y;
            B[(4*c4s+2)*68+r1]=xb1.z; B[(4*c4s+3)*68+r1]=xb1.w;
        }
    }
    __syncthreads();

    for(int k0i = 0; k0i < 16; k0i++){
        const int cur = k0i & 1;
        if(k0i < 15){
            const int off = (k0i + 1) * 32;
            xa0 = *(const float4*)(a0p + off);
            xa1 = *(const float4*)(a1p + off);
            if(!diag){
                xb0 = *(const float4*)(b0p + off);
                xb1 = *(const float4*)(b1p + off);
            }
        }
        const float* A = Sb[cur][0];
        const float* B = diag ? Sb[cur][0] : Sb[cur][1];
        #pragma unroll 8
        for(int k = 0; k < 32; k++){
            float4 af = *(const float4*)&A[k*68 + 4*ty];
            float4 bf = *(const float4*)&B[k*68 + 4*tx];
            acc[0][0] += af.x*bf.x; acc[0][1] += af.x*bf.y; acc[0][2] += af.x*bf.z; acc[0][3] += af.x*bf.w;
            acc[1][0] += af.y*bf.x; acc[1][1] += af.y*bf.y; acc[1][2] += af.y*bf.z; acc[1][3] += af.y*bf.w;
            acc[2][0] += af.z*bf.x; acc[2][1] += af.z*bf.y; acc[2][2] += af.z*bf.z; acc[2][3] += af.z*bf.w;
            acc[3][0] += af.w*bf.x; acc[3][1] += af.w*bf.y; acc[3][2] += af.w*bf.z; acc[3][3] += af.w*bf.w;
        }
        if(k0i < 15){
            float* An = Sb[cur^1][0];
            An[(4*c4s+0)*68+r0]=xa0.x; An[(4*c4s+1)*68+r0]=xa0.y;
            An[(4*c4s+2)*68+r0]=xa0.z; An[(4*c4s+3)*68+r0]=xa0.w;
            An[(4*c4s+0)*68+r1]=xa1.x; An[(4*c4s+1)*68+r1]=xa1.y;
            An[(4*c4s+2)*68+r1]=xa1.z; An[(4*c4s+3)*68+r1]=xa1.w;
            if(!diag){
                float* Bn = Sb[cur^1][1];
                Bn[(4*c4s+0)*68+r0]=xb0.x; Bn[(4*c4s+1)*68+r0]=xb0.y;
                Bn[(4*c4s+2)*68+r0]=xb0.z; Bn[(4*c4s+3)*68+r0]=xb0.w;
                Bn[(4*c4s+0)*68+r1]=xb1.x; Bn[(4*c4s+1)*68+r1]=xb1.y;
                Bn[(4*c4s+2)*68+r1]=xb1.z; Bn[(4*c4s+3)*68+r1]=xb1.w;
            }
        }
        __syncthreads();
    }

    // G stores, float4 layout: Gf4[(c>>2)*NS_CAP + t], component c&3.
    float4* Gf4 = (float4*)(G0 + (size_t)b * NS_CAP * NS_CAP);
    // direct block: c-quad = ti*16+ty (components a), t = tj*64+4tx+jc
    #pragma unroll
    for(int jc = 0; jc < 4; jc++){
        float4 v = make_float4(acc[0][jc], acc[1][jc], acc[2][jc], acc[3][jc]);
        Gf4[(size_t)(ti*16 + ty)*NS_CAP + tj*GTILE + 4*tx + jc] = v;
    }
    // mirror block (G symmetric): c-quad = tj*16+tx (components jc), t = ti*64+4ty+a
    if(!diag){
        #pragma unroll
        for(int a = 0; a < 4; a++){
            float4 v = make_float4(acc[a][0], acc[a][1], acc[a][2], acc[a][3]);
            Gf4[(size_t)(tj*16 + tx)*NS_CAP + ti*GTILE + 4*ty + a] = v;
        }
    }
}

// ---------------------------------------------------------------------------
// Kernel 3: coefficient-space Chronopoulos-Gear CG with the Gram cached in
// dynamic LDS (compact stride nsc). 3 barriers/iteration.
// ---------------------------------------------------------------------------
extern __shared__ float4 gl4[];                // GL_F4 float4 (152576 B)

__global__ __launch_bounds__(512, 2) void k_cgc(
        const float* __restrict__ X, const float* __restrict__ G0,
        const int* __restrict__ sup_idx, const int* __restrict__ sup_lab,
        const int* __restrict__ counts, const float* __restrict__ row_sums,
        float* __restrict__ vout)
{
    const int bid  = blockIdx.x;
    const int sys  = ((bid & 7) << 5) | (bid >> 3);   // pair-local XCD swizzle
    const int b    = sys >> 1;
    const int cls  = sys & 1;
    const int tid  = threadIdx.x;
    const int lane = tid & 63;
    const int wave = tid >> 6;

    __shared__ __align__(16) float u[NS_CAP];
    __shared__ int   idx_l[NS_CAP];
    __shared__ float redA[8][5];

    const int ns   = counts[b*4 + 0];
    const int nsc  = min(ns, NS_CAP);
    const int ncls = cls ? counts[b*4 + 2] : counts[b*4 + 3];
    const float c_task = 0.9f / (float)(ns - 1);
    const float c_cls  = 0.1f / (float)(ncls - 1);
    const float inv_ns = 1.f / (float)ns;
    const float inv_nc = 1.f / (float)ncls;
    const float4* G4 = (const float4*)(G0 + (size_t)b * NS_CAP * NS_CAP);
    const float4* u4 = (const float4*)u;
    const int nf4 = (nsc + 3) >> 2;
    const int c4l = min(nf4, GL_F4 / nsc);     // Gram blocks cached in LDS

    const bool mth = tid < NS_CAP;
    const bool own = tid < nsc;
    float mfl = 0.f, sraw = 0.f;
    if(own){
        mfl  = (sup_lab[b*LPAD + tid] == cls) ? 1.f : 0.f;
        sraw = row_sums[b*LPAD + tid];
    }
    for(int s = tid; s < nsc; s += 512) idx_l[s] = sup_idx[b*LPAD + s];

    // Stage Gram blocks into LDS: gl4[c4*nsc + t] = G4[c4*NS_CAP + t]
    {
        const int total = c4l * nsc;
        for(int i = tid; i < total; i += 512){
            int c4 = i / nsc;
            int t  = i - c4 * nsc;
            gl4[i] = G4[(size_t)c4 * NS_CAP + t];
        }
    }
    __syncthreads();

    auto reduce5 = [&](float v0, float v1, float v2, float v3, float v4,
                       float* out){
        #pragma unroll
        for(int off = 32; off; off >>= 1){
            v0 += __shfl_xor(v0, off); v1 += __shfl_xor(v1, off);
            v2 += __shfl_xor(v2, off); v3 += __shfl_xor(v3, off);
            v4 += __shfl_xor(v4, off);
        }
        __syncthreads();
        if(lane == 0){
            redA[wave][0] = v0; redA[wave][1] = v1; redA[wave][2] = v2;
            redA[wave][3] = v3; redA[wave][4] = v4;
        }
        __syncthreads();
        #pragma unroll
        for(int k = 0; k < 5; k++){
            float s = 0.f;
            #pragma unroll
            for(int w = 0; w < 8; w++) s += redA[w][k];
            out[k] = s;
        }
    };

    // tq[tid] = sum_c u[c] * G(c, tid); requires u published + barrier.
    auto matvec = [&]() -> float {
        float s0 = 0.f, s1 = 0.f, s2 = 0.f, s3 = 0.f;
        if(own){
            const float4* gq = gl4 + tid;
            int c4 = 0;
            for(; c4 + 8 <= c4l; c4 += 8){
                float4 g0 = gq[(c4+0)*nsc], g1 = gq[(c4+1)*nsc];
                float4 g2 = gq[(c4+2)*nsc], g3 = gq[(c4+3)*nsc];
                float4 g4 = gq[(c4+4)*nsc], g5 = gq[(c4+5)*nsc];
                float4 g6 = gq[(c4+6)*nsc], g7 = gq[(c4+7)*nsc];
                s0 += f4dot(g0, u4[c4+0]); s1 += f4dot(g1, u4[c4+1]);
                s2 += f4dot(g2, u4[c4+2]); s3 += f4dot(g3, u4[c4+3]);
                s0 += f4dot(g4, u4[c4+4]); s1 += f4dot(g5, u4[c4+5]);
                s2 += f4dot(g6, u4[c4+6]); s3 += f4dot(g7, u4[c4+7]);
            }
            for(; c4 < c4l; c4++) s0 += f4dot(gq[c4*nsc], u4[c4]);
            // overflow blocks from global (rare): ILP-8
            for(; c4 + 8 <= nf4; c4 += 8){
                float4 g[8];
                #pragma unroll
                for(int j = 0; j < 8; j++) g[j] = G4[(size_t)(c4+j)*NS_CAP + tid];
                #pragma unroll
                for(int j = 0; j < 8; j++){
                    float d = f4dot(g[j], u4[c4+j]);
                    if((j & 3) == 0) s0 += d; else if((j & 3) == 1) s1 += d;
                    else if((j & 3) == 2) s2 += d; else s3 += d;
                }
            }
            for(; c4 < nf4; c4++) s0 += f4dot(G4[(size_t)c4*NS_CAP + tid], u4[c4]);
        }
        return (s0 + s1) + (s2 + s3);
    };

    // init: r0 = -10 * A * 1  (t-image of p=1_D is the row-sum vector)
    float out5[5];
    reduce5(sraw, mfl * sraw, 0.f, 0.f, 0.f, out5);
    float A0 = out5[0] * inv_ns, A1 = out5[1] * inv_nc;
    float cr = own ? -10.f * (c_task*(sraw - A0) + mfl*c_cls*(sraw - A1)) : 0.f;
    if(mth) u[tid] = own ? cr : 0.f;
    __syncthreads();
    float tr = matvec();

    float cp = 0.f, tp = 0.f, cq = 0.f, tq = 0.f, cx = 0.f;
    float gamma_old = 1.f, alpha_old = 1.f;
    bool first = true;

    for(int it = 0; it < CG_ITERS; ++it){
        // bundle: S1=Σtr, S2=Σm·tr, S3=Σtr², S4=Σm·tr², S5=Σtr·cr
        reduce5(tr, mfl*tr, tr*tr, mfl*tr*tr, tr*cr, out5);
        A0 = out5[0] * inv_ns; A1 = out5[1] * inv_nc;
        float gamma = out5[4];                               // (r,r)
        float delta = 0.1f*gamma + c_task*(out5[2] - out5[0]*A0)
                                 + c_cls *(out5[3] - out5[1]*A1);  // (r,Mr)
        if(gamma < 1e-26f) break;
        float ur = own ? (c_task*(tr - A0) + mfl*c_cls*(tr - A1)) : 0.f;
        float cw = 0.1f*cr + ur;                             // c of w = M r
        if(mth) u[tid] = ur;
        __syncthreads();
        float gv = matvec();                                 // G0 * u_r
        float tw = 0.1f*tr + gv;                             // t of w
        float beta  = first ? 0.f : gamma / gamma_old;
        float alpha = first ? gamma / delta
                            : gamma / (delta - beta * gamma / alpha_old);
        cp = cr + beta * cp;  tp = tr + beta * tp;
        cq = cw + beta * cq;  tq = tw + beta * tq;
        cx += alpha * cp;
        cr -= alpha * cq;     tr -= alpha * tq;
        gamma_old = gamma; alpha_old = alpha; first = false;
    }

    // v = 10*1 + Xs^T c_x : float4, 4-way row split, gl4 reused as scratch.
    __syncthreads();
    if(mth) u[tid] = own ? cx : 0.f;
    __syncthreads();
    const float4* X4 = (const float4*)X;
    const int f4c = tid & 127;
    const int rg  = tid >> 7;                  // 0..3
    float4 acc = make_float4(0.f,0.f,0.f,0.f);
    int s = rg;
    for(; s + 12 < nsc; s += 16){
        int n0 = idx_l[s], n1 = idx_l[s+4], n2 = idx_l[s+8], n3 = idx_l[s+12];
        float w0 = u[s], w1 = u[s+4], w2 = u[s+8], w3 = u[s+12];
        float4 x0 = X4[(size_t)n0*128 + f4c];
        float4 x1 = X4[(size_t)n1*128 + f4c];
        float4 x2 = X4[(size_t)n2*128 + f4c];
        float4 x3 = X4[(size_t)n3*128 + f4c];
        acc = f4fma(w0,x0, f4fma(w1,x1, f4fma(w2,x2, f4fma(w3,x3, acc))));
    }
    for(; s < nsc; s += 4)
        acc = f4fma(u[s], X4[(size_t)idx_l[s]*128 + f4c], acc);
    gl4[rg*128 + f4c] = acc;
    __syncthreads();
    if(tid < 128){
        float4 v = f4add(f4add(gl4[tid], gl4[128+tid]),
                         f4add(gl4[256+tid], gl4[384+tid]));
        v.x += 10.f; v.y += 10.f; v.z += 10.f; v.w += 10.f;
        ((float4*)vout)[(size_t)sys * 128 + tid] = v;
    }
}

// ---------------------------------------------------------------------------
// Kernel 4: per-query output. 2 WGs per episode; float4 row loads.
// ---------------------------------------------------------------------------
__global__ __launch_bounds__(256) void k_out(
        const float* __restrict__ X,
        const int* __restrict__ qry_idx, const int* __restrict__ counts,
        const float* __restrict__ pos_mean, const float* __restrict__ neg_mean,
        const float* __restrict__ vsol, const float* __restrict__ log_scale,
        float* __restrict__ out)
{
    const int bid  = blockIdx.x;
    const int b    = bid >> 1;
    const int h    = bid & 1;
    const int tid  = threadIdx.x;
    const int lane = tid & 63;
    const int wave = tid >> 6;

    __shared__ __align__(16) float vpos[DDIM];
    __shared__ __align__(16) float vneg[DDIM];
    __shared__ float red4[4][4];
    __shared__ float sc[4];

    const int nq  = counts[b*4 + 1];
    const int nqc = min(nq, LPAD);
    const float scale = expf(log_scale[0]);

    float pm0 = pos_mean[b*DDIM + tid], pm1 = pos_mean[b*DDIM + tid + 256];
    float nm0 = neg_mean[b*DDIM + tid], nm1 = neg_mean[b*DDIM + tid + 256];
    float vp0 = vsol[(size_t)(b*2 + 1) * DDIM + tid];
    float vp1 = vsol[(size_t)(b*2 + 1) * DDIM + tid + 256];
    float vn0 = vsol[(size_t)(b*2 + 0) * DDIM + tid];
    float vn1 = vsol[(size_t)(b*2 + 0) * DDIM + tid + 256];
    vpos[tid] = vp0; vpos[tid + 256] = vp1;
    vneg[tid] = vn0; vneg[tid + 256] = vn1;

    float smp = pm0 + pm1;
    float smn = nm0 + nm1;
    float mvp = pm0 * vp0 + pm1 * vp1;
    float mvn = nm0 * vn0 + nm1 * vn1;
    #pragma unroll
    for(int off = 32; off; off >>= 1){
        smp += __shfl_xor(smp, off);
        smn += __shfl_xor(smn, off);
        mvp += __shfl_xor(mvp, off);
        mvn += __shfl_xor(mvn, off);
    }
    if(lane == 0){
        red4[wave][0] = smp; red4[wave][1] = smn;
        red4[wave][2] = mvp; red4[wave][3] = mvn;
    }
    __syncthreads();
    if(tid < 4) sc[tid] = red4[0][tid] + red4[1][tid] + red4[2][tid] + red4[3][tid];
    __syncthreads();

    const float4* vp4 = (const float4*)vpos;
    const float4* vn4 = (const float4*)vneg;
    for(int r = wave + 4*h; r < nqc; r += 8){
        int n = qry_idx[b * LPAD + r];
        const float4* xr = (const float4*)(X + (size_t)n * DDIM);
        float4 x0 = xr[lane], x1 = xr[lane + 64];
        float tp = f4dot(x0, vp4[lane]) + f4dot(x1, vp4[lane + 64]);
        float tn = f4dot(x0, vn4[lane]) + f4dot(x1, vn4[lane + 64]);
        float sx = f4sum(x0) + f4sum(x1);
        #pragma unroll
        for(int off = 32; off; off >>= 1){
            tp += __shfl_xor(tp, off);
            tn += __shfl_xor(tn, off);
            sx += __shfl_xor(sx, off);
        }
        if(lane == 0){
            float mp = (tp - sc[2]) * (sx - sc[0]);
            float mn = (tn - sc[3]) * (sx - sc[1]);
            ((float2*)out)[(size_t)b * LPAD + r] = make_float2(mn * scale, mp * scale);
        }
    }
    const int lo = max(nqc, h * 256), hi = (h + 1) * 256;
    for(int r = lo + tid; r < hi; r += 256)
        ((float2*)out)[(size_t)b * LPAD + r] = make_float2(0.f, 0.f);
}

// ---------------------------------------------------------------------------
extern "C" void kernel_launch(void* const* d_in, const int* in_sizes, int n_in,
                              void* d_out, int out_size, void* d_ws, size_t ws_size,
                              hipStream_t stream)
{
    const float* X         = (const float*)d_in[0];
    const float* log_scale = (const float*)d_in[1];
    const int*   labels    = (const int*)d_in[2];
    const int*   is_query  = (const int*)d_in[3];
    const int*   bidx      = (const int*)d_in[4];
    const int N = in_sizes[2];

    char* ws = (char*)d_ws;
    auto alloc = [&](size_t bytes) -> char* {
        char* p = ws;
        ws += (bytes + 255) & ~(size_t)255;
        return p;
    };
    int*   sup_idx   = (int*)  alloc((size_t)EPISODES * LPAD * sizeof(int));
    int*   qry_idx   = (int*)  alloc((size_t)EPISODES * LPAD * sizeof(int));
    int*   sup_lab   = (int*)  alloc((size_t)EPISODES * LPAD * sizeof(int));
    int*   counts    = (int*)  alloc((size_t)EPISODES * 4 * sizeof(int));
    float* task_mean = (float*)alloc((size_t)EPISODES * DDIM * sizeof(float));
    float* pos_mean  = (float*)alloc((size_t)EPISODES * DDIM * sizeof(float));
    float* neg_mean  = (float*)alloc((size_t)EPISODES * DDIM * sizeof(float));
    float* vsol      = (float*)alloc((size_t)EPISODES * 2 * DDIM * sizeof(float));
    float* row_sums  = (float*)alloc((size_t)EPISODES * LPAD * sizeof(float));
    float* G0        = (float*)alloc((size_t)EPISODES * NS_CAP * NS_CAP * sizeof(float));
    (void)ws_size;
    (void)task_mean;

    k_seg<<<EPISODES, 256, 0, stream>>>(labels, is_query, bidx, N,
                                        sup_idx, qry_idx, sup_lab, counts);
    k_stats<<<EPISODES*2, 256, 0, stream>>>(X, sup_idx, sup_lab, counts,
                                            task_mean, pos_mean, neg_mean, row_sums);
    k_gram<<<EPISODES * NPAIRS, 256, 0, stream>>>(X, sup_idx, counts, G0);
    k_cgc<<<EPISODES * 2, 512, GL_F4 * sizeof(float4), stream>>>(
                                            X, G0, sup_idx, sup_lab, counts,
                                            row_sums, vsol);
    k_out<<<EPISODES*2, 256, 0, stream>>>(X, qry_idx, counts, pos_mean, neg_mean,
                                          vsol, log_scale, (float*)d_out);
}

// Round 9
// 333.392 us; speedup vs baseline: 2.6508x; 1.0701x over previous
//
#include <hip/hip_runtime.h>
#include <cstdint>
#include <cstddef>

#define EPISODES 128
#define LPAD     512
#define DDIM     512
#define NS_CAP   320
#define GTILE    64
#define NPAIRS   15          // 5*(5+1)/2 tile pairs (NS_CAP/GTILE = 5)
#define CG_ITERS 14
#define GL_F4    10016       // dynamic-LDS float4 capacity (160256 B)

__device__ __forceinline__ int lower_bound_dev(const int* __restrict__ a, int n, int key){
    int lo = 0, hi = n;
    while(lo < hi){
        int m = (lo + hi) >> 1;
        if(a[m] < key) lo = m + 1; else hi = m;
    }
    return lo;
}

__device__ __forceinline__ float4 f4add(float4 a, float4 b){
    return make_float4(a.x+b.x, a.y+b.y, a.z+b.z, a.w+b.w);
}
__device__ __forceinline__ float4 f4fma(float s, float4 a, float4 acc){
    return make_float4(acc.x + s*a.x, acc.y + s*a.y, acc.z + s*a.z, acc.w + s*a.w);
}
__device__ __forceinline__ float f4dot(float4 a, float4 b){
    return a.x*b.x + a.y*b.y + a.z*b.z + a.w*b.w;
}
__device__ __forceinline__ float f4sum(float4 a){ return (a.x+a.y)+(a.z+a.w); }

// ---------------------------------------------------------------------------
// Kernel 1: fused segmentation + means + per-half row sums.
// 2 WGs per episode (h = dim half). Both WGs redundantly run the cheap
// ballot scan (keeps sidx/slab in LDS); h==0 publishes indices/counts.
// Row sums computed IN the means pass: wave-reduce of f4sum per loaded row,
// stored per-half in row_sums2[(b*LPAD+r)*2 + h].
// ---------------------------------------------------------------------------
__global__ __launch_bounds__(256) void k_prep(
        const int* __restrict__ labels, const int* __restrict__ is_query,
        const int* __restrict__ bidx, const float* __restrict__ X, int N,
        int* __restrict__ sup_idx, int* __restrict__ qry_idx,
        int* __restrict__ sup_lab, int* __restrict__ counts,
        float* __restrict__ task_mean, float* __restrict__ pos_mean,
        float* __restrict__ neg_mean, float* __restrict__ row_sums2)
{
    const int bid  = blockIdx.x;
    const int b    = bid >> 1;
    const int h    = bid & 1;
    const int tid  = threadIdx.x;
    const int lane = tid & 63;
    const int wave = tid >> 6;

    __shared__ int s_start, s_end;
    __shared__ int wq[4];
    __shared__ int s_runq, s_npos;
    __shared__ int   sidx[NS_CAP];
    __shared__ float slabf[NS_CAP];
    __shared__ float4 pa[4][64];
    __shared__ float4 pp[4][64];

    if(tid == 0){
        s_start = lower_bound_dev(bidx, N, b);
        s_end   = lower_bound_dev(bidx, N, b + 1);
        s_runq  = 0;
        s_npos  = 0;
    }
    __syncthreads();
    const int start = s_start, end = s_end;

    for(int base = start; base < end; base += 256){
        int idx   = base + tid;
        bool valid = idx < end;
        int q   = valid ? is_query[idx] : 0;
        int lab = valid ? labels[idx]   : 0;
        unsigned long long m = __ballot(q == 1);
        if(lane == 0) wq[wave] = __popcll(m);
        __syncthreads();
        int woff = 0;
        for(int w = 0; w < wave; w++) woff += wq[w];
        int qbefore = __popcll(m & ((1ull << lane) - 1ull)) + woff;
        int runq0 = s_runq;
        int chunk_total = wq[0] + wq[1] + wq[2] + wq[3];
        if(valid){
            int pos_in_seg = idx - start;
            if(q){
                int qr = runq0 + qbefore;
                if(h == 0 && qr < LPAD) qry_idx[b * LPAD + qr] = idx;
            } else {
                int sr = pos_in_seg - runq0 - qbefore;
                if(sr < LPAD){
                    if(h == 0){
                        sup_idx[b * LPAD + sr] = idx;
                        sup_lab[b * LPAD + sr] = lab;
                    }
                    if(sr < NS_CAP){ sidx[sr] = idx; slabf[sr] = (float)lab; }
                    if(lab == 1) atomicAdd(&s_npos, 1);
                }
            }
        }
        __syncthreads();
        if(tid == 0) s_runq = runq0 + chunk_total;
        __syncthreads();
    }

    const int nq   = s_runq;
    const int ns   = (end - start) - nq;
    const int npos = s_npos;
    const int nneg = ns - npos;
    if(h == 0 && tid == 0){
        counts[b*4 + 0] = ns;
        counts[b*4 + 1] = nq;
        counts[b*4 + 2] = npos;
        counts[b*4 + 3] = nneg;
    }
    const int nsb = min(ns, NS_CAP);

    // Fused means (dim half h) + per-half row sums.
    const float4* X4 = (const float4*)X;
    const int colg = h*64 + lane;              // float4 column for this WG
    float4 sa = make_float4(0.f,0.f,0.f,0.f);
    float4 sp = make_float4(0.f,0.f,0.f,0.f);
    int r = wave;
    for(; r + 12 < nsb; r += 16){
        int n0 = sidx[r], n1 = sidx[r+4], n2 = sidx[r+8], n3 = sidx[r+12];
        float l0 = slabf[r], l1 = slabf[r+4], l2 = slabf[r+8], l3 = slabf[r+12];
        float4 x0 = X4[(size_t)n0*128 + colg];
        float4 x1 = X4[(size_t)n1*128 + colg];
        float4 x2 = X4[(size_t)n2*128 + colg];
        float4 x3 = X4[(size_t)n3*128 + colg];
        sa = f4add(sa, f4add(f4add(x0,x1), f4add(x2,x3)));
        sp = f4fma(l0,x0, f4fma(l1,x1, f4fma(l2,x2, f4fma(l3,x3, sp))));
        float r0s = f4sum(x0), r1s = f4sum(x1), r2s = f4sum(x2), r3s = f4sum(x3);
        #pragma unroll
        for(int off = 32; off; off >>= 1){
            r0s += __shfl_xor(r0s, off); r1s += __shfl_xor(r1s, off);
            r2s += __shfl_xor(r2s, off); r3s += __shfl_xor(r3s, off);
        }
        if(lane == 0){
            row_sums2[(b*LPAD + r   )*2 + h] = r0s;
            row_sums2[(b*LPAD + r+4 )*2 + h] = r1s;
            row_sums2[(b*LPAD + r+8 )*2 + h] = r2s;
            row_sums2[(b*LPAD + r+12)*2 + h] = r3s;
        }
    }
    for(; r < nsb; r += 4){
        int n = sidx[r];
        float l = slabf[r];
        float4 x = X4[(size_t)n*128 + colg];
        sa = f4add(sa, x);
        sp = f4fma(l, x, sp);
        float rs = f4sum(x);
        #pragma unroll
        for(int off = 32; off; off >>= 1) rs += __shfl_xor(rs, off);
        if(lane == 0) row_sums2[(b*LPAD + r)*2 + h] = rs;
    }
    pa[wave][lane] = sa;
    pp[wave][lane] = sp;
    __syncthreads();
    if(tid < 64){
        float4 A = f4add(f4add(pa[0][tid],pa[1][tid]), f4add(pa[2][tid],pa[3][tid]));
        float4 P = f4add(f4add(pp[0][tid],pp[1][tid]), f4add(pp[2][tid],pp[3][tid]));
        float4 Nn = make_float4(A.x-P.x, A.y-P.y, A.z-P.z, A.w-P.w);
        float ia = 1.f/(float)ns, ip = 1.f/(float)npos, in = 1.f/(float)nneg;
        int c = b*128 + h*64 + tid;
        ((float4*)task_mean)[c] = make_float4(A.x*ia, A.y*ia, A.z*ia, A.w*ia);
        ((float4*)pos_mean )[c] = make_float4(P.x*ip, P.y*ip, P.z*ip, P.w*ip);
        ((float4*)neg_mean )[c] = make_float4(Nn.x*in, Nn.y*in, Nn.z*in, Nn.w*in);
    }
}

// ---------------------------------------------------------------------------
// Kernel 2: raw support Gram, float4 layout Gf4[(c>>2)*NS_CAP + t] with
// component (c&3). No zero-fill (k_cgc multiplies c>=nsc rows by u=0).
// Double-buffered LDS staging, diag tiles single-staged, float4 G stores.
// ---------------------------------------------------------------------------
__global__ __launch_bounds__(256) void k_gram(
        const float* __restrict__ X, const int* __restrict__ sup_idx,
        const int* __restrict__ counts, float* __restrict__ G0)
{
    const int bid = blockIdx.x;
    const int b   = bid / NPAIRS;
    int tp = bid % NPAIRS;
    int ti = 0;
    while((ti+1)*(ti+2)/2 <= tp) ti++;
    const int tj  = tp - ti*(ti+1)/2;          // ti >= tj
    const int tid = threadIdx.x;
    const int ty  = tid >> 4, tx = tid & 15;

    const int ns  = counts[b*4 + 0];
    const int nsc = min(ns, NS_CAP);
    if(ti * GTILE >= nsc) return;

    const bool diag = (ti == tj);

    __shared__ float Sb[2][2][32*68];
    __shared__ int ia[GTILE], ib[GTILE];

    if(tid < GTILE)        ia[tid]    = sup_idx[b*LPAD + min(ti*GTILE + tid,      nsc-1)];
    else if(tid < 2*GTILE) ib[tid-64] = sup_idx[b*LPAD + min(tj*GTILE + (tid-64), nsc-1)];
    __syncthreads();

    const int r0 = tid >> 3,  c4s = tid & 7;
    const int r1 = r0 + 32;
    const float* a0p = X + (size_t)ia[r0]*DDIM + 4*c4s;
    const float* a1p = X + (size_t)ia[r1]*DDIM + 4*c4s;
    const float* b0p = X + (size_t)ib[r0]*DDIM + 4*c4s;
    const float* b1p = X + (size_t)ib[r1]*DDIM + 4*c4s;

    float acc[4][4];
    #pragma unroll
    for(int a = 0; a < 4; a++)
        #pragma unroll
        for(int c = 0; c < 4; c++) acc[a][c] = 0.f;

    float4 xa0 = *(const float4*)a0p;
    float4 xa1 = *(const float4*)a1p;
    float4 xb0 = make_float4(0,0,0,0), xb1 = make_float4(0,0,0,0);
    if(!diag){ xb0 = *(const float4*)b0p; xb1 = *(const float4*)b1p; }
    {
        float* A = Sb[0][0];
        A[(4*c4s+0)*68+r0]=xa0.x; A[(4*c4s+1)*68+r0]=xa0.y;
        A[(4*c4s+2)*68+r0]=xa0.z; A[(4*c4s+3)*68+r0]=xa0.w;
        A[(4*c4s+0)*68+r1]=xa1.x; A[(4*c4s+1)*68+r1]=xa1.y;
        A[(4*c4s+2)*68+r1]=xa1.z; A[(4*c4s+3)*68+r1]=xa1.w;
        if(!diag){
            float* B = Sb[0][1];
            B[(4*c4s+0)*68+r0]=xb0.x; B[(4*c4s+1)*68+r0]=xb0.y;
            B[(4*c4s+2)*68+r0]=xb0.z; B[(4*c4s+3)*68+r0]=xb0.w;
            B[(4*c4s+0)*68+r1]=xb1.x; B[(4*c4s+1)*68+r1]=xb1.y;
            B[(4*c4s+2)*68+r1]=xb1.z; B[(4*c4s+3)*68+r1]=xb1.w;
        }
    }
    __syncthreads();

    for(int k0i = 0; k0i < 16; k0i++){
        const int cur = k0i & 1;
        if(k0i < 15){
            const int off = (k0i + 1) * 32;
            xa0 = *(const float4*)(a0p + off);
            xa1 = *(const float4*)(a1p + off);
            if(!diag){
                xb0 = *(const float4*)(b0p + off);
                xb1 = *(const float4*)(b1p + off);
            }
        }
        const float* A = Sb[cur][0];
        const float* B = diag ? Sb[cur][0] : Sb[cur][1];
        #pragma unroll 8
        for(int k = 0; k < 32; k++){
            float4 af = *(const float4*)&A[k*68 + 4*ty];
            float4 bf = *(const float4*)&B[k*68 + 4*tx];
            acc[0][0] += af.x*bf.x; acc[0][1] += af.x*bf.y; acc[0][2] += af.x*bf.z; acc[0][3] += af.x*bf.w;
            acc[1][0] += af.y*bf.x; acc[1][1] += af.y*bf.y; acc[1][2] += af.y*bf.z; acc[1][3] += af.y*bf.w;
            acc[2][0] += af.z*bf.x; acc[2][1] += af.z*bf.y; acc[2][2] += af.z*bf.z; acc[2][3] += af.z*bf.w;
            acc[3][0] += af.w*bf.x; acc[3][1] += af.w*bf.y; acc[3][2] += af.w*bf.z; acc[3][3] += af.w*bf.w;
        }
        if(k0i < 15){
            float* An = Sb[cur^1][0];
            An[(4*c4s+0)*68+r0]=xa0.x; An[(4*c4s+1)*68+r0]=xa0.y;
            An[(4*c4s+2)*68+r0]=xa0.z; An[(4*c4s+3)*68+r0]=xa0.w;
            An[(4*c4s+0)*68+r1]=xa1.x; An[(4*c4s+1)*68+r1]=xa1.y;
            An[(4*c4s+2)*68+r1]=xa1.z; An[(4*c4s+3)*68+r1]=xa1.w;
            if(!diag){
                float* Bn = Sb[cur^1][1];
                Bn[(4*c4s+0)*68+r0]=xb0.x; Bn[(4*c4s+1)*68+r0]=xb0.y;
                Bn[(4*c4s+2)*68+r0]=xb0.z; Bn[(4*c4s+3)*68+r0]=xb0.w;
                Bn[(4*c4s+0)*68+r1]=xb1.x; Bn[(4*c4s+1)*68+r1]=xb1.y;
                Bn[(4*c4s+2)*68+r1]=xb1.z; Bn[(4*c4s+3)*68+r1]=xb1.w;
            }
        }
        __syncthreads();
    }

    float4* Gf4 = (float4*)(G0 + (size_t)b * NS_CAP * NS_CAP);
    #pragma unroll
    for(int jc = 0; jc < 4; jc++){
        float4 v = make_float4(acc[0][jc], acc[1][jc], acc[2][jc], acc[3][jc]);
        Gf4[(size_t)(ti*16 + ty)*NS_CAP + tj*GTILE + 4*tx + jc] = v;
    }
    if(!diag){
        #pragma unroll
        for(int a = 0; a < 4; a++){
            float4 v = make_float4(acc[a][0], acc[a][1], acc[a][2], acc[a][3]);
            Gf4[(size_t)(tj*16 + tx)*NS_CAP + ti*GTILE + 4*ty + a] = v;
        }
    }
}

// ---------------------------------------------------------------------------
// Kernel 3: coefficient-space Chronopoulos-Gear CG, Gram in dynamic LDS
// (160 KB — covers nsc up to ~200 fully). 3 barriers/iteration.
// ---------------------------------------------------------------------------
extern __shared__ float4 gl4[];                // GL_F4 float4 (160256 B)

__global__ __launch_bounds__(512, 2) void k_cgc(
        const float* __restrict__ X, const float* __restrict__ G0,
        const int* __restrict__ sup_idx, const int* __restrict__ sup_lab,
        const int* __restrict__ counts, const float* __restrict__ row_sums2,
        float* __restrict__ vout)
{
    const int bid  = blockIdx.x;
    const int sys  = ((bid & 7) << 5) | (bid >> 3);   // pair-local XCD swizzle
    const int b    = sys >> 1;
    const int cls  = sys & 1;
    const int tid  = threadIdx.x;
    const int lane = tid & 63;
    const int wave = tid >> 6;

    __shared__ __align__(16) float u[NS_CAP];
    __shared__ int   idx_l[NS_CAP];
    __shared__ float redA[8][5];

    const int ns   = counts[b*4 + 0];
    const int nsc  = min(ns, NS_CAP);
    const int ncls = cls ? counts[b*4 + 2] : counts[b*4 + 3];
    const float c_task = 0.9f / (float)(ns - 1);
    const float c_cls  = 0.1f / (float)(ncls - 1);
    const float inv_ns = 1.f / (float)ns;
    const float inv_nc = 1.f / (float)ncls;
    const float4* G4 = (const float4*)(G0 + (size_t)b * NS_CAP * NS_CAP);
    const float4* u4 = (const float4*)u;
    const int nf4 = (nsc + 3) >> 2;
    const int c4l = min(nf4, GL_F4 / nsc);     // Gram blocks cached in LDS

    const bool mth = tid < NS_CAP;
    const bool own = tid < nsc;
    float mfl = 0.f, sraw = 0.f;
    if(own){
        mfl  = (sup_lab[b*LPAD + tid] == cls) ? 1.f : 0.f;
        float2 rs = ((const float2*)row_sums2)[b*LPAD + tid];
        sraw = rs.x + rs.y;
    }
    for(int s = tid; s < nsc; s += 512) idx_l[s] = sup_idx[b*LPAD + s];

    // Stage Gram blocks into LDS: gl4[c4*nsc + t] = G4[c4*NS_CAP + t]
    for(int c4 = 0; c4 < c4l; c4++)
        for(int t = tid; t < nsc; t += 512)
            gl4[c4*nsc + t] = G4[(size_t)c4 * NS_CAP + t];
    __syncthreads();

    auto reduce5 = [&](float v0, float v1, float v2, float v3, float v4,
                       float* out){
        #pragma unroll
        for(int off = 32; off; off >>= 1){
            v0 += __shfl_xor(v0, off); v1 += __shfl_xor(v1, off);
            v2 += __shfl_xor(v2, off); v3 += __shfl_xor(v3, off);
            v4 += __shfl_xor(v4, off);
        }
        __syncthreads();
        if(lane == 0){
            redA[wave][0] = v0; redA[wave][1] = v1; redA[wave][2] = v2;
            redA[wave][3] = v3; redA[wave][4] = v4;
        }
        __syncthreads();
        #pragma unroll
        for(int k = 0; k < 5; k++){
            float s = 0.f;
            #pragma unroll
            for(int w = 0; w < 8; w++) s += redA[w][k];
            out[k] = s;
        }
    };

    auto matvec = [&]() -> float {
        float s0 = 0.f, s1 = 0.f, s2 = 0.f, s3 = 0.f;
        if(own){
            const float4* gq = gl4 + tid;
            int c4 = 0;
            for(; c4 + 8 <= c4l; c4 += 8){
                float4 g0 = gq[(c4+0)*nsc], g1 = gq[(c4+1)*nsc];
                float4 g2 = gq[(c4+2)*nsc], g3 = gq[(c4+3)*nsc];
                float4 g4 = gq[(c4+4)*nsc], g5 = gq[(c4+5)*nsc];
                float4 g6 = gq[(c4+6)*nsc], g7 = gq[(c4+7)*nsc];
                s0 += f4dot(g0, u4[c4+0]); s1 += f4dot(g1, u4[c4+1]);
                s2 += f4dot(g2, u4[c4+2]); s3 += f4dot(g3, u4[c4+3]);
                s0 += f4dot(g4, u4[c4+4]); s1 += f4dot(g5, u4[c4+5]);
                s2 += f4dot(g6, u4[c4+6]); s3 += f4dot(g7, u4[c4+7]);
            }
            for(; c4 < c4l; c4++) s0 += f4dot(gq[c4*nsc], u4[c4]);
            for(; c4 + 8 <= nf4; c4 += 8){
                float4 g[8];
                #pragma unroll
                for(int j = 0; j < 8; j++) g[j] = G4[(size_t)(c4+j)*NS_CAP + tid];
                #pragma unroll
                for(int j = 0; j < 8; j++){
                    float d = f4dot(g[j], u4[c4+j]);
                    if((j & 3) == 0) s0 += d; else if((j & 3) == 1) s1 += d;
                    else if((j & 3) == 2) s2 += d; else s3 += d;
                }
            }
            for(; c4 < nf4; c4++) s0 += f4dot(G4[(size_t)c4*NS_CAP + tid], u4[c4]);
        }
        return (s0 + s1) + (s2 + s3);
    };

    // init: r0 = -10 * A * 1  (t-image of p=1_D is the row-sum vector)
    float out5[5];
    reduce5(sraw, mfl * sraw, 0.f, 0.f, 0.f, out5);
    float A0 = out5[0] * inv_ns, A1 = out5[1] * inv_nc;
    float cr = own ? -10.f * (c_task*(sraw - A0) + mfl*c_cls*(sraw - A1)) : 0.f;
    if(mth) u[tid] = own ? cr : 0.f;
    __syncthreads();
    float tr = matvec();

    float cp = 0.f, tp = 0.f, cq = 0.f, tq = 0.f, cx = 0.f;
    float gamma_old = 1.f, alpha_old = 1.f;
    bool first = true;

    for(int it = 0; it < CG_ITERS; ++it){
        // bundle: S1=Σtr, S2=Σm·tr, S3=Σtr², S4=Σm·tr², S5=Σtr·cr
        reduce5(tr, mfl*tr, tr*tr, mfl*tr*tr, tr*cr, out5);
        A0 = out5[0] * inv_ns; A1 = out5[1] * inv_nc;
        float gamma = out5[4];                               // (r,r)
        float delta = 0.1f*gamma + c_task*(out5[2] - out5[0]*A0)
                                 + c_cls *(out5[3] - out5[1]*A1);  // (r,Mr)
        if(gamma < 1e-26f) break;
        float ur = own ? (c_task*(tr - A0) + mfl*c_cls*(tr - A1)) : 0.f;
        float cw = 0.1f*cr + ur;                             // c of w = M r
        if(mth) u[tid] = ur;
        __syncthreads();
        float gv = matvec();                                 // G0 * u_r
        float tw = 0.1f*tr + gv;                             // t of w
        float beta  = first ? 0.f : gamma / gamma_old;
        float alpha = first ? gamma / delta
                            : gamma / (delta - beta * gamma / alpha_old);
        cp = cr + beta * cp;  tp = tr + beta * tp;
        cq = cw + beta * cq;  tq = tw + beta * tq;
        cx += alpha * cp;
        cr -= alpha * cq;     tr -= alpha * tq;
        gamma_old = gamma; alpha_old = alpha; first = false;
    }

    // v = 10*1 + Xs^T c_x : float4, 4-way row split, 8 loads in flight.
    __syncthreads();
    if(mth) u[tid] = own ? cx : 0.f;
    __syncthreads();
    const float4* X4 = (const float4*)X;
    const int f4c = tid & 127;
    const int rg  = tid >> 7;                  // 0..3
    float4 acc = make_float4(0.f,0.f,0.f,0.f);
    int s = rg;
    for(; s + 28 < nsc; s += 32){
        int n0 = idx_l[s],    n1 = idx_l[s+4],  n2 = idx_l[s+8],  n3 = idx_l[s+12];
        int n4 = idx_l[s+16], n5 = idx_l[s+20], n6 = idx_l[s+24], n7 = idx_l[s+28];
        float w0 = u[s],    w1 = u[s+4],  w2 = u[s+8],  w3 = u[s+12];
        float w4 = u[s+16], w5 = u[s+20], w6 = u[s+24], w7 = u[s+28];
        float4 x0 = X4[(size_t)n0*128 + f4c];
        float4 x1 = X4[(size_t)n1*128 + f4c];
        float4 x2 = X4[(size_t)n2*128 + f4c];
        float4 x3 = X4[(size_t)n3*128 + f4c];
        float4 x4 = X4[(size_t)n4*128 + f4c];
        float4 x5 = X4[(size_t)n5*128 + f4c];
        float4 x6 = X4[(size_t)n6*128 + f4c];
        float4 x7 = X4[(size_t)n7*128 + f4c];
        acc = f4fma(w0,x0, f4fma(w1,x1, f4fma(w2,x2, f4fma(w3,x3, acc))));
        acc = f4fma(w4,x4, f4fma(w5,x5, f4fma(w6,x6, f4fma(w7,x7, acc))));
    }
    for(; s < nsc; s += 4)
        acc = f4fma(u[s], X4[(size_t)idx_l[s]*128 + f4c], acc);
    gl4[rg*128 + f4c] = acc;
    __syncthreads();
    if(tid < 128){
        float4 v = f4add(f4add(gl4[tid], gl4[128+tid]),
                         f4add(gl4[256+tid], gl4[384+tid]));
        v.x += 10.f; v.y += 10.f; v.z += 10.f; v.w += 10.f;
        ((float4*)vout)[(size_t)sys * 128 + tid] = v;
    }
}

// ---------------------------------------------------------------------------
// Kernel 4: per-query output. 2 WGs/episode; 2 query rows per wave iteration.
// ---------------------------------------------------------------------------
__global__ __launch_bounds__(256) void k_out(
        const float* __restrict__ X,
        const int* __restrict__ qry_idx, const int* __restrict__ counts,
        const float* __restrict__ pos_mean, const float* __restrict__ neg_mean,
        const float* __restrict__ vsol, const float* __restrict__ log_scale,
        float* __restrict__ out)
{
    const int bid  = blockIdx.x;
    const int b    = bid >> 1;
    const int h    = bid & 1;
    const int tid  = threadIdx.x;
    const int lane = tid & 63;
    const int wave = tid >> 6;

    __shared__ __align__(16) float vpos[DDIM];
    __shared__ __align__(16) float vneg[DDIM];
    __shared__ float red4[4][4];
    __shared__ float sc[4];

    const int nq  = counts[b*4 + 1];
    const int nqc = min(nq, LPAD);
    const float scale = expf(log_scale[0]);

    float pm0 = pos_mean[b*DDIM + tid], pm1 = pos_mean[b*DDIM + tid + 256];
    float nm0 = neg_mean[b*DDIM + tid], nm1 = neg_mean[b*DDIM + tid + 256];
    float vp0 = vsol[(size_t)(b*2 + 1) * DDIM + tid];
    float vp1 = vsol[(size_t)(b*2 + 1) * DDIM + tid + 256];
    float vn0 = vsol[(size_t)(b*2 + 0) * DDIM + tid];
    float vn1 = vsol[(size_t)(b*2 + 0) * DDIM + tid + 256];
    vpos[tid] = vp0; vpos[tid + 256] = vp1;
    vneg[tid] = vn0; vneg[tid + 256] = vn1;

    float smp = pm0 + pm1;
    float smn = nm0 + nm1;
    float mvp = pm0 * vp0 + pm1 * vp1;
    float mvn = nm0 * vn0 + nm1 * vn1;
    #pragma unroll
    for(int off = 32; off; off >>= 1){
        smp += __shfl_xor(smp, off);
        smn += __shfl_xor(smn, off);
        mvp += __shfl_xor(mvp, off);
        mvn += __shfl_xor(mvn, off);
    }
    if(lane == 0){
        red4[wave][0] = smp; red4[wave][1] = smn;
        red4[wave][2] = mvp; red4[wave][3] = mvn;
    }
    __syncthreads();
    if(tid < 4) sc[tid] = red4[0][tid] + red4[1][tid] + red4[2][tid] + red4[3][tid];
    __syncthreads();

    const float4* vp4 = (const float4*)vpos;
    const float4* vn4 = (const float4*)vneg;
    const float4 vpa = vp4[lane], vpb = vp4[lane + 64];
    const float4 vna = vn4[lane], vnb = vn4[lane + 64];
    for(int r = wave + 4*h; r < nqc; r += 16){
        int r2 = r + 8;
        bool has2 = r2 < nqc;
        int n  = qry_idx[b * LPAD + r];
        int n2 = qry_idx[b * LPAD + (has2 ? r2 : r)];
        const float4* xr = (const float4*)(X + (size_t)n  * DDIM);
        const float4* yr = (const float4*)(X + (size_t)n2 * DDIM);
        float4 x0 = xr[lane], x1 = xr[lane + 64];
        float4 y0 = yr[lane], y1 = yr[lane + 64];
        float tp = f4dot(x0, vpa) + f4dot(x1, vpb);
        float tn = f4dot(x0, vna) + f4dot(x1, vnb);
        float sx = f4sum(x0) + f4sum(x1);
        float tp2 = f4dot(y0, vpa) + f4dot(y1, vpb);
        float tn2 = f4dot(y0, vna) + f4dot(y1, vnb);
        float sx2 = f4sum(y0) + f4sum(y1);
        #pragma unroll
        for(int off = 32; off; off >>= 1){
            tp  += __shfl_xor(tp,  off);
            tn  += __shfl_xor(tn,  off);
            sx  += __shfl_xor(sx,  off);
            tp2 += __shfl_xor(tp2, off);
            tn2 += __shfl_xor(tn2, off);
            sx2 += __shfl_xor(sx2, off);
        }
        if(lane == 0){
            float mp = (tp - sc[2]) * (sx - sc[0]);
            float mn = (tn - sc[3]) * (sx - sc[1]);
            ((float2*)out)[(size_t)b * LPAD + r] = make_float2(mn * scale, mp * scale);
            if(has2){
                float mp2 = (tp2 - sc[2]) * (sx2 - sc[0]);
                float mn2 = (tn2 - sc[3]) * (sx2 - sc[1]);
                ((float2*)out)[(size_t)b * LPAD + r2] = make_float2(mn2 * scale, mp2 * scale);
            }
        }
    }
    const int lo = max(nqc, h * 256), hi = (h + 1) * 256;
    for(int r = lo + tid; r < hi; r += 256)
        ((float2*)out)[(size_t)b * LPAD + r] = make_float2(0.f, 0.f);
}

// ---------------------------------------------------------------------------
extern "C" void kernel_launch(void* const* d_in, const int* in_sizes, int n_in,
                              void* d_out, int out_size, void* d_ws, size_t ws_size,
                              hipStream_t stream)
{
    const float* X         = (const float*)d_in[0];
    const float* log_scale = (const float*)d_in[1];
    const int*   labels    = (const int*)d_in[2];
    const int*   is_query  = (const int*)d_in[3];
    const int*   bidx      = (const int*)d_in[4];
    const int N = in_sizes[2];

    char* ws = (char*)d_ws;
    auto alloc = [&](size_t bytes) -> char* {
        char* p = ws;
        ws += (bytes + 255) & ~(size_t)255;
        return p;
    };
    int*   sup_idx   = (int*)  alloc((size_t)EPISODES * LPAD * sizeof(int));
    int*   qry_idx   = (int*)  alloc((size_t)EPISODES * LPAD * sizeof(int));
    int*   sup_lab   = (int*)  alloc((size_t)EPISODES * LPAD * sizeof(int));
    int*   counts    = (int*)  alloc((size_t)EPISODES * 4 * sizeof(int));
    float* task_mean = (float*)alloc((size_t)EPISODES * DDIM * sizeof(float));
    float* pos_mean  = (float*)alloc((size_t)EPISODES * DDIM * sizeof(float));
    float* neg_mean  = (float*)alloc((size_t)EPISODES * DDIM * sizeof(float));
    float* vsol      = (float*)alloc((size_t)EPISODES * 2 * DDIM * sizeof(float));
    float* row_sums2 = (float*)alloc((size_t)EPISODES * LPAD * 2 * sizeof(float));
    float* G0        = (float*)alloc((size_t)EPISODES * NS_CAP * NS_CAP * sizeof(float));
    (void)ws_size;
    (void)task_mean;

    k_prep<<<EPISODES*2, 256, 0, stream>>>(labels, is_query, bidx, X, N,
                                           sup_idx, qry_idx, sup_lab, counts,
                                           task_mean, pos_mean, neg_mean, row_sums2);
    k_gram<<<EPISODES * NPAIRS, 256, 0, stream>>>(X, sup_idx, counts, G0);
    k_cgc<<<EPISODES * 2, 512, GL_F4 * sizeof(float4), stream>>>(
                                            X, G0, sup_idx, sup_lab, counts,
                                            row_sums2, vsol);
    k_out<<<EPISODES*2, 256, 0, stream>>>(X, qry_idx, counts, pos_mean, neg_mean,
                                          vsol, log_scale, (float*)d_out);
}

// Round 10
// 315.555 us; speedup vs baseline: 2.8006x; 1.0565x over previous
//
#include <hip/hip_runtime.h>
#include <cstdint>
#include <cstddef>

#define EPISODES 128
#define LPAD     512
#define DDIM     512
#define NS_CAP   320
#define GTILE    64
#define NPAIRS   15          // 5*(5+1)/2 tile pairs (NS_CAP/GTILE = 5)
#define CG_ITERS 14
#define GL_F4    10016       // dynamic-LDS float4 capacity (160256 B)
#define KCH      64          // k per staged chunk in k_gram
#define KSTR     72          // ushorts per staged row (64 + 8 pad)

typedef __attribute__((ext_vector_type(8))) __bf16 bf16x8;
typedef __attribute__((ext_vector_type(4))) float  floatx4;

__device__ __forceinline__ int lower_bound_dev(const int* __restrict__ a, int n, int key){
    int lo = 0, hi = n;
    while(lo < hi){
        int m = (lo + hi) >> 1;
        if(a[m] < key) lo = m + 1; else hi = m;
    }
    return lo;
}

__device__ __forceinline__ float4 f4add(float4 a, float4 b){
    return make_float4(a.x+b.x, a.y+b.y, a.z+b.z, a.w+b.w);
}
__device__ __forceinline__ float4 f4fma(float s, float4 a, float4 acc){
    return make_float4(acc.x + s*a.x, acc.y + s*a.y, acc.z + s*a.z, acc.w + s*a.w);
}
__device__ __forceinline__ float f4dot(float4 a, float4 b){
    return a.x*b.x + a.y*b.y + a.z*b.z + a.w*b.w;
}
__device__ __forceinline__ float f4sum(float4 a){ return (a.x+a.y)+(a.z+a.w); }

__device__ __forceinline__ unsigned short f2bf(float x){
    unsigned u = __float_as_uint(x);
    u += 0x7FFFu + ((u >> 16) & 1u);
    return (unsigned short)(u >> 16);
}
__device__ __forceinline__ float bf2f(unsigned short h){
    return __uint_as_float(((unsigned)h) << 16);
}

// ---------------------------------------------------------------------------
// Kernel 1: fused segmentation + means + per-half row sums (unchanged).
// ---------------------------------------------------------------------------
__global__ __launch_bounds__(256) void k_prep(
        const int* __restrict__ labels, const int* __restrict__ is_query,
        const int* __restrict__ bidx, const float* __restrict__ X, int N,
        int* __restrict__ sup_idx, int* __restrict__ qry_idx,
        int* __restrict__ sup_lab, int* __restrict__ counts,
        float* __restrict__ task_mean, float* __restrict__ pos_mean,
        float* __restrict__ neg_mean, float* __restrict__ row_sums2)
{
    const int bid  = blockIdx.x;
    const int b    = bid >> 1;
    const int h    = bid & 1;
    const int tid  = threadIdx.x;
    const int lane = tid & 63;
    const int wave = tid >> 6;

    __shared__ int s_start, s_end;
    __shared__ int wq[4];
    __shared__ int s_runq, s_npos;
    __shared__ int   sidx[NS_CAP];
    __shared__ float slabf[NS_CAP];
    __shared__ float4 pa[4][64];
    __shared__ float4 pp[4][64];

    if(tid == 0){
        s_start = lower_bound_dev(bidx, N, b);
        s_end   = lower_bound_dev(bidx, N, b + 1);
        s_runq  = 0;
        s_npos  = 0;
    }
    __syncthreads();
    const int start = s_start, end = s_end;

    for(int base = start; base < end; base += 256){
        int idx   = base + tid;
        bool valid = idx < end;
        int q   = valid ? is_query[idx] : 0;
        int lab = valid ? labels[idx]   : 0;
        unsigned long long m = __ballot(q == 1);
        if(lane == 0) wq[wave] = __popcll(m);
        __syncthreads();
        int woff = 0;
        for(int w = 0; w < wave; w++) woff += wq[w];
        int qbefore = __popcll(m & ((1ull << lane) - 1ull)) + woff;
        int runq0 = s_runq;
        int chunk_total = wq[0] + wq[1] + wq[2] + wq[3];
        if(valid){
            int pos_in_seg = idx - start;
            if(q){
                int qr = runq0 + qbefore;
                if(h == 0 && qr < LPAD) qry_idx[b * LPAD + qr] = idx;
            } else {
                int sr = pos_in_seg - runq0 - qbefore;
                if(sr < LPAD){
                    if(h == 0){
                        sup_idx[b * LPAD + sr] = idx;
                        sup_lab[b * LPAD + sr] = lab;
                    }
                    if(sr < NS_CAP){ sidx[sr] = idx; slabf[sr] = (float)lab; }
                    if(lab == 1) atomicAdd(&s_npos, 1);
                }
            }
        }
        __syncthreads();
        if(tid == 0) s_runq = runq0 + chunk_total;
        __syncthreads();
    }

    const int nq   = s_runq;
    const int ns   = (end - start) - nq;
    const int npos = s_npos;
    const int nneg = ns - npos;
    if(h == 0 && tid == 0){
        counts[b*4 + 0] = ns;
        counts[b*4 + 1] = nq;
        counts[b*4 + 2] = npos;
        counts[b*4 + 3] = nneg;
    }
    const int nsb = min(ns, NS_CAP);

    const float4* X4 = (const float4*)X;
    const int colg = h*64 + lane;
    float4 sa = make_float4(0.f,0.f,0.f,0.f);
    float4 sp = make_float4(0.f,0.f,0.f,0.f);
    int r = wave;
    for(; r + 12 < nsb; r += 16){
        int n0 = sidx[r], n1 = sidx[r+4], n2 = sidx[r+8], n3 = sidx[r+12];
        float l0 = slabf[r], l1 = slabf[r+4], l2 = slabf[r+8], l3 = slabf[r+12];
        float4 x0 = X4[(size_t)n0*128 + colg];
        float4 x1 = X4[(size_t)n1*128 + colg];
        float4 x2 = X4[(size_t)n2*128 + colg];
        float4 x3 = X4[(size_t)n3*128 + colg];
        sa = f4add(sa, f4add(f4add(x0,x1), f4add(x2,x3)));
        sp = f4fma(l0,x0, f4fma(l1,x1, f4fma(l2,x2, f4fma(l3,x3, sp))));
        float r0s = f4sum(x0), r1s = f4sum(x1), r2s = f4sum(x2), r3s = f4sum(x3);
        #pragma unroll
        for(int off = 32; off; off >>= 1){
            r0s += __shfl_xor(r0s, off); r1s += __shfl_xor(r1s, off);
            r2s += __shfl_xor(r2s, off); r3s += __shfl_xor(r3s, off);
        }
        if(lane == 0){
            row_sums2[(b*LPAD + r   )*2 + h] = r0s;
            row_sums2[(b*LPAD + r+4 )*2 + h] = r1s;
            row_sums2[(b*LPAD + r+8 )*2 + h] = r2s;
            row_sums2[(b*LPAD + r+12)*2 + h] = r3s;
        }
    }
    for(; r < nsb; r += 4){
        int n = sidx[r];
        float l = slabf[r];
        float4 x = X4[(size_t)n*128 + colg];
        sa = f4add(sa, x);
        sp = f4fma(l, x, sp);
        float rs = f4sum(x);
        #pragma unroll
        for(int off = 32; off; off >>= 1) rs += __shfl_xor(rs, off);
        if(lane == 0) row_sums2[(b*LPAD + r)*2 + h] = rs;
    }
    pa[wave][lane] = sa;
    pp[wave][lane] = sp;
    __syncthreads();
    if(tid < 64){
        float4 A = f4add(f4add(pa[0][tid],pa[1][tid]), f4add(pa[2][tid],pa[3][tid]));
        float4 P = f4add(f4add(pp[0][tid],pp[1][tid]), f4add(pp[2][tid],pp[3][tid]));
        float4 Nn = make_float4(A.x-P.x, A.y-P.y, A.z-P.z, A.w-P.w);
        float ia = 1.f/(float)ns, ip = 1.f/(float)npos, in = 1.f/(float)nneg;
        int c = b*128 + h*64 + tid;
        ((float4*)task_mean)[c] = make_float4(A.x*ia, A.y*ia, A.z*ia, A.w*ia);
        ((float4*)pos_mean )[c] = make_float4(P.x*ip, P.y*ip, P.z*ip, P.w*ip);
        ((float4*)neg_mean )[c] = make_float4(Nn.x*in, Nn.y*in, Nn.z*in, Nn.w*in);
    }
}

// ---------------------------------------------------------------------------
// Kernel 2: Gram via bf16 MFMA with hi/lo split (G = hh + hl + lh, fp32 acc).
// Output float4 layout Gf4[(c>>2)*NS_CAP + t], component (c&3) — each lane's
// 4-reg MFMA accumulator IS one Gf4 entry (C/D: col=lane&15, row=quad*4+reg).
// A/B fragments use the verified layout [row=lane&15][k=(lane>>4)*8+j]; for
// G = Xi·Xj^T both operands load identically from row-major bf16 LDS tiles.
// Mirror blocks bounce through LDS once. No zero-fill (u=0 masks padding).
// ---------------------------------------------------------------------------
__global__ __launch_bounds__(256) void k_gram(
        const float* __restrict__ X, const int* __restrict__ sup_idx,
        const int* __restrict__ counts, float* __restrict__ G0)
{
    const int bid = blockIdx.x;
    const int b   = bid / NPAIRS;
    int tp = bid % NPAIRS;
    int ti = 0;
    while((ti+1)*(ti+2)/2 <= tp) ti++;
    const int tj  = tp - ti*(ti+1)/2;          // ti >= tj
    const int tid = threadIdx.x;
    const int lane = tid & 63;
    const int wave = tid >> 6;

    const int ns  = counts[b*4 + 0];
    const int nsc = min(ns, NS_CAP);
    if(ti * GTILE >= nsc) return;
    const bool diag = (ti == tj);

    __shared__ int ia[GTILE], ib[GTILE];
    __shared__ __align__(16) unsigned short SM[4 * GTILE * KSTR];  // 36864 B
    unsigned short* SAh = SM;
    unsigned short* SAl = SM + GTILE*KSTR;
    unsigned short* SBh = SM + 2*GTILE*KSTR;
    unsigned short* SBl = SM + 3*GTILE*KSTR;

    if(tid < GTILE)        ia[tid]    = sup_idx[b*LPAD + min(ti*GTILE + tid,      nsc-1)];
    else if(tid < 2*GTILE) ib[tid-64] = sup_idx[b*LPAD + min(tj*GTILE + (tid-64), nsc-1)];

    const unsigned short* Bh = diag ? SAh : SBh;
    const unsigned short* Bl = diag ? SAl : SBl;

    const int ry = (wave >> 1) * 32;           // wave's output row base
    const int cx = (wave & 1) * 32;            // wave's output col base
    const int fr = lane & 15;                  // fragment row within 16
    const int fq = (lane >> 4) * 8;            // fragment k offset

    floatx4 acc[2][2];
    acc[0][0] = (floatx4){0.f,0.f,0.f,0.f};
    acc[0][1] = (floatx4){0.f,0.f,0.f,0.f};
    acc[1][0] = (floatx4){0.f,0.f,0.f,0.f};
    acc[1][1] = (floatx4){0.f,0.f,0.f,0.f};

    for(int k0 = 0; k0 < DDIM; k0 += KCH){
        __syncthreads();                       // prev compute done (covers ia/ib)
        #pragma unroll
        for(int p = 0; p < 4; p++){
            int e = tid + p*256;
            int row = e >> 4, kq = e & 15;
            float4 xa = *(const float4*)(X + (size_t)ia[row]*DDIM + k0 + kq*4);
            ushort4 hh, ll;
            hh.x = f2bf(xa.x); ll.x = f2bf(xa.x - bf2f(hh.x));
            hh.y = f2bf(xa.y); ll.y = f2bf(xa.y - bf2f(hh.y));
            hh.z = f2bf(xa.z); ll.z = f2bf(xa.z - bf2f(hh.z));
            hh.w = f2bf(xa.w); ll.w = f2bf(xa.w - bf2f(hh.w));
            *(ushort4*)&SAh[row*KSTR + kq*4] = hh;
            *(ushort4*)&SAl[row*KSTR + kq*4] = ll;
            if(!diag){
                float4 xb = *(const float4*)(X + (size_t)ib[row]*DDIM + k0 + kq*4);
                ushort4 h2, l2;
                h2.x = f2bf(xb.x); l2.x = f2bf(xb.x - bf2f(h2.x));
                h2.y = f2bf(xb.y); l2.y = f2bf(xb.y - bf2f(h2.y));
                h2.z = f2bf(xb.z); l2.z = f2bf(xb.z - bf2f(h2.z));
                h2.w = f2bf(xb.w); l2.w = f2bf(xb.w - bf2f(h2.w));
                *(ushort4*)&SBh[row*KSTR + kq*4] = h2;
                *(ushort4*)&SBl[row*KSTR + kq*4] = l2;
            }
        }
        __syncthreads();
        #pragma unroll
        for(int ks = 0; ks < KCH; ks += 32){
            bf16x8 ah0 = *(const bf16x8*)&SAh[(ry     + fr)*KSTR + ks + fq];
            bf16x8 ah1 = *(const bf16x8*)&SAh[(ry + 16 + fr)*KSTR + ks + fq];
            bf16x8 al0 = *(const bf16x8*)&SAl[(ry     + fr)*KSTR + ks + fq];
            bf16x8 al1 = *(const bf16x8*)&SAl[(ry + 16 + fr)*KSTR + ks + fq];
            bf16x8 bh0 = *(const bf16x8*)&Bh[(cx     + fr)*KSTR + ks + fq];
            bf16x8 bh1 = *(const bf16x8*)&Bh[(cx + 16 + fr)*KSTR + ks + fq];
            bf16x8 bl0 = *(const bf16x8*)&Bl[(cx     + fr)*KSTR + ks + fq];
            bf16x8 bl1 = *(const bf16x8*)&Bl[(cx + 16 + fr)*KSTR + ks + fq];
            acc[0][0] = __builtin_amdgcn_mfma_f32_16x16x32_bf16(ah0, bh0, acc[0][0], 0,0,0);
            acc[0][1] = __builtin_amdgcn_mfma_f32_16x16x32_bf16(ah0, bh1, acc[0][1], 0,0,0);
            acc[1][0] = __builtin_amdgcn_mfma_f32_16x16x32_bf16(ah1, bh0, acc[1][0], 0,0,0);
            acc[1][1] = __builtin_amdgcn_mfma_f32_16x16x32_bf16(ah1, bh1, acc[1][1], 0,0,0);
            acc[0][0] = __builtin_amdgcn_mfma_f32_16x16x32_bf16(ah0, bl0, acc[0][0], 0,0,0);
            acc[0][1] = __builtin_amdgcn_mfma_f32_16x16x32_bf16(ah0, bl1, acc[0][1], 0,0,0);
            acc[1][0] = __builtin_amdgcn_mfma_f32_16x16x32_bf16(ah1, bl0, acc[1][0], 0,0,0);
            acc[1][1] = __builtin_amdgcn_mfma_f32_16x16x32_bf16(ah1, bl1, acc[1][1], 0,0,0);
            acc[0][0] = __builtin_amdgcn_mfma_f32_16x16x32_bf16(al0, bh0, acc[0][0], 0,0,0);
            acc[0][1] = __builtin_amdgcn_mfma_f32_16x16x32_bf16(al0, bh1, acc[0][1], 0,0,0);
            acc[1][0] = __builtin_amdgcn_mfma_f32_16x16x32_bf16(al1, bh0, acc[1][0], 0,0,0);
            acc[1][1] = __builtin_amdgcn_mfma_f32_16x16x32_bf16(al1, bh1, acc[1][1], 0,0,0);
        }
    }

    // Direct stores: lane's 4-reg acc = Gf4[(rowbase/4 + quad)*NS_CAP + col]
    float4* Gf4 = (float4*)(G0 + (size_t)b * NS_CAP * NS_CAP);
    const int q = lane >> 4, j = lane & 15;
    #pragma unroll
    for(int sy = 0; sy < 2; sy++)
        #pragma unroll
        for(int sx = 0; sx < 2; sx++){
            int cq = ((ti*GTILE + ry + sy*16) >> 2) + q;
            int t  = tj*GTILE + cx + sx*16 + j;
            Gf4[(size_t)cq * NS_CAP + t] =
                make_float4(acc[sy][sx].x, acc[sy][sx].y, acc[sy][sx].z, acc[sy][sx].w);
        }

    // Mirror (G symmetric): bounce through LDS to transpose.
    if(!diag){
        __syncthreads();                       // staging area free
        float* Tb = (float*)SM;                // 64 x 68 floats (17408 B)
        #pragma unroll
        for(int sy = 0; sy < 2; sy++)
            #pragma unroll
            for(int sx = 0; sx < 2; sx++){
                int r0 = ry + sy*16 + 4*q;
                int c  = cx + sx*16 + j;
                Tb[(r0+0)*68 + c] = acc[sy][sx].x;
                Tb[(r0+1)*68 + c] = acc[sy][sx].y;
                Tb[(r0+2)*68 + c] = acc[sy][sx].z;
                Tb[(r0+3)*68 + c] = acc[sy][sx].w;
            }
        __syncthreads();
        for(int e = tid; e < 16*GTILE; e += 256){
            int cc = e >> 6;                   // mirror c-quad within tile
            int r  = e & 63;                   // mirror col within tile
            float4 v = *(const float4*)&Tb[r*68 + 4*cc];
            Gf4[(size_t)(tj*16 + cc) * NS_CAP + ti*GTILE + r] = v;
        }
    }
}

// ---------------------------------------------------------------------------
// Kernel 3: coefficient-space Chronopoulos-Gear CG, Gram in dynamic LDS.
// ---------------------------------------------------------------------------
extern __shared__ float4 gl4[];                // GL_F4 float4 (160256 B)

__global__ __launch_bounds__(512, 2) void k_cgc(
        const float* __restrict__ X, const float* __restrict__ G0,
        const int* __restrict__ sup_idx, const int* __restrict__ sup_lab,
        const int* __restrict__ counts, const float* __restrict__ row_sums2,
        float* __restrict__ vout)
{
    const int bid  = blockIdx.x;
    const int sys  = ((bid & 7) << 5) | (bid >> 3);   // pair-local XCD swizzle
    const int b    = sys >> 1;
    const int cls  = sys & 1;
    const int tid  = threadIdx.x;
    const int lane = tid & 63;
    const int wave = tid >> 6;

    __shared__ __align__(16) float u[NS_CAP];
    __shared__ int   idx_l[NS_CAP];
    __shared__ float redA[8][5];

    const int ns   = counts[b*4 + 0];
    const int nsc  = min(ns, NS_CAP);
    const int ncls = cls ? counts[b*4 + 2] : counts[b*4 + 3];
    const float c_task = 0.9f / (float)(ns - 1);
    const float c_cls  = 0.1f / (float)(ncls - 1);
    const float inv_ns = 1.f / (float)ns;
    const float inv_nc = 1.f / (float)ncls;
    const float4* G4 = (const float4*)(G0 + (size_t)b * NS_CAP * NS_CAP);
    const float4* u4 = (const float4*)u;
    const int nf4 = (nsc + 3) >> 2;
    const int c4l = min(nf4, GL_F4 / nsc);     // Gram blocks cached in LDS

    const bool mth = tid < NS_CAP;
    const bool own = tid < nsc;
    float mfl = 0.f, sraw = 0.f;
    if(own){
        mfl  = (sup_lab[b*LPAD + tid] == cls) ? 1.f : 0.f;
        float2 rs = ((const float2*)row_sums2)[b*LPAD + tid];
        sraw = rs.x + rs.y;
    }
    for(int s = tid; s < nsc; s += 512) idx_l[s] = sup_idx[b*LPAD + s];

    for(int c4 = 0; c4 < c4l; c4++)
        for(int t = tid; t < nsc; t += 512)
            gl4[c4*nsc + t] = G4[(size_t)c4 * NS_CAP + t];
    __syncthreads();

    auto reduce5 = [&](float v0, float v1, float v2, float v3, float v4,
                       float* out){
        #pragma unroll
        for(int off = 32; off; off >>= 1){
            v0 += __shfl_xor(v0, off); v1 += __shfl_xor(v1, off);
            v2 += __shfl_xor(v2, off); v3 += __shfl_xor(v3, off);
            v4 += __shfl_xor(v4, off);
        }
        __syncthreads();
        if(lane == 0){
            redA[wave][0] = v0; redA[wave][1] = v1; redA[wave][2] = v2;
            redA[wave][3] = v3; redA[wave][4] = v4;
        }
        __syncthreads();
        #pragma unroll
        for(int k = 0; k < 5; k++){
            float s = 0.f;
            #pragma unroll
            for(int w = 0; w < 8; w++) s += redA[w][k];
            out[k] = s;
        }
    };

    auto matvec = [&]() -> float {
        float s0 = 0.f, s1 = 0.f, s2 = 0.f, s3 = 0.f;
        if(own){
            const float4* gq = gl4 + tid;
            int c4 = 0;
            for(; c4 + 8 <= c4l; c4 += 8){
                float4 g0 = gq[(c4+0)*nsc], g1 = gq[(c4+1)*nsc];
                float4 g2 = gq[(c4+2)*nsc], g3 = gq[(c4+3)*nsc];
                float4 g4 = gq[(c4+4)*nsc], g5 = gq[(c4+5)*nsc];
                float4 g6 = gq[(c4+6)*nsc], g7 = gq[(c4+7)*nsc];
                s0 += f4dot(g0, u4[c4+0]); s1 += f4dot(g1, u4[c4+1]);
                s2 += f4dot(g2, u4[c4+2]); s3 += f4dot(g3, u4[c4+3]);
                s0 += f4dot(g4, u4[c4+4]); s1 += f4dot(g5, u4[c4+5]);
                s2 += f4dot(g6, u4[c4+6]); s3 += f4dot(g7, u4[c4+7]);
            }
            for(; c4 < c4l; c4++) s0 += f4dot(gq[c4*nsc], u4[c4]);
            for(; c4 + 8 <= nf4; c4 += 8){
                float4 g[8];
                #pragma unroll
                for(int jj = 0; jj < 8; jj++) g[jj] = G4[(size_t)(c4+jj)*NS_CAP + tid];
                #pragma unroll
                for(int jj = 0; jj < 8; jj++){
                    float d = f4dot(g[jj], u4[c4+jj]);
                    if((jj & 3) == 0) s0 += d; else if((jj & 3) == 1) s1 += d;
                    else if((jj & 3) == 2) s2 += d; else s3 += d;
                }
            }
            for(; c4 < nf4; c4++) s0 += f4dot(G4[(size_t)c4*NS_CAP + tid], u4[c4]);
        }
        return (s0 + s1) + (s2 + s3);
    };

    // init: r0 = -10 * A * 1  (t-image of p=1_D is the row-sum vector)
    float out5[5];
    reduce5(sraw, mfl * sraw, 0.f, 0.f, 0.f, out5);
    float A0 = out5[0] * inv_ns, A1 = out5[1] * inv_nc;
    float cr = own ? -10.f * (c_task*(sraw - A0) + mfl*c_cls*(sraw - A1)) : 0.f;
    if(mth) u[tid] = own ? cr : 0.f;
    __syncthreads();
    float tr = matvec();

    float cp = 0.f, tp = 0.f, cq = 0.f, tq = 0.f, cx = 0.f;
    float gamma_old = 1.f, alpha_old = 1.f;
    bool first = true;

    for(int it = 0; it < CG_ITERS; ++it){
        reduce5(tr, mfl*tr, tr*tr, mfl*tr*tr, tr*cr, out5);
        A0 = out5[0] * inv_ns; A1 = out5[1] * inv_nc;
        float gamma = out5[4];                               // (r,r)
        float delta = 0.1f*gamma + c_task*(out5[2] - out5[0]*A0)
                                 + c_cls *(out5[3] - out5[1]*A1);  // (r,Mr)
        if(gamma < 1e-26f) break;
        float ur = own ? (c_task*(tr - A0) + mfl*c_cls*(tr - A1)) : 0.f;
        float cw = 0.1f*cr + ur;
        if(mth) u[tid] = ur;
        __syncthreads();
        float gv = matvec();
        float tw = 0.1f*tr + gv;
        float beta  = first ? 0.f : gamma / gamma_old;
        float alpha = first ? gamma / delta
                            : gamma / (delta - beta * gamma / alpha_old);
        cp = cr + beta * cp;  tp = tr + beta * tp;
        cq = cw + beta * cq;  tq = tw + beta * tq;
        cx += alpha * cp;
        cr -= alpha * cq;     tr -= alpha * tq;
        gamma_old = gamma; alpha_old = alpha; first = false;
    }

    // v = 10*1 + Xs^T c_x
    __syncthreads();
    if(mth) u[tid] = own ? cx : 0.f;
    __syncthreads();
    const float4* X4 = (const float4*)X;
    const int f4c = tid & 127;
    const int rg  = tid >> 7;
    float4 acc = make_float4(0.f,0.f,0.f,0.f);
    int s = rg;
    for(; s + 28 < nsc; s += 32){
        int n0 = idx_l[s],    n1 = idx_l[s+4],  n2 = idx_l[s+8],  n3 = idx_l[s+12];
        int n4 = idx_l[s+16], n5 = idx_l[s+20], n6 = idx_l[s+24], n7 = idx_l[s+28];
        float w0 = u[s],    w1 = u[s+4],  w2 = u[s+8],  w3 = u[s+12];
        float w4 = u[s+16], w5 = u[s+20], w6 = u[s+24], w7 = u[s+28];
        float4 x0 = X4[(size_t)n0*128 + f4c];
        float4 x1 = X4[(size_t)n1*128 + f4c];
        float4 x2 = X4[(size_t)n2*128 + f4c];
        float4 x3 = X4[(size_t)n3*128 + f4c];
        float4 x4 = X4[(size_t)n4*128 + f4c];
        float4 x5 = X4[(size_t)n5*128 + f4c];
        float4 x6 = X4[(size_t)n6*128 + f4c];
        float4 x7 = X4[(size_t)n7*128 + f4c];
        acc = f4fma(w0,x0, f4fma(w1,x1, f4fma(w2,x2, f4fma(w3,x3, acc))));
        acc = f4fma(w4,x4, f4fma(w5,x5, f4fma(w6,x6, f4fma(w7,x7, acc))));
    }
    for(; s < nsc; s += 4)
        acc = f4fma(u[s], X4[(size_t)idx_l[s]*128 + f4c], acc);
    gl4[rg*128 + f4c] = acc;
    __syncthreads();
    if(tid < 128){
        float4 v = f4add(f4add(gl4[tid], gl4[128+tid]),
                         f4add(gl4[256+tid], gl4[384+tid]));
        v.x += 10.f; v.y += 10.f; v.z += 10.f; v.w += 10.f;
        ((float4*)vout)[(size_t)sys * 128 + tid] = v;
    }
}

// ---------------------------------------------------------------------------
// Kernel 4: per-query output (unchanged).
// ---------------------------------------------------------------------------
__global__ __launch_bounds__(256) void k_out(
        const float* __restrict__ X,
        const int* __restrict__ qry_idx, const int* __restrict__ counts,
        const float* __restrict__ pos_mean, const float* __restrict__ neg_mean,
        const float* __restrict__ vsol, const float* __restrict__ log_scale,
        float* __restrict__ out)
{
    const int bid  = blockIdx.x;
    const int b    = bid >> 1;
    const int h    = bid & 1;
    const int tid  = threadIdx.x;
    const int lane = tid & 63;
    const int wave = tid >> 6;

    __shared__ __align__(16) float vpos[DDIM];
    __shared__ __align__(16) float vneg[DDIM];
    __shared__ float red4[4][4];
    __shared__ float sc[4];

    const int nq  = counts[b*4 + 1];
    const int nqc = min(nq, LPAD);
    const float scale = expf(log_scale[0]);

    float pm0 = pos_mean[b*DDIM + tid], pm1 = pos_mean[b*DDIM + tid + 256];
    float nm0 = neg_mean[b*DDIM + tid], nm1 = neg_mean[b*DDIM + tid + 256];
    float vp0 = vsol[(size_t)(b*2 + 1) * DDIM + tid];
    float vp1 = vsol[(size_t)(b*2 + 1) * DDIM + tid + 256];
    float vn0 = vsol[(size_t)(b*2 + 0) * DDIM + tid];
    float vn1 = vsol[(size_t)(b*2 + 0) * DDIM + tid + 256];
    vpos[tid] = vp0; vpos[tid + 256] = vp1;
    vneg[tid] = vn0; vneg[tid + 256] = vn1;

    float smp = pm0 + pm1;
    float smn = nm0 + nm1;
    float mvp = pm0 * vp0 + pm1 * vp1;
    float mvn = nm0 * vn0 + nm1 * vn1;
    #pragma unroll
    for(int off = 32; off; off >>= 1){
        smp += __shfl_xor(smp, off);
        smn += __shfl_xor(smn, off);
        mvp += __shfl_xor(mvp, off);
        mvn += __shfl_xor(mvn, off);
    }
    if(lane == 0){
        red4[wave][0] = smp; red4[wave][1] = smn;
        red4[wave][2] = mvp; red4[wave][3] = mvn;
    }
    __syncthreads();
    if(tid < 4) sc[tid] = red4[0][tid] + red4[1][tid] + red4[2][tid] + red4[3][tid];
    __syncthreads();

    const float4* vp4 = (const float4*)vpos;
    const float4* vn4 = (const float4*)vneg;
    const float4 vpa = vp4[lane], vpb = vp4[lane + 64];
    const float4 vna = vn4[lane], vnb = vn4[lane + 64];
    for(int r = wave + 4*h; r < nqc; r += 16){
        int r2 = r + 8;
        bool has2 = r2 < nqc;
        int n  = qry_idx[b * LPAD + r];
        int n2 = qry_idx[b * LPAD + (has2 ? r2 : r)];
        const float4* xr = (const float4*)(X + (size_t)n  * DDIM);
        const float4* yr = (const float4*)(X + (size_t)n2 * DDIM);
        float4 x0 = xr[lane], x1 = xr[lane + 64];
        float4 y0 = yr[lane], y1 = yr[lane + 64];
        float tp = f4dot(x0, vpa) + f4dot(x1, vpb);
        float tn = f4dot(x0, vna) + f4dot(x1, vnb);
        float sx = f4sum(x0) + f4sum(x1);
        float tp2 = f4dot(y0, vpa) + f4dot(y1, vpb);
        float tn2 = f4dot(y0, vna) + f4dot(y1, vnb);
        float sx2 = f4sum(y0) + f4sum(y1);
        #pragma unroll
        for(int off = 32; off; off >>= 1){
            tp  += __shfl_xor(tp,  off);
            tn  += __shfl_xor(tn,  off);
            sx  += __shfl_xor(sx,  off);
            tp2 += __shfl_xor(tp2, off);
            tn2 += __shfl_xor(tn2, off);
            sx2 += __shfl_xor(sx2, off);
        }
        if(lane == 0){
            float mp = (tp - sc[2]) * (sx - sc[0]);
            float mn = (tn - sc[3]) * (sx - sc[1]);
            ((float2*)out)[(size_t)b * LPAD + r] = make_float2(mn * scale, mp * scale);
            if(has2){
                float mp2 = (tp2 - sc[2]) * (sx2 - sc[0]);
                float mn2 = (tn2 - sc[3]) * (sx2 - sc[1]);
                ((float2*)out)[(size_t)b * LPAD + r2] = make_float2(mn2 * scale, mp2 * scale);
            }
        }
    }
    const int lo = max(nqc, h * 256), hi = (h + 1) * 256;
    for(int r = lo + tid; r < hi; r += 256)
        ((float2*)out)[(size_t)b * LPAD + r] = make_float2(0.f, 0.f);
}

// ---------------------------------------------------------------------------
extern "C" void kernel_launch(void* const* d_in, const int* in_sizes, int n_in,
                              void* d_out, int out_size, void* d_ws, size_t ws_size,
                              hipStream_t stream)
{
    const float* X         = (const float*)d_in[0];
    const float* log_scale = (const float*)d_in[1];
    const int*   labels    = (const int*)d_in[2];
    const int*   is_query  = (const int*)d_in[3];
    const int*   bidx      = (const int*)d_in[4];
    const int N = in_sizes[2];

    char* ws = (char*)d_ws;
    auto alloc = [&](size_t bytes) -> char* {
        char* p = ws;
        ws += (bytes + 255) & ~(size_t)255;
        return p;
    };
    int*   sup_idx   = (int*)  alloc((size_t)EPISODES * LPAD * sizeof(int));
    int*   qry_idx   = (int*)  alloc((size_t)EPISODES * LPAD * sizeof(int));
    int*   sup_lab   = (int*)  alloc((size_t)EPISODES * LPAD * sizeof(int));
    int*   counts    = (int*)  alloc((size_t)EPISODES * 4 * sizeof(int));
    float* task_mean = (float*)alloc((size_t)EPISODES * DDIM * sizeof(float));
    float* pos_mean  = (float*)alloc((size_t)EPISODES * DDIM * sizeof(float));
    float* neg_mean  = (float*)alloc((size_t)EPISODES * DDIM * sizeof(float));
    float* vsol      = (float*)alloc((size_t)EPISODES * 2 * DDIM * sizeof(float));
    float* row_sums2 = (float*)alloc((size_t)EPISODES * LPAD * 2 * sizeof(float));
    float* G0        = (float*)alloc((size_t)EPISODES * NS_CAP * NS_CAP * sizeof(float));
    (void)ws_size;
    (void)task_mean;

    k_prep<<<EPISODES*2, 256, 0, stream>>>(labels, is_query, bidx, X, N,
                                           sup_idx, qry_idx, sup_lab, counts,
                                           task_mean, pos_mean, neg_mean, row_sums2);
    k_gram<<<EPISODES * NPAIRS, 256, 0, stream>>>(X, sup_idx, counts, G0);
    k_cgc<<<EPISODES * 2, 512, GL_F4 * sizeof(float4), stream>>>(
                                            X, G0, sup_idx, sup_lab, counts,
                                            row_sums2, vsol);
    k_out<<<EPISODES*2, 256, 0, stream>>>(X, qry_idx, counts, pos_mean, neg_mean,
                                          vsol, log_scale, (float*)d_out);
}

// Round 11
// 309.614 us; speedup vs baseline: 2.8543x; 1.0192x over previous
//
#include <hip/hip_runtime.h>
#include <cstdint>
#include <cstddef>

#define EPISODES 128
#define LPAD     512
#define DDIM     512
#define NS_CAP   320
#define GTILE    64
#define NPAIRS   15          // 5*(5+1)/2 tile pairs (NS_CAP/GTILE = 5)
#define CG_ITERS 14
#define GL_F4    10016       // dynamic-LDS float4 capacity (160256 B)
#define KCH      64          // k per staged chunk in k_gram
#define KSTR     72          // ushorts per staged row (64 + 8 pad)

typedef __attribute__((ext_vector_type(8))) __bf16 bf16x8;
typedef __attribute__((ext_vector_type(4))) float  floatx4;

__device__ __forceinline__ int lower_bound_dev(const int* __restrict__ a, int n, int key){
    int lo = 0, hi = n;
    while(lo < hi){
        int m = (lo + hi) >> 1;
        if(a[m] < key) lo = m + 1; else hi = m;
    }
    return lo;
}

__device__ __forceinline__ float4 f4add(float4 a, float4 b){
    return make_float4(a.x+b.x, a.y+b.y, a.z+b.z, a.w+b.w);
}
__device__ __forceinline__ float4 f4fma(float s, float4 a, float4 acc){
    return make_float4(acc.x + s*a.x, acc.y + s*a.y, acc.z + s*a.z, acc.w + s*a.w);
}
__device__ __forceinline__ float f4dot(float4 a, float4 b){
    return a.x*b.x + a.y*b.y + a.z*b.z + a.w*b.w;
}
__device__ __forceinline__ float f4sum(float4 a){ return (a.x+a.y)+(a.z+a.w); }

__device__ __forceinline__ unsigned short f2bf(float x){
    unsigned u = __float_as_uint(x);
    u += 0x7FFFu + ((u >> 16) & 1u);
    return (unsigned short)(u >> 16);
}
__device__ __forceinline__ float bf2f(unsigned short h){
    return __uint_as_float(((unsigned)h) << 16);
}

// ---------------------------------------------------------------------------
// Kernel 1: fused segmentation + means + per-half row sums (unchanged).
// ---------------------------------------------------------------------------
__global__ __launch_bounds__(256) void k_prep(
        const int* __restrict__ labels, const int* __restrict__ is_query,
        const int* __restrict__ bidx, const float* __restrict__ X, int N,
        int* __restrict__ sup_idx, int* __restrict__ qry_idx,
        int* __restrict__ sup_lab, int* __restrict__ counts,
        float* __restrict__ task_mean, float* __restrict__ pos_mean,
        float* __restrict__ neg_mean, float* __restrict__ row_sums2)
{
    const int bid  = blockIdx.x;
    const int b    = bid >> 1;
    const int h    = bid & 1;
    const int tid  = threadIdx.x;
    const int lane = tid & 63;
    const int wave = tid >> 6;

    __shared__ int s_start, s_end;
    __shared__ int wq[4];
    __shared__ int s_runq, s_npos;
    __shared__ int   sidx[NS_CAP];
    __shared__ float slabf[NS_CAP];
    __shared__ float4 pa[4][64];
    __shared__ float4 pp[4][64];

    if(tid == 0){
        s_start = lower_bound_dev(bidx, N, b);
        s_end   = lower_bound_dev(bidx, N, b + 1);
        s_runq  = 0;
        s_npos  = 0;
    }
    __syncthreads();
    const int start = s_start, end = s_end;

    for(int base = start; base < end; base += 256){
        int idx   = base + tid;
        bool valid = idx < end;
        int q   = valid ? is_query[idx] : 0;
        int lab = valid ? labels[idx]   : 0;
        unsigned long long m = __ballot(q == 1);
        if(lane == 0) wq[wave] = __popcll(m);
        __syncthreads();
        int woff = 0;
        for(int w = 0; w < wave; w++) woff += wq[w];
        int qbefore = __popcll(m & ((1ull << lane) - 1ull)) + woff;
        int runq0 = s_runq;
        int chunk_total = wq[0] + wq[1] + wq[2] + wq[3];
        if(valid){
            int pos_in_seg = idx - start;
            if(q){
                int qr = runq0 + qbefore;
                if(h == 0 && qr < LPAD) qry_idx[b * LPAD + qr] = idx;
            } else {
                int sr = pos_in_seg - runq0 - qbefore;
                if(sr < LPAD){
                    if(h == 0){
                        sup_idx[b * LPAD + sr] = idx;
                        sup_lab[b * LPAD + sr] = lab;
                    }
                    if(sr < NS_CAP){ sidx[sr] = idx; slabf[sr] = (float)lab; }
                    if(lab == 1) atomicAdd(&s_npos, 1);
                }
            }
        }
        __syncthreads();
        if(tid == 0) s_runq = runq0 + chunk_total;
        __syncthreads();
    }

    const int nq   = s_runq;
    const int ns   = (end - start) - nq;
    const int npos = s_npos;
    const int nneg = ns - npos;
    if(h == 0 && tid == 0){
        counts[b*4 + 0] = ns;
        counts[b*4 + 1] = nq;
        counts[b*4 + 2] = npos;
        counts[b*4 + 3] = nneg;
    }
    const int nsb = min(ns, NS_CAP);

    const float4* X4 = (const float4*)X;
    const int colg = h*64 + lane;
    float4 sa = make_float4(0.f,0.f,0.f,0.f);
    float4 sp = make_float4(0.f,0.f,0.f,0.f);
    int r = wave;
    for(; r + 12 < nsb; r += 16){
        int n0 = sidx[r], n1 = sidx[r+4], n2 = sidx[r+8], n3 = sidx[r+12];
        float l0 = slabf[r], l1 = slabf[r+4], l2 = slabf[r+8], l3 = slabf[r+12];
        float4 x0 = X4[(size_t)n0*128 + colg];
        float4 x1 = X4[(size_t)n1*128 + colg];
        float4 x2 = X4[(size_t)n2*128 + colg];
        float4 x3 = X4[(size_t)n3*128 + colg];
        sa = f4add(sa, f4add(f4add(x0,x1), f4add(x2,x3)));
        sp = f4fma(l0,x0, f4fma(l1,x1, f4fma(l2,x2, f4fma(l3,x3, sp))));
        float r0s = f4sum(x0), r1s = f4sum(x1), r2s = f4sum(x2), r3s = f4sum(x3);
        #pragma unroll
        for(int off = 32; off; off >>= 1){
            r0s += __shfl_xor(r0s, off); r1s += __shfl_xor(r1s, off);
            r2s += __shfl_xor(r2s, off); r3s += __shfl_xor(r3s, off);
        }
        if(lane == 0){
            row_sums2[(b*LPAD + r   )*2 + h] = r0s;
            row_sums2[(b*LPAD + r+4 )*2 + h] = r1s;
            row_sums2[(b*LPAD + r+8 )*2 + h] = r2s;
            row_sums2[(b*LPAD + r+12)*2 + h] = r3s;
        }
    }
    for(; r < nsb; r += 4){
        int n = sidx[r];
        float l = slabf[r];
        float4 x = X4[(size_t)n*128 + colg];
        sa = f4add(sa, x);
        sp = f4fma(l, x, sp);
        float rs = f4sum(x);
        #pragma unroll
        for(int off = 32; off; off >>= 1) rs += __shfl_xor(rs, off);
        if(lane == 0) row_sums2[(b*LPAD + r)*2 + h] = rs;
    }
    pa[wave][lane] = sa;
    pp[wave][lane] = sp;
    __syncthreads();
    if(tid < 64){
        float4 A = f4add(f4add(pa[0][tid],pa[1][tid]), f4add(pa[2][tid],pa[3][tid]));
        float4 P = f4add(f4add(pp[0][tid],pp[1][tid]), f4add(pp[2][tid],pp[3][tid]));
        float4 Nn = make_float4(A.x-P.x, A.y-P.y, A.z-P.z, A.w-P.w);
        float ia = 1.f/(float)ns, ip = 1.f/(float)npos, in = 1.f/(float)nneg;
        int c = b*128 + h*64 + tid;
        ((float4*)task_mean)[c] = make_float4(A.x*ia, A.y*ia, A.z*ia, A.w*ia);
        ((float4*)pos_mean )[c] = make_float4(P.x*ip, P.y*ip, P.z*ip, P.w*ip);
        ((float4*)neg_mean )[c] = make_float4(Nn.x*in, Nn.y*in, Nn.z*in, Nn.w*in);
    }
}

// ---------------------------------------------------------------------------
// Kernel 2: Gram via bf16 MFMA with hi/lo split (unchanged from R10).
// ---------------------------------------------------------------------------
__global__ __launch_bounds__(256) void k_gram(
        const float* __restrict__ X, const int* __restrict__ sup_idx,
        const int* __restrict__ counts, float* __restrict__ G0)
{
    const int bid = blockIdx.x;
    const int b   = bid / NPAIRS;
    int tp = bid % NPAIRS;
    int ti = 0;
    while((ti+1)*(ti+2)/2 <= tp) ti++;
    const int tj  = tp - ti*(ti+1)/2;          // ti >= tj
    const int tid = threadIdx.x;
    const int lane = tid & 63;
    const int wave = tid >> 6;

    const int ns  = counts[b*4 + 0];
    const int nsc = min(ns, NS_CAP);
    if(ti * GTILE >= nsc) return;
    const bool diag = (ti == tj);

    __shared__ int ia[GTILE], ib[GTILE];
    __shared__ __align__(16) unsigned short SM[4 * GTILE * KSTR];  // 36864 B
    unsigned short* SAh = SM;
    unsigned short* SAl = SM + GTILE*KSTR;
    unsigned short* SBh = SM + 2*GTILE*KSTR;
    unsigned short* SBl = SM + 3*GTILE*KSTR;

    if(tid < GTILE)        ia[tid]    = sup_idx[b*LPAD + min(ti*GTILE + tid,      nsc-1)];
    else if(tid < 2*GTILE) ib[tid-64] = sup_idx[b*LPAD + min(tj*GTILE + (tid-64), nsc-1)];

    const unsigned short* Bh = diag ? SAh : SBh;
    const unsigned short* Bl = diag ? SAl : SBl;

    const int ry = (wave >> 1) * 32;
    const int cx = (wave & 1) * 32;
    const int fr = lane & 15;
    const int fq = (lane >> 4) * 8;

    floatx4 acc[2][2];
    acc[0][0] = (floatx4){0.f,0.f,0.f,0.f};
    acc[0][1] = (floatx4){0.f,0.f,0.f,0.f};
    acc[1][0] = (floatx4){0.f,0.f,0.f,0.f};
    acc[1][1] = (floatx4){0.f,0.f,0.f,0.f};

    for(int k0 = 0; k0 < DDIM; k0 += KCH){
        __syncthreads();
        #pragma unroll
        for(int p = 0; p < 4; p++){
            int e = tid + p*256;
            int row = e >> 4, kq = e & 15;
            float4 xa = *(const float4*)(X + (size_t)ia[row]*DDIM + k0 + kq*4);
            ushort4 hh, ll;
            hh.x = f2bf(xa.x); ll.x = f2bf(xa.x - bf2f(hh.x));
            hh.y = f2bf(xa.y); ll.y = f2bf(xa.y - bf2f(hh.y));
            hh.z = f2bf(xa.z); ll.z = f2bf(xa.z - bf2f(hh.z));
            hh.w = f2bf(xa.w); ll.w = f2bf(xa.w - bf2f(hh.w));
            *(ushort4*)&SAh[row*KSTR + kq*4] = hh;
            *(ushort4*)&SAl[row*KSTR + kq*4] = ll;
            if(!diag){
                float4 xb = *(const float4*)(X + (size_t)ib[row]*DDIM + k0 + kq*4);
                ushort4 h2, l2;
                h2.x = f2bf(xb.x); l2.x = f2bf(xb.x - bf2f(h2.x));
                h2.y = f2bf(xb.y); l2.y = f2bf(xb.y - bf2f(h2.y));
                h2.z = f2bf(xb.z); l2.z = f2bf(xb.z - bf2f(h2.z));
                h2.w = f2bf(xb.w); l2.w = f2bf(xb.w - bf2f(h2.w));
                *(ushort4*)&SBh[row*KSTR + kq*4] = h2;
                *(ushort4*)&SBl[row*KSTR + kq*4] = l2;
            }
        }
        __syncthreads();
        #pragma unroll
        for(int ks = 0; ks < KCH; ks += 32){
            bf16x8 ah0 = *(const bf16x8*)&SAh[(ry     + fr)*KSTR + ks + fq];
            bf16x8 ah1 = *(const bf16x8*)&SAh[(ry + 16 + fr)*KSTR + ks + fq];
            bf16x8 al0 = *(const bf16x8*)&SAl[(ry     + fr)*KSTR + ks + fq];
            bf16x8 al1 = *(const bf16x8*)&SAl[(ry + 16 + fr)*KSTR + ks + fq];
            bf16x8 bh0 = *(const bf16x8*)&Bh[(cx     + fr)*KSTR + ks + fq];
            bf16x8 bh1 = *(const bf16x8*)&Bh[(cx + 16 + fr)*KSTR + ks + fq];
            bf16x8 bl0 = *(const bf16x8*)&Bl[(cx     + fr)*KSTR + ks + fq];
            bf16x8 bl1 = *(const bf16x8*)&Bl[(cx + 16 + fr)*KSTR + ks + fq];
            acc[0][0] = __builtin_amdgcn_mfma_f32_16x16x32_bf16(ah0, bh0, acc[0][0], 0,0,0);
            acc[0][1] = __builtin_amdgcn_mfma_f32_16x16x32_bf16(ah0, bh1, acc[0][1], 0,0,0);
            acc[1][0] = __builtin_amdgcn_mfma_f32_16x16x32_bf16(ah1, bh0, acc[1][0], 0,0,0);
            acc[1][1] = __builtin_amdgcn_mfma_f32_16x16x32_bf16(ah1, bh1, acc[1][1], 0,0,0);
            acc[0][0] = __builtin_amdgcn_mfma_f32_16x16x32_bf16(ah0, bl0, acc[0][0], 0,0,0);
            acc[0][1] = __builtin_amdgcn_mfma_f32_16x16x32_bf16(ah0, bl1, acc[0][1], 0,0,0);
            acc[1][0] = __builtin_amdgcn_mfma_f32_16x16x32_bf16(ah1, bl0, acc[1][0], 0,0,0);
            acc[1][1] = __builtin_amdgcn_mfma_f32_16x16x32_bf16(ah1, bl1, acc[1][1], 0,0,0);
            acc[0][0] = __builtin_amdgcn_mfma_f32_16x16x32_bf16(al0, bh0, acc[0][0], 0,0,0);
            acc[0][1] = __builtin_amdgcn_mfma_f32_16x16x32_bf16(al0, bh1, acc[0][1], 0,0,0);
            acc[1][0] = __builtin_amdgcn_mfma_f32_16x16x32_bf16(al1, bh0, acc[1][0], 0,0,0);
            acc[1][1] = __builtin_amdgcn_mfma_f32_16x16x32_bf16(al1, bh1, acc[1][1], 0,0,0);
        }
    }

    float4* Gf4 = (float4*)(G0 + (size_t)b * NS_CAP * NS_CAP);
    const int q = lane >> 4, j = lane & 15;
    #pragma unroll
    for(int sy = 0; sy < 2; sy++)
        #pragma unroll
        for(int sx = 0; sx < 2; sx++){
            int cq = ((ti*GTILE + ry + sy*16) >> 2) + q;
            int t  = tj*GTILE + cx + sx*16 + j;
            Gf4[(size_t)cq * NS_CAP + t] =
                make_float4(acc[sy][sx].x, acc[sy][sx].y, acc[sy][sx].z, acc[sy][sx].w);
        }

    if(!diag){
        __syncthreads();
        float* Tb = (float*)SM;
        #pragma unroll
        for(int sy = 0; sy < 2; sy++)
            #pragma unroll
            for(int sx = 0; sx < 2; sx++){
                int r0 = ry + sy*16 + 4*q;
                int c  = cx + sx*16 + j;
                Tb[(r0+0)*68 + c] = acc[sy][sx].x;
                Tb[(r0+1)*68 + c] = acc[sy][sx].y;
                Tb[(r0+2)*68 + c] = acc[sy][sx].z;
                Tb[(r0+3)*68 + c] = acc[sy][sx].w;
            }
        __syncthreads();
        for(int e = tid; e < 16*GTILE; e += 256){
            int cc = e >> 6;
            int r  = e & 63;
            float4 v = *(const float4*)&Tb[r*68 + 4*cc];
            Gf4[(size_t)(tj*16 + cc) * NS_CAP + ti*GTILE + r] = v;
        }
    }
}

// ---------------------------------------------------------------------------
// Kernel 3: coefficient-space Chronopoulos-Gear CG, Gram in dynamic LDS.
// v2: 2 barriers/iteration (u-publish folded into reduction), cheap
// cross-wave combine (1 LDS read + shfl_xor tree + 5 extracts instead of
// 40 LDS reads/thread), final sweep skipped (only alpha needed).
// ---------------------------------------------------------------------------
extern __shared__ float4 gl4[];                // GL_F4 float4 (160256 B)

__global__ __launch_bounds__(512, 2) void k_cgc(
        const float* __restrict__ X, const float* __restrict__ G0,
        const int* __restrict__ sup_idx, const int* __restrict__ sup_lab,
        const int* __restrict__ counts, const float* __restrict__ row_sums2,
        float* __restrict__ vout)
{
    const int bid  = blockIdx.x;
    const int sys  = ((bid & 7) << 5) | (bid >> 3);   // pair-local XCD swizzle
    const int b    = sys >> 1;
    const int cls  = sys & 1;
    const int tid  = threadIdx.x;
    const int lane = tid & 63;
    const int wave = tid >> 6;

    __shared__ __align__(16) float u[NS_CAP];
    __shared__ int   idx_l[NS_CAP];
    __shared__ float P[64];                    // [wave*8 + k], k<5 valid

    const int ns   = counts[b*4 + 0];
    const int nsc  = min(ns, NS_CAP);
    const int ncls = cls ? counts[b*4 + 2] : counts[b*4 + 3];
    const float c_task = 0.9f / (float)(ns - 1);
    const float c_cls  = 0.1f / (float)(ncls - 1);
    const float inv_ns = 1.f / (float)ns;
    const float inv_nc = 1.f / (float)ncls;
    const float4* G4 = (const float4*)(G0 + (size_t)b * NS_CAP * NS_CAP);
    const float4* u4 = (const float4*)u;
    const int nf4 = (nsc + 3) >> 2;
    const int c4l = min(nf4, GL_F4 / nsc);     // Gram blocks cached in LDS

    const bool mth = tid < NS_CAP;
    const bool own = tid < nsc;
    float mfl = 0.f, sraw = 0.f;
    if(own){
        mfl  = (sup_lab[b*LPAD + tid] == cls) ? 1.f : 0.f;
        float2 rs = ((const float2*)row_sums2)[b*LPAD + tid];
        sraw = rs.x + rs.y;
    }
    for(int s = tid; s < nsc; s += 512) idx_l[s] = sup_idx[b*LPAD + s];
    if(tid < 64) P[tid] = 0.f;                 // zero pad slots (k>=5)

    // Stage Gram blocks into LDS: gl4[c4*nsc + t] = G4[c4*NS_CAP + t]
    for(int c4 = 0; c4 < c4l; c4++)
        for(int t = tid; t < nsc; t += 512)
            gl4[c4*nsc + t] = G4[(size_t)c4 * NS_CAP + t];
    __syncthreads();

    // bundle: in-wave 5-reduce, partials to P, barrier (a), cross-wave
    // combine via shfl_xor tree + 5 extracts. Caller must place barrier (b)
    // (after its u-write) before the next LDS-write phase.
    auto bundle = [&](float v0, float v1, float v2, float v3, float v4,
                      float* S){
        #pragma unroll
        for(int off = 32; off; off >>= 1){
            v0 += __shfl_xor(v0, off); v1 += __shfl_xor(v1, off);
            v2 += __shfl_xor(v2, off); v3 += __shfl_xor(v3, off);
            v4 += __shfl_xor(v4, off);
        }
        if(lane == 0){
            P[wave*8 + 0] = v0; P[wave*8 + 1] = v1; P[wave*8 + 2] = v2;
            P[wave*8 + 3] = v3; P[wave*8 + 4] = v4;
        }
        __syncthreads();                       // (a)
        float pv = P[lane];
        pv += __shfl_xor(pv, 8);
        pv += __shfl_xor(pv, 16);
        pv += __shfl_xor(pv, 32);              // pv = S[lane & 7]
        S[0] = __shfl(pv, 0); S[1] = __shfl(pv, 1); S[2] = __shfl(pv, 2);
        S[3] = __shfl(pv, 3); S[4] = __shfl(pv, 4);
    };

    auto matvec = [&]() -> float {
        float s0 = 0.f, s1 = 0.f, s2 = 0.f, s3 = 0.f;
        if(own){
            const float4* gq = gl4 + tid;
            int c4 = 0;
            for(; c4 + 8 <= c4l; c4 += 8){
                float4 g0 = gq[(c4+0)*nsc], g1 = gq[(c4+1)*nsc];
                float4 g2 = gq[(c4+2)*nsc], g3 = gq[(c4+3)*nsc];
                float4 g4 = gq[(c4+4)*nsc], g5 = gq[(c4+5)*nsc];
                float4 g6 = gq[(c4+6)*nsc], g7 = gq[(c4+7)*nsc];
                s0 += f4dot(g0, u4[c4+0]); s1 += f4dot(g1, u4[c4+1]);
                s2 += f4dot(g2, u4[c4+2]); s3 += f4dot(g3, u4[c4+3]);
                s0 += f4dot(g4, u4[c4+4]); s1 += f4dot(g5, u4[c4+5]);
                s2 += f4dot(g6, u4[c4+6]); s3 += f4dot(g7, u4[c4+7]);
            }
            for(; c4 < c4l; c4++) s0 += f4dot(gq[c4*nsc], u4[c4]);
            for(; c4 + 8 <= nf4; c4 += 8){
                float4 g[8];
                #pragma unroll
                for(int jj = 0; jj < 8; jj++) g[jj] = G4[(size_t)(c4+jj)*NS_CAP + tid];
                #pragma unroll
                for(int jj = 0; jj < 8; jj++){
                    float d = f4dot(g[jj], u4[c4+jj]);
                    if((jj & 3) == 0) s0 += d; else if((jj & 3) == 1) s1 += d;
                    else if((jj & 3) == 2) s2 += d; else s3 += d;
                }
            }
            for(; c4 < nf4; c4++) s0 += f4dot(G4[(size_t)c4*NS_CAP + tid], u4[c4]);
        }
        return (s0 + s1) + (s2 + s3);
    };

    // init: r0 = -10 * A * 1  (t-image of p=1_D is the row-sum vector)
    float S[5];
    bundle(sraw, mfl * sraw, 0.f, 0.f, 0.f, S);
    float A0 = S[0] * inv_ns, A1 = S[1] * inv_nc;
    float cr = own ? -10.f * (c_task*(sraw - A0) + mfl*c_cls*(sraw - A1)) : 0.f;
    if(mth) u[tid] = cr;                       // cr = 0 for !own
    __syncthreads();                           // (b)
    float tr = matvec();

    float cp = 0.f, cq = 0.f, tq = 0.f, cx = 0.f;
    float gamma_old = 1.f, alpha_old = 1.f;
    bool first = true;

    for(int it = 0; it < CG_ITERS; ++it){
        // bundle: S1=Σtr, S2=Σm·tr, S3=Σtr², S4=Σm·tr², S5=Σtr·cr
        bundle(tr, mfl*tr, tr*tr, mfl*tr*tr, tr*cr, S);
        A0 = S[0] * inv_ns; A1 = S[1] * inv_nc;
        float gamma = S[4];                                  // (r,r)
        float delta = 0.1f*gamma + c_task*(S[2] - S[0]*A0)
                                 + c_cls *(S[3] - S[1]*A1);  // (r,Mr)
        float beta  = first ? 0.f : gamma / gamma_old;
        float denom = first ? delta : (delta - beta * gamma / alpha_old);
        float alpha = (gamma < 1e-30f) ? 0.f : gamma / denom;
        float ur = own ? (c_task*(tr - A0) + mfl*c_cls*(tr - A1)) : 0.f;
        float cw = 0.1f*cr + ur;                             // c of w = M r
        cp = cr + beta * cp;
        cq = cw + beta * cq;
        cx += alpha * cp;
        if(it == CG_ITERS - 1 || gamma < 1e-26f) break;      // final sweep skipped
        if(mth) u[tid] = ur;
        __syncthreads();                                     // (b)
        float gv = matvec();                                 // G0 * u_r
        float tw = 0.1f*tr + gv;                             // t of w
        tq = tw + beta * tq;
        cr -= alpha * cq;
        tr -= alpha * tq;
        gamma_old = gamma; alpha_old = alpha; first = false;
    }

    // v = 10*1 + Xs^T c_x
    __syncthreads();
    if(mth) u[tid] = own ? cx : 0.f;
    __syncthreads();
    const float4* X4 = (const float4*)X;
    const int f4c = tid & 127;
    const int rg  = tid >> 7;
    float4 acc = make_float4(0.f,0.f,0.f,0.f);
    int s = rg;
    for(; s + 28 < nsc; s += 32){
        int n0 = idx_l[s],    n1 = idx_l[s+4],  n2 = idx_l[s+8],  n3 = idx_l[s+12];
        int n4 = idx_l[s+16], n5 = idx_l[s+20], n6 = idx_l[s+24], n7 = idx_l[s+28];
        float w0 = u[s],    w1 = u[s+4],  w2 = u[s+8],  w3 = u[s+12];
        float w4 = u[s+16], w5 = u[s+20], w6 = u[s+24], w7 = u[s+28];
        float4 x0 = X4[(size_t)n0*128 + f4c];
        float4 x1 = X4[(size_t)n1*128 + f4c];
        float4 x2 = X4[(size_t)n2*128 + f4c];
        float4 x3 = X4[(size_t)n3*128 + f4c];
        float4 x4 = X4[(size_t)n4*128 + f4c];
        float4 x5 = X4[(size_t)n5*128 + f4c];
        float4 x6 = X4[(size_t)n6*128 + f4c];
        float4 x7 = X4[(size_t)n7*128 + f4c];
        acc = f4fma(w0,x0, f4fma(w1,x1, f4fma(w2,x2, f4fma(w3,x3, acc))));
        acc = f4fma(w4,x4, f4fma(w5,x5, f4fma(w6,x6, f4fma(w7,x7, acc))));
    }
    for(; s < nsc; s += 4)
        acc = f4fma(u[s], X4[(size_t)idx_l[s]*128 + f4c], acc);
    gl4[rg*128 + f4c] = acc;
    __syncthreads();
    if(tid < 128){
        float4 v = f4add(f4add(gl4[tid], gl4[128+tid]),
                         f4add(gl4[256+tid], gl4[384+tid]));
        v.x += 10.f; v.y += 10.f; v.z += 10.f; v.w += 10.f;
        ((float4*)vout)[(size_t)sys * 128 + tid] = v;
    }
}

// ---------------------------------------------------------------------------
// Kernel 4: per-query output (unchanged).
// ---------------------------------------------------------------------------
__global__ __launch_bounds__(256) void k_out(
        const float* __restrict__ X,
        const int* __restrict__ qry_idx, const int* __restrict__ counts,
        const float* __restrict__ pos_mean, const float* __restrict__ neg_mean,
        const float* __restrict__ vsol, const float* __restrict__ log_scale,
        float* __restrict__ out)
{
    const int bid  = blockIdx.x;
    const int b    = bid >> 1;
    const int h    = bid & 1;
    const int tid  = threadIdx.x;
    const int lane = tid & 63;
    const int wave = tid >> 6;

    __shared__ __align__(16) float vpos[DDIM];
    __shared__ __align__(16) float vneg[DDIM];
    __shared__ float red4[4][4];
    __shared__ float sc[4];

    const int nq  = counts[b*4 + 1];
    const int nqc = min(nq, LPAD);
    const float scale = expf(log_scale[0]);

    float pm0 = pos_mean[b*DDIM + tid], pm1 = pos_mean[b*DDIM + tid + 256];
    float nm0 = neg_mean[b*DDIM + tid], nm1 = neg_mean[b*DDIM + tid + 256];
    float vp0 = vsol[(size_t)(b*2 + 1) * DDIM + tid];
    float vp1 = vsol[(size_t)(b*2 + 1) * DDIM + tid + 256];
    float vn0 = vsol[(size_t)(b*2 + 0) * DDIM + tid];
    float vn1 = vsol[(size_t)(b*2 + 0) * DDIM + tid + 256];
    vpos[tid] = vp0; vpos[tid + 256] = vp1;
    vneg[tid] = vn0; vneg[tid + 256] = vn1;

    float smp = pm0 + pm1;
    float smn = nm0 + nm1;
    float mvp = pm0 * vp0 + pm1 * vp1;
    float mvn = nm0 * vn0 + nm1 * vn1;
    #pragma unroll
    for(int off = 32; off; off >>= 1){
        smp += __shfl_xor(smp, off);
        smn += __shfl_xor(smn, off);
        mvp += __shfl_xor(mvp, off);
        mvn += __shfl_xor(mvn, off);
    }
    if(lane == 0){
        red4[wave][0] = smp; red4[wave][1] = smn;
        red4[wave][2] = mvp; red4[wave][3] = mvn;
    }
    __syncthreads();
    if(tid < 4) sc[tid] = red4[0][tid] + red4[1][tid] + red4[2][tid] + red4[3][tid];
    __syncthreads();

    const float4* vp4 = (const float4*)vpos;
    const float4* vn4 = (const float4*)vneg;
    const float4 vpa = vp4[lane], vpb = vp4[lane + 64];
    const float4 vna = vn4[lane], vnb = vn4[lane + 64];
    for(int r = wave + 4*h; r < nqc; r += 16){
        int r2 = r + 8;
        bool has2 = r2 < nqc;
        int n  = qry_idx[b * LPAD + r];
        int n2 = qry_idx[b * LPAD + (has2 ? r2 : r)];
        const float4* xr = (const float4*)(X + (size_t)n  * DDIM);
        const float4* yr = (const float4*)(X + (size_t)n2 * DDIM);
        float4 x0 = xr[lane], x1 = xr[lane + 64];
        float4 y0 = yr[lane], y1 = yr[lane + 64];
        float tp = f4dot(x0, vpa) + f4dot(x1, vpb);
        float tn = f4dot(x0, vna) + f4dot(x1, vnb);
        float sx = f4sum(x0) + f4sum(x1);
        float tp2 = f4dot(y0, vpa) + f4dot(y1, vpb);
        float tn2 = f4dot(y0, vna) + f4dot(y1, vnb);
        float sx2 = f4sum(y0) + f4sum(y1);
        #pragma unroll
        for(int off = 32; off; off >>= 1){
            tp  += __shfl_xor(tp,  off);
            tn  += __shfl_xor(tn,  off);
            sx  += __shfl_xor(sx,  off);
            tp2 += __shfl_xor(tp2, off);
            tn2 += __shfl_xor(tn2, off);
            sx2 += __shfl_xor(sx2, off);
        }
        if(lane == 0){
            float mp = (tp - sc[2]) * (sx - sc[0]);
            float mn = (tn - sc[3]) * (sx - sc[1]);
            ((float2*)out)[(size_t)b * LPAD + r] = make_float2(mn * scale, mp * scale);
            if(has2){
                float mp2 = (tp2 - sc[2]) * (sx2 - sc[0]);
                float mn2 = (tn2 - sc[3]) * (sx2 - sc[1]);
                ((float2*)out)[(size_t)b * LPAD + r2] = make_float2(mn2 * scale, mp2 * scale);
            }
        }
    }
    const int lo = max(nqc, h * 256), hi = (h + 1) * 256;
    for(int r = lo + tid; r < hi; r += 256)
        ((float2*)out)[(size_t)b * LPAD + r] = make_float2(0.f, 0.f);
}

// ---------------------------------------------------------------------------
extern "C" void kernel_launch(void* const* d_in, const int* in_sizes, int n_in,
                              void* d_out, int out_size, void* d_ws, size_t ws_size,
                              hipStream_t stream)
{
    const float* X         = (const float*)d_in[0];
    const float* log_scale = (const float*)d_in[1];
    const int*   labels    = (const int*)d_in[2];
    const int*   is_query  = (const int*)d_in[3];
    const int*   bidx      = (const int*)d_in[4];
    const int N = in_sizes[2];

    char* ws = (char*)d_ws;
    auto alloc = [&](size_t bytes) -> char* {
        char* p = ws;
        ws += (bytes + 255) & ~(size_t)255;
        return p;
    };
    int*   sup_idx   = (int*)  alloc((size_t)EPISODES * LPAD * sizeof(int));
    int*   qry_idx   = (int*)  alloc((size_t)EPISODES * LPAD * sizeof(int));
    int*   sup_lab   = (int*)  alloc((size_t)EPISODES * LPAD * sizeof(int));
    int*   counts    = (int*)  alloc((size_t)EPISODES * 4 * sizeof(int));
    float* task_mean = (float*)alloc((size_t)EPISODES * DDIM * sizeof(float));
    float* pos_mean  = (float*)alloc((size_t)EPISODES * DDIM * sizeof(float));
    float* neg_mean  = (float*)alloc((size_t)EPISODES * DDIM * sizeof(float));
    float* vsol      = (float*)alloc((size_t)EPISODES * 2 * DDIM * sizeof(float));
    float* row_sums2 = (float*)alloc((size_t)EPISODES * LPAD * 2 * sizeof(float));
    float* G0        = (float*)alloc((size_t)EPISODES * NS_CAP * NS_CAP * sizeof(float));
    (void)ws_size;
    (void)task_mean;

    k_prep<<<EPISODES*2, 256, 0, stream>>>(labels, is_query, bidx, X, N,
                                           sup_idx, qry_idx, sup_lab, counts,
                                           task_mean, pos_mean, neg_mean, row_sums2);
    k_gram<<<EPISODES * NPAIRS, 256, 0, stream>>>(X, sup_idx, counts, G0);
    k_cgc<<<EPISODES * 2, 512, GL_F4 * sizeof(float4), stream>>>(
                                            X, G0, sup_idx, sup_lab, counts,
                                            row_sums2, vsol);
    k_out<<<EPISODES*2, 256, 0, stream>>>(X, qry_idx, counts, pos_mean, neg_mean,
                                          vsol, log_scale, (float*)d_out);
}